// Round 8
// baseline (2090.701 us; speedup 1.0000x reference)
//
#include <hip/hip_runtime.h>
#include <hip/hip_bf16.h>

// Hetero-SAGE: bucket-binned aggregation (no CSR sort, no global atomics) +
// bf16-MFMA GEMMs with folded classifier (layer-2 linear => z@Wc1 folded).
#define NUV 100000
#define NMV 20000
#define NEV 1000000
#define ETV 500000

#define DT   56                 // dests per bucket (agg LDS tile)
#define NBKM 358                // ceil(NMV/DT)
#define NBKU 1786               // ceil(NUV/DT)
#define CHK  8192               // edges per bin chunk
#define NCH  123                // ceil(NEV/CHK)
#define G1MB 625                // merchant layer-1 gemm blocks (NMV/32)
#define G2MB 313                // merchant layer-2 gemm blocks (ceil(NMV/64))

typedef unsigned short u16;
typedef unsigned int u32;
typedef __attribute__((ext_vector_type(8))) short s16x8;
typedef __attribute__((ext_vector_type(4))) float f32x4;
typedef __attribute__((ext_vector_type(4))) unsigned short u16x4;
typedef __attribute__((ext_vector_type(4))) unsigned int u32x4;

__device__ inline u16 bf16r(float f) {  // RTNE float->bf16
  u32 b = __builtin_bit_cast(u32, f);
  u32 r = b + 0x7fffu + ((b >> 16) & 1u);
  return (u16)(r >> 16);
}
__device__ inline float bflo(u32 v) { return __builtin_bit_cast(float, v << 16); }
__device__ inline float bfhi(u32 v) { return __builtin_bit_cast(float, v & 0xffff0000u); }

#define GLOAD_LDS16(src, dst) \
  __builtin_amdgcn_global_load_lds((const __attribute__((address_space(1))) void*)(src), \
                                   (__attribute__((address_space(3))) void*)(dst), 16, 0, 0)

// ---------------- x_user -> bf16 (halves layer-1 gather traffic) ----------------
__global__ __launch_bounds__(256) void k_xub(const float* __restrict__ in, u32* __restrict__ o, int n8) {
  int stride = gridDim.x * 256;
  for (int i = blockIdx.x * 256 + threadIdx.x; i < n8; i += stride) {
    float4 a = *(const float4*)(in + (size_t)i * 8);
    float4 b = *(const float4*)(in + (size_t)i * 8 + 4);
    u32x4 r;
    r[0] = (u32)bf16r(a.x) | ((u32)bf16r(a.y) << 16);
    r[1] = (u32)bf16r(a.z) | ((u32)bf16r(a.w) << 16);
    r[2] = (u32)bf16r(b.x) | ((u32)bf16r(b.y) << 16);
    r[3] = (u32)bf16r(b.z) | ((u32)bf16r(b.w) << 16);
    *(u32x4*)(o + (size_t)i * 4) = r;
  }
}

// ---------------- bucket binning: chunk-local counting sort, zero global atomics ----
// Per block: one 8192-edge chunk of one edge type. Output: binned[chunk range]
// grouped by bucket, plus seg[(chunk,bucket)] = (offset_in_chunk<<16 | len).
// Packed edge: (dest % DT) << 24 | src_row.
__global__ __launch_bounds__(256) void k_bin(
    const int* __restrict__ col_um, const int* __restrict__ row_um,
    u32* __restrict__ binned_um, u32* __restrict__ seg_um,
    const int* __restrict__ col_mu, const int* __restrict__ row_mu,
    u32* __restrict__ binned_mu, u32* __restrict__ seg_mu) {
  __shared__ u16 rank16[CHK];
  __shared__ int cnt[NBKU];
  __shared__ int wsum[4];
  __shared__ int s_carry;
  int bid = blockIdx.x, tid = threadIdx.x;
  bool um = bid < NCH;
  int nb = um ? NBKM : NBKU;
  const int* col = um ? col_um : col_mu;
  const int* row = um ? row_um : row_mu;
  u32* binned = um ? binned_um : binned_mu;
  u32* seg = um ? seg_um : seg_mu;
  int blk = um ? bid : bid - NCH;
  int e0 = blk * CHK;
  for (int i = tid; i < nb; i += 256) cnt[i] = 0;
  if (tid == 0) s_carry = 0;
  __syncthreads();
  // phase 1: count + local rank
  #pragma unroll
  for (int k = 0; k < CHK / 1024; ++k) {
    int li = (k * 256 + tid) * 4;
    int e = e0 + li;
    if (e < NEV) {  // tail chunk has multiple-of-4 edges, int4 safe
      int4 c = *(const int4*)(col + e);
      int cc[4] = {c.x, c.y, c.z, c.w};
      #pragma unroll
      for (int q = 0; q < 4; ++q) {
        int bkt = (int)((u32)cc[q] / DT);
        rank16[li + q] = (u16)atomicAdd(&cnt[bkt], 1);
      }
    }
  }
  __syncthreads();
  // exclusive scan of cnt (in place) + emit segment table
  int lane = tid & 63, wv = tid >> 6;
  for (int c0 = 0; c0 < nb; c0 += 256) {
    int i = c0 + tid;
    int v = (i < nb) ? cnt[i] : 0;
    int s = v;
    #pragma unroll
    for (int d = 1; d < 64; d <<= 1) { int t = __shfl_up(s, d); if (lane >= d) s += t; }
    if (lane == 63) wsum[wv] = s;
    __syncthreads();
    if (tid == 0) {
      int a = 0;
      for (int j = 0; j < 4; ++j) { int t = wsum[j]; wsum[j] = a; a += t; }
    }
    __syncthreads();
    int incl = s + wsum[wv] + s_carry;
    int excl = incl - v;
    if (i < nb) {
      seg[(size_t)blk * nb + i] = ((u32)excl << 16) | (u32)v;
      cnt[i] = excl;
    }
    __syncthreads();
    if (tid == 255) s_carry = incl;
    __syncthreads();
  }
  // phase 3: place edges bucket-grouped within the chunk's own range
  #pragma unroll
  for (int k = 0; k < CHK / 1024; ++k) {
    int li = (k * 256 + tid) * 4;
    int e = e0 + li;
    if (e < NEV) {
      int4 c = *(const int4*)(col + e);
      int4 r = *(const int4*)(row + e);
      int cc[4] = {c.x, c.y, c.z, c.w}, rr[4] = {r.x, r.y, r.z, r.w};
      #pragma unroll
      for (int q = 0; q < 4; ++q) {
        u32 cv = (u32)cc[q];
        int bkt = (int)(cv / DT);
        u32 dloc = cv - (u32)bkt * DT;
        binned[e0 + cnt[bkt] + (int)rank16[li + q]] = (dloc << 24) | (u32)rr[q];
      }
    }
  }
}

// ---------------- layer-1 binned agg: block = one 56-dest bucket ----------------
// merchant (bid<NBKM): gather xub bf16 rows (32 u32), half-wave per edge.
// user: gather x_merch fp32 rows (32 f32), half-wave per edge.
__global__ __launch_bounds__(512) void k_bagg_l1(
    const u32* __restrict__ binned_um, const u32* __restrict__ seg_um,
    const u32* __restrict__ xub, float* __restrict__ agg_m,
    const u32* __restrict__ binned_mu, const u32* __restrict__ seg_mu,
    const float* __restrict__ xm, float* __restrict__ agg_u) {
  __shared__ float accA[DT * 32];
  __shared__ float accB[DT * 32];
  __shared__ int cnt[DT];
  __shared__ u32 hdrs[NCH];
  int bid = blockIdx.x, tid = threadIdx.x;
  bool mer = bid < NBKM;
  int b = mer ? bid : bid - NBKM;
  for (int i = tid; i < DT * 32; i += 512) { accA[i] = 0.f; accB[i] = 0.f; }
  for (int i = tid; i < DT; i += 512) cnt[i] = 0;
  {
    const u32* seg = mer ? seg_um : seg_mu;
    int nb = mer ? NBKM : NBKU;
    for (int i = tid; i < NCH; i += 512) hdrs[i] = seg[(size_t)i * nb + b];
  }
  __syncthreads();
  int unit = tid >> 5, f = tid & 31;  // 16 half-wave units
  if (mer) {
    for (int blk = unit; blk < NCH; blk += 16) {
      u32 h = hdrs[blk];
      const u32* bp = binned_um + blk * CHK + (int)(h >> 16);
      int len = (int)(h & 0xFFFF);
      int i = 0;
      for (; i + 4 <= len; i += 4) {
        u32 p0 = bp[i], p1 = bp[i + 1], p2 = bp[i + 2], p3 = bp[i + 3];
        u32 v0 = xub[(size_t)(p0 & 0xFFFFFF) * 32 + f];
        u32 v1 = xub[(size_t)(p1 & 0xFFFFFF) * 32 + f];
        u32 v2 = xub[(size_t)(p2 & 0xFFFFFF) * 32 + f];
        u32 v3 = xub[(size_t)(p3 & 0xFFFFFF) * 32 + f];
        int d0 = p0 >> 24, d1 = p1 >> 24, d2 = p2 >> 24, d3 = p3 >> 24;
        atomicAdd(&accA[d0 * 32 + f], bflo(v0)); atomicAdd(&accB[d0 * 32 + f], bfhi(v0));
        atomicAdd(&accA[d1 * 32 + f], bflo(v1)); atomicAdd(&accB[d1 * 32 + f], bfhi(v1));
        atomicAdd(&accA[d2 * 32 + f], bflo(v2)); atomicAdd(&accB[d2 * 32 + f], bfhi(v2));
        atomicAdd(&accA[d3 * 32 + f], bflo(v3)); atomicAdd(&accB[d3 * 32 + f], bfhi(v3));
        if (f == 0) {
          atomicAdd(&cnt[d0], 1); atomicAdd(&cnt[d1], 1);
          atomicAdd(&cnt[d2], 1); atomicAdd(&cnt[d3], 1);
        }
      }
      for (; i < len; ++i) {
        u32 p = bp[i];
        u32 v = xub[(size_t)(p & 0xFFFFFF) * 32 + f];
        int d = p >> 24;
        atomicAdd(&accA[d * 32 + f], bflo(v));
        atomicAdd(&accB[d * 32 + f], bfhi(v));
        if (f == 0) atomicAdd(&cnt[d], 1);
      }
    }
  } else {
    for (int blk = unit; blk < NCH; blk += 16) {
      u32 h = hdrs[blk];
      const u32* bp = binned_mu + blk * CHK + (int)(h >> 16);
      int len = (int)(h & 0xFFFF);
      int i = 0;
      for (; i + 4 <= len; i += 4) {
        u32 p0 = bp[i], p1 = bp[i + 1], p2 = bp[i + 2], p3 = bp[i + 3];
        float v0 = xm[(size_t)(p0 & 0xFFFFFF) * 32 + f];
        float v1 = xm[(size_t)(p1 & 0xFFFFFF) * 32 + f];
        float v2 = xm[(size_t)(p2 & 0xFFFFFF) * 32 + f];
        float v3 = xm[(size_t)(p3 & 0xFFFFFF) * 32 + f];
        int d0 = p0 >> 24, d1 = p1 >> 24, d2 = p2 >> 24, d3 = p3 >> 24;
        atomicAdd(&accA[d0 * 32 + f], v0);
        atomicAdd(&accA[d1 * 32 + f], v1);
        atomicAdd(&accA[d2 * 32 + f], v2);
        atomicAdd(&accA[d3 * 32 + f], v3);
        if (f == 0) {
          atomicAdd(&cnt[d0], 1); atomicAdd(&cnt[d1], 1);
          atomicAdd(&cnt[d2], 1); atomicAdd(&cnt[d3], 1);
        }
      }
      for (; i < len; ++i) {
        u32 p = bp[i];
        float v = xm[(size_t)(p & 0xFFFFFF) * 32 + f];
        int d = p >> 24;
        atomicAdd(&accA[d * 32 + f], v);
        if (f == 0) atomicAdd(&cnt[d], 1);
      }
    }
  }
  __syncthreads();
  if (mer) {
    for (int d = unit; d < DT; d += 16) {
      int dm = b * DT + d;
      if (dm < NMV) {
        float inv = 1.f / (float)max(cnt[d], 1);
        float2 o = make_float2(accA[d * 32 + f] * inv, accB[d * 32 + f] * inv);
        *(float2*)(agg_m + (size_t)dm * 64 + 2 * f) = o;
      }
    }
  } else {
    for (int d = unit; d < DT; d += 16) {
      int du = b * DT + d;
      if (du < NUV) {
        float inv = 1.f / (float)max(cnt[d], 1);
        agg_u[(size_t)du * 32 + f] = accA[d * 32 + f] * inv;
      }
    }
  }
}

// ---------------- layer-2 binned agg: block = one bucket, full wave per edge ----------------
__global__ __launch_bounds__(512) void k_bagg_l2(
    const u32* __restrict__ binned_um, const u32* __restrict__ seg_um,
    const u32* __restrict__ hu, u32* __restrict__ aggb_m,
    const u32* __restrict__ binned_mu, const u32* __restrict__ seg_mu,
    const u32* __restrict__ hm, u32* __restrict__ aggb_u) {
  __shared__ float accA[DT * 64];
  __shared__ float accB[DT * 64];
  __shared__ int cnt[DT];
  __shared__ u32 hdrs[NCH];
  int bid = blockIdx.x, tid = threadIdx.x;
  bool mer = bid < NBKM;
  int b = mer ? bid : bid - NBKM;
  const u32* binned = mer ? binned_um : binned_mu;
  const u32* tab = mer ? hu : hm;
  u32* outp = mer ? aggb_m : aggb_u;
  int nd = mer ? NMV : NUV;
  for (int i = tid; i < DT * 64; i += 512) { accA[i] = 0.f; accB[i] = 0.f; }
  for (int i = tid; i < DT; i += 512) cnt[i] = 0;
  {
    const u32* seg = mer ? seg_um : seg_mu;
    int nb = mer ? NBKM : NBKU;
    for (int i = tid; i < NCH; i += 512) hdrs[i] = seg[(size_t)i * nb + b];
  }
  __syncthreads();
  int wv = tid >> 6, l = tid & 63;  // 8 waves
  for (int blk = wv; blk < NCH; blk += 8) {
    u32 h = hdrs[blk];
    const u32* bp = binned + blk * CHK + (int)(h >> 16);
    int len = (int)(h & 0xFFFF);
    int i = 0;
    for (; i + 4 <= len; i += 4) {
      u32 p0 = bp[i], p1 = bp[i + 1], p2 = bp[i + 2], p3 = bp[i + 3];
      u32 v0 = tab[(size_t)(p0 & 0xFFFFFF) * 64 + l];
      u32 v1 = tab[(size_t)(p1 & 0xFFFFFF) * 64 + l];
      u32 v2 = tab[(size_t)(p2 & 0xFFFFFF) * 64 + l];
      u32 v3 = tab[(size_t)(p3 & 0xFFFFFF) * 64 + l];
      int d0 = p0 >> 24, d1 = p1 >> 24, d2 = p2 >> 24, d3 = p3 >> 24;
      atomicAdd(&accA[d0 * 64 + l], bflo(v0)); atomicAdd(&accB[d0 * 64 + l], bfhi(v0));
      atomicAdd(&accA[d1 * 64 + l], bflo(v1)); atomicAdd(&accB[d1 * 64 + l], bfhi(v1));
      atomicAdd(&accA[d2 * 64 + l], bflo(v2)); atomicAdd(&accB[d2 * 64 + l], bfhi(v2));
      atomicAdd(&accA[d3 * 64 + l], bflo(v3)); atomicAdd(&accB[d3 * 64 + l], bfhi(v3));
      if (l == 0) {
        atomicAdd(&cnt[d0], 1); atomicAdd(&cnt[d1], 1);
        atomicAdd(&cnt[d2], 1); atomicAdd(&cnt[d3], 1);
      }
    }
    for (; i < len; ++i) {
      u32 p = bp[i];
      u32 v = tab[(size_t)(p & 0xFFFFFF) * 64 + l];
      int d = p >> 24;
      atomicAdd(&accA[d * 64 + l], bflo(v));
      atomicAdd(&accB[d * 64 + l], bfhi(v));
      if (l == 0) atomicAdd(&cnt[d], 1);
    }
  }
  __syncthreads();
  for (int d = wv; d < DT; d += 8) {
    int dg = b * DT + d;
    if (dg < nd) {
      float inv = 1.f / (float)max(cnt[d], 1);
      u32 o = (u32)bf16r(accA[d * 64 + l] * inv) | ((u32)bf16r(accB[d * 64 + l] * inv) << 16);
      outp[(size_t)dg * 64 + l] = o;
    }
  }
}

// ---------------- layer-1 dual GEMM body (fp32 in, bf16 out) ----------------
template <int KA, int KB>
__device__ inline void gemm1_body(const float* __restrict__ A, const float* __restrict__ B,
                                  const float* __restrict__ Wa, const float* __restrict__ Wb,
                                  const float* __restrict__ bias, u16* __restrict__ outb,
                                  int m0, float* At, float* Bt) {
  int tid = threadIdx.x;
  {
    int m = tid & 31, kq = tid >> 5;
    const float* Ar = A + (size_t)(m0 + m) * KA;
    for (int k0 = kq * 4; k0 < KA; k0 += 32) {
      float4 v = *(const float4*)(Ar + k0);
      At[(k0 + 0) * 32 + m] = v.x; At[(k0 + 1) * 32 + m] = v.y;
      At[(k0 + 2) * 32 + m] = v.z; At[(k0 + 3) * 32 + m] = v.w;
    }
    const float* Br = B + (size_t)(m0 + m) * KB;
    for (int k0 = kq * 4; k0 < KB; k0 += 32) {
      float4 v = *(const float4*)(Br + k0);
      Bt[(k0 + 0) * 32 + m] = v.x; Bt[(k0 + 1) * 32 + m] = v.y;
      Bt[(k0 + 2) * 32 + m] = v.z; Bt[(k0 + 3) * 32 + m] = v.w;
    }
  }
  __syncthreads();
  int tx = tid & 31, ty = tid >> 5;
  float acc[4][4] = {};
  #pragma unroll 4
  for (int k = 0; k < KA; ++k) {
    float4 wv = *(const float4*)(Wa + k * 128 + tx * 4);
    float4 av = *(const float4*)(&At[k * 32 + ty * 4]);
    float am[4] = {av.x, av.y, av.z, av.w};
    float wo[4] = {wv.x, wv.y, wv.z, wv.w};
    #pragma unroll
    for (int mi = 0; mi < 4; ++mi)
      #pragma unroll
      for (int oi = 0; oi < 4; ++oi) acc[mi][oi] += am[mi] * wo[oi];
  }
  #pragma unroll 4
  for (int k = 0; k < KB; ++k) {
    float4 wv = *(const float4*)(Wb + k * 128 + tx * 4);
    float4 av = *(const float4*)(&Bt[k * 32 + ty * 4]);
    float am[4] = {av.x, av.y, av.z, av.w};
    float wo[4] = {wv.x, wv.y, wv.z, wv.w};
    #pragma unroll
    for (int mi = 0; mi < 4; ++mi)
      #pragma unroll
      for (int oi = 0; oi < 4; ++oi) acc[mi][oi] += am[mi] * wo[oi];
  }
  float4 bv = *(const float4*)(bias + tx * 4);
  float bb[4] = {bv.x, bv.y, bv.z, bv.w};
  #pragma unroll
  for (int mi = 0; mi < 4; ++mi) {
    u16x4 o;
    #pragma unroll
    for (int oi = 0; oi < 4; ++oi) {
      float v = acc[mi][oi] + bb[oi];
      v = v > 0.f ? v : 0.f;  // layer-1 relu
      o[oi] = bf16r(v);
    }
    *(u16x4*)(outb + (size_t)(m0 + ty * 4 + mi) * 128 + tx * 4) = o;
  }
}

// merged layer-1 GEMM: blocks [0,G1MB) merchant <64,32>, rest user <32,64>
__global__ __launch_bounds__(256) void k_gemm1(
    const float* __restrict__ agg_m, const float* __restrict__ x_merch,
    const float* __restrict__ W1l_um, const float* __restrict__ W1r_um,
    const float* __restrict__ b1_um, u16* __restrict__ h_m,
    const float* __restrict__ agg_u, const float* __restrict__ x_user,
    const float* __restrict__ W1l_mu, const float* __restrict__ W1r_mu,
    const float* __restrict__ b1_mu, u16* __restrict__ h_u) {
  __shared__ float At[64 * 32];
  __shared__ float Bt[64 * 32];
  int bid = blockIdx.x;
  if (bid < G1MB)
    gemm1_body<64, 32>(agg_m, x_merch, W1l_um, W1r_um, b1_um, h_m, bid * 32, At, Bt);
  else
    gemm1_body<32, 64>(agg_u, x_user, W1l_mu, W1r_mu, b1_mu, h_u, (bid - G1MB) * 32, At, Bt);
}

// ---------------- combined-weight prep: Wt = (W2 @ Wc1half)^T in bf16, plus folded biases ----------------
__global__ __launch_bounds__(256) void k_prep_comb(
    const float* __restrict__ W2l_um, const float* __restrict__ W2r_um,
    const float* __restrict__ W2l_mu, const float* __restrict__ W2r_mu,
    const float* __restrict__ b2_um, const float* __restrict__ b2_mu,
    const float* __restrict__ Wc1, const float* __restrict__ bc1,
    u16* __restrict__ WtA_u, u16* __restrict__ WtB_u,
    u16* __restrict__ WtA_m, u16* __restrict__ WtB_m,
    float* __restrict__ bias_u, float* __restrict__ bias_m) {
  int t = blockIdx.x * 256 + threadIdx.x;
  if (t < 65536) {
    int mat = t >> 14, rem = t & 16383;
    int o = rem >> 7, k = rem & 127;
    const float* W2 = mat == 0 ? W2l_mu : mat == 1 ? W2r_mu : mat == 2 ? W2l_um : W2r_um;
    const float* wc = Wc1 + (mat >= 2 ? 128 * 128 : 0) + o;
    float s = 0.f;
    #pragma unroll 4
    for (int j = 0; j < 128; ++j) s += W2[k * 128 + j] * wc[j * 128];
    u16* dst = mat == 0 ? WtA_u : mat == 1 ? WtB_u : mat == 2 ? WtA_m : WtB_m;
    dst[o * 128 + k] = bf16r(s);
  } else if (t < 65536 + 256) {
    int r = t - 65536;
    int o = r & 127;
    if (r < 128) {
      float s = 0.f;
      for (int j = 0; j < 128; ++j) s += b2_mu[j] * Wc1[j * 128 + o];
      bias_u[o] = s;
    } else {
      float s = bc1[o];  // fold bc1 into merchant-side bias
      for (int j = 0; j < 128; ++j) s += b2_um[j] * Wc1[(128 + j) * 128 + o];
      bias_m[o] = s;
    }
  }
}

// ---------------- merged layer-2 GEMM (bf16 MFMA): outb = bf16(aggb@Wtl + hb@Wtr + bias) ----------------
__global__ __launch_bounds__(256) void k_gemm2_mfma(
    const u16* __restrict__ aggb_m, const u16* __restrict__ h_m,
    const u16* __restrict__ WtA_m, const u16* __restrict__ WtB_m,
    const float* __restrict__ bias_m, u16* __restrict__ pm_b,
    const u16* __restrict__ aggb_u, const u16* __restrict__ h_u,
    const u16* __restrict__ WtA_u, const u16* __restrict__ WtB_u,
    const float* __restrict__ bias_u, u16* __restrict__ pu_b) {
  __shared__ u16 Zs[64 * 256];  // 32KB
  int tid = threadIdx.x;
  int bid = blockIdx.x;
  const u16 *aggb, *hb, *Wtl, *Wtr; const float* bias; u16* zb; int nd, r0;
  if (bid < G2MB) {
    aggb = aggb_m; hb = h_m; Wtl = WtA_m; Wtr = WtB_m; bias = bias_m; zb = pm_b;
    nd = NMV; r0 = bid * 64;
  } else {
    aggb = aggb_u; hb = h_u; Wtl = WtA_u; Wtr = WtB_u; bias = bias_u; zb = pu_b;
    nd = NUV; r0 = (bid - G2MB) * 64;
  }
  {
    int half = (tid >> 4) & 1;
    const u16* tab = half ? hb : aggb;
    #pragma unroll
    for (int it = 0; it < 8; ++it) {
      int q = tid + it * 256;
      int rl = q >> 5;
      int cc = (q & 15) ^ (rl & 7);
      int r = r0 + rl; r = r < nd ? r : nd - 1;
      const u16* src = tab + (size_t)r * 128 + cc * 8;
      u16* dst = Zs + (tid >> 6) * 512 + it * 2048;
      GLOAD_LDS16(src, dst);
    }
  }
  __syncthreads();
  int l = tid & 63, wv = tid >> 6;
  int lg = l >> 4, lr = l & 15;
  f32x4 acc[4][2];
  #pragma unroll
  for (int mt = 0; mt < 4; ++mt)
    #pragma unroll
    for (int c = 0; c < 2; ++c) acc[mt][c] = (f32x4){0.f, 0.f, 0.f, 0.f};
  #pragma unroll
  for (int cti = 0; cti < 2; ++cti) {
    int o = (wv * 2 + cti) * 16 + lr;
    const u16* wpl = Wtl + (size_t)o * 128 + lg * 8;
    const u16* wpr = Wtr + (size_t)o * 128 + lg * 8;
    s16x8 b[8];
    #pragma unroll
    for (int ks = 0; ks < 4; ++ks) b[ks] = *(const s16x8*)(wpl + ks * 32);
    #pragma unroll
    for (int ks = 0; ks < 4; ++ks) b[ks + 4] = *(const s16x8*)(wpr + ks * 32);
    #pragma unroll
    for (int mt = 0; mt < 4; ++mt) {
      int rl = mt * 16 + lr;
      int rb = rl * 512, sw = (rl & 7) << 4;
      #pragma unroll
      for (int ks = 0; ks < 8; ++ks) {
        s16x8 a = *(const s16x8*)((const char*)Zs + ((rb + ks * 64 + lg * 16) ^ sw));
        acc[mt][cti] = __builtin_amdgcn_mfma_f32_16x16x32_bf16(a, b[ks], acc[mt][cti], 0, 0, 0);
      }
    }
  }
  float bv[2];
  #pragma unroll
  for (int cti = 0; cti < 2; ++cti) bv[cti] = bias[(wv * 2 + cti) * 16 + lr];
  #pragma unroll
  for (int mt = 0; mt < 4; ++mt)
    #pragma unroll
    for (int cti = 0; cti < 2; ++cti) {
      int o = (wv * 2 + cti) * 16 + lr;
      #pragma unroll
      for (int rg = 0; rg < 4; ++rg) {
        int r = r0 + mt * 16 + lg * 4 + rg;
        if (r < nd) zb[(size_t)r * 128 + o] = bf16r(acc[mt][cti][rg] + bv[cti]);
      }
    }
}

// ---------------- edge op: out[e] = Wc2 . relu(pu[row_t[e]] + pm[col_t[e]]) + bc2 ----------------
// 16-lane groups: one edge per group (u32x4 = full 128-feat row), 4 edges/wave in flight.
__global__ __launch_bounds__(256) void k_edge(
    const u32* __restrict__ pu, const u32* __restrict__ pm,
    const int* __restrict__ row_t, const int* __restrict__ col_t,
    const float* __restrict__ Wc2, const float* __restrict__ bc2,
    float* __restrict__ out) {
  __shared__ float res[256];
  int tid = threadIdx.x, l = tid & 63, wv = tid >> 6;
  int lr = l & 15, g = l >> 4;
  float w2v[8];
  #pragma unroll
  for (int q = 0; q < 8; ++q) w2v[q] = Wc2[lr * 8 + q];
  int base = blockIdx.x * 256 + wv * 64;
  #pragma unroll 2
  for (int it = 0; it < 16; ++it) {
    int e = base + it * 4 + g;
    int ec = e < ETV ? e : ETV - 1;
    int r = row_t[ec], c = col_t[ec];
    u32x4 a = *(const u32x4*)(pu + (size_t)r * 64 + lr * 4);
    u32x4 b = *(const u32x4*)(pm + (size_t)c * 64 + lr * 4);
    float p = 0.f;
    #pragma unroll
    for (int q = 0; q < 4; ++q) {
      float h0 = bflo(a[q]) + bflo(b[q]);
      float h1 = bfhi(a[q]) + bfhi(b[q]);
      h0 = h0 > 0.f ? h0 : 0.f;
      h1 = h1 > 0.f ? h1 : 0.f;
      p += h0 * w2v[2 * q] + h1 * w2v[2 * q + 1];
    }
    p += __shfl_xor(p, 1); p += __shfl_xor(p, 2);
    p += __shfl_xor(p, 4); p += __shfl_xor(p, 8);
    if (lr == 0) res[wv * 64 + it * 4 + g] = p;
  }
  __syncthreads();
  int eo = blockIdx.x * 256 + tid;
  if (eo < ETV) out[eo] = res[tid] + bc2[0];
}

extern "C" void kernel_launch(void* const* d_in, const int* in_sizes, int n_in,
                              void* d_out, int out_size, void* d_ws, size_t ws_size,
                              hipStream_t stream) {
  const float* x_user  = (const float*)d_in[0];
  const float* x_merch = (const float*)d_in[1];
  const int* row_um = (const int*)d_in[2]; const int* col_um = (const int*)d_in[3];
  const int* row_mu = (const int*)d_in[4]; const int* col_mu = (const int*)d_in[5];
  const int* row_t  = (const int*)d_in[6]; const int* col_t  = (const int*)d_in[7];
  const float* W1l_um = (const float*)d_in[8];  const float* W1r_um = (const float*)d_in[9];  const float* b1_um = (const float*)d_in[10];
  const float* W1l_mu = (const float*)d_in[11]; const float* W1r_mu = (const float*)d_in[12]; const float* b1_mu = (const float*)d_in[13];
  const float* W2l_um = (const float*)d_in[14]; const float* W2r_um = (const float*)d_in[15]; const float* b2_um = (const float*)d_in[16];
  const float* W2l_mu = (const float*)d_in[17]; const float* W2r_mu = (const float*)d_in[18]; const float* b2_mu = (const float*)d_in[19];
  const float* Wc1 = (const float*)d_in[20]; const float* bc1 = (const float*)d_in[21];
  const float* Wc2 = (const float*)d_in[22]; const float* bc2 = (const float*)d_in[23];
  float* out = (float*)d_out;

  char* ws = (char*)d_ws;
  size_t p = 0;
  auto alloc = [&](size_t bytes) -> char* {
    char* r = ws + p;
    p = (p + bytes + 255) & ~(size_t)255;
    return r;
  };
  u32* binned_um = (u32*)alloc((size_t)NCH * CHK * 4);
  u32* binned_mu = (u32*)alloc((size_t)NCH * CHK * 4);
  u32* seg_um = (u32*)alloc((size_t)NCH * NBKM * 4);
  u32* seg_mu = (u32*)alloc((size_t)NCH * NBKU * 4);
  u32* xub = (u32*)alloc((size_t)NUV * 32 * 4);          // x_user in bf16 (packed pairs)
  float* agg_m = (float*)alloc((size_t)NMV * 64 * 4);    // layer1 merchant agg (fp32, 64 feats)
  float* agg_u = (float*)alloc((size_t)NUV * 32 * 4);    // layer1 user agg (fp32, 32 feats)
  u16* h_m   = (u16*)alloc((size_t)NMV * 128 * 2);       // bf16 hidden
  u16* h_u   = (u16*)alloc((size_t)NUV * 128 * 2);
  u16* aggb_m = (u16*)alloc((size_t)NMV * 128 * 2);      // layer2 agg (bf16)
  u16* aggb_u = (u16*)alloc((size_t)NUV * 128 * 2);
  u16* pm_b  = (u16*)alloc((size_t)NMV * 128 * 2);       // folded classifier projections (bf16)
  u16* pu_b  = (u16*)alloc((size_t)NUV * 128 * 2);
  u16* WtA_u = (u16*)alloc((size_t)128 * 128 * 2);
  u16* WtB_u = (u16*)alloc((size_t)128 * 128 * 2);
  u16* WtA_m = (u16*)alloc((size_t)128 * 128 * 2);
  u16* WtB_m = (u16*)alloc((size_t)128 * 128 * 2);
  float* bias_u = (float*)alloc(128 * 4);
  float* bias_m = (float*)alloc(128 * 4);
  if (p > ws_size) return;  // workspace too small: fail loudly via absmax

  k_prep_comb<<<257, 256, 0, stream>>>(W2l_um, W2r_um, W2l_mu, W2r_mu, b2_um, b2_mu, Wc1, bc1,
                                       WtA_u, WtB_u, WtA_m, WtB_m, bias_u, bias_m);
  k_xub<<<1024, 256, 0, stream>>>(x_user, xub, NUV * 64 / 8);
  // bucket binning (replaces CSR build; zero global atomics)
  k_bin<<<2 * NCH, 256, 0, stream>>>(col_um, row_um, binned_um, seg_um,
                                     col_mu, row_mu, binned_mu, seg_mu);
  // layer 1: binned agg -> dual GEMM (bf16 h out)
  k_bagg_l1<<<NBKM + NBKU, 512, 0, stream>>>(binned_um, seg_um, xub, agg_m,
                                             binned_mu, seg_mu, x_merch, agg_u);
  k_gemm1<<<G1MB + NUV / 32, 256, 0, stream>>>(agg_m, x_merch, W1l_um, W1r_um, b1_um, h_m,
                                               agg_u, x_user, W1l_mu, W1r_mu, b1_mu, h_u);
  // layer 2: binned agg (bf16 gather) -> MFMA GEMM with folded classifier weights
  k_bagg_l2<<<NBKM + NBKU, 512, 0, stream>>>(binned_um, seg_um, (const u32*)h_u, (u32*)aggb_m,
                                             binned_mu, seg_mu, (const u32*)h_m, (u32*)aggb_u);
  k_gemm2_mfma<<<G2MB + (NUV + 63) / 64, 256, 0, stream>>>(
      aggb_m, h_m, WtA_m, WtB_m, bias_m, pm_b,
      aggb_u, h_u, WtA_u, WtB_u, bias_u, pu_b);
  // edge classifier: gather + relu + dot
  k_edge<<<(ETV + 255) / 256, 256, 0, stream>>>((const u32*)pu_b, (const u32*)pm_b,
                                                row_t, col_t, Wc2, bc2, out);
}

// Round 9
// 423.499 us; speedup vs baseline: 4.9367x; 4.9367x over previous
//
#include <hip/hip_runtime.h>
#include <hip/hip_bf16.h>

// Hetero-SAGE: replica-privatized CSR build + merged latency-bound launches +
// bf16-MFMA GEMMs with folded classifier (layer-2 linear => z@Wc1 folded).
#define NUV 100000
#define NMV 20000
#define NEV 1000000
#define ETV 500000

#define REP 8                     // histogram replicas (contention /8)
#define SCH2 16384                // scan elements per block (1024 thr x 16)
#define NCA 10                    // ceil(8*NMV/SCH2)
#define NCB 49                    // ceil(8*NUV/SCH2)
#define HGRID 1954                // ceil(2*NEV/4/256)
#define MBLK 5000                 // merchant agg blocks (NMV/4)
#define G1MB 625                  // merchant layer-1 gemm blocks (NMV/32)
#define G2MB 313                  // merchant layer-2 gemm blocks (ceil(NMV/64))

typedef unsigned short u16;
typedef unsigned int u32;
typedef __attribute__((ext_vector_type(8))) short s16x8;
typedef __attribute__((ext_vector_type(4))) float f32x4;
typedef __attribute__((ext_vector_type(4))) unsigned short u16x4;
typedef __attribute__((ext_vector_type(4))) unsigned int u32x4;

__device__ inline u16 bf16r(float f) {  // RTNE float->bf16
  u32 b = __builtin_bit_cast(u32, f);
  u32 r = b + 0x7fffu + ((b >> 16) & 1u);
  return (u16)(r >> 16);
}
__device__ inline float bflo(u32 v) { return __builtin_bit_cast(float, v << 16); }
__device__ inline float bfhi(u32 v) { return __builtin_bit_cast(float, v & 0xffff0000u); }

#define GLOAD_LDS16(src, dst) \
  __builtin_amdgcn_global_load_lds((const __attribute__((address_space(1))) void*)(src), \
                                   (__attribute__((address_space(3))) void*)(dst), 16, 0, 0)

// ---------------- CSR: replica-privatized histogram + rank ----------------
// cnt layout: cnt[c*REP + r], r = blockIdx & 7. rank = local rank within (c,r).
__global__ __launch_bounds__(256) void k_hist_rank_p(
    const int* __restrict__ col_um, int* __restrict__ cnt_um, int* __restrict__ rank_um,
    const int* __restrict__ col_mu, int* __restrict__ cnt_mu, int* __restrict__ rank_mu) {
  int bid = blockIdx.x;
  int i = (bid * 256 + threadIdx.x) * 4;
  if (i >= 2 * NEV) return;
  int r = bid & (REP - 1);
  bool um = i < NEV;
  const int* col = um ? col_um : col_mu;
  int* cnt = um ? cnt_um : cnt_mu;
  int* rank = um ? rank_um : rank_mu;
  int lo = um ? i : i - NEV;
  int4 c = *(const int4*)(col + lo);
  int4 k;
  k.x = atomicAdd(&cnt[c.x * REP + r], 1);
  k.y = atomicAdd(&cnt[c.y * REP + r], 1);
  k.z = atomicAdd(&cnt[c.z * REP + r], 1);
  k.w = atomicAdd(&cnt[c.w * REP + r], 1);
  *(int4*)(rank + lo) = k;
}

// ---- 3-phase scan over (dest,replica)-ordered count arrays ----
__global__ __launch_bounds__(1024) void k_scan_p1(const int* __restrict__ cntA, int nA,
                                                  const int* __restrict__ cntB, int nB,
                                                  int* __restrict__ bsum) {
  int b = blockIdx.x;
  const int* arr; int n; int c;
  if (b < NCA) { arr = cntA; n = nA; c = b; }
  else         { arr = cntB; n = nB; c = b - NCA; }
  __shared__ int wsum[16];
  int tid = threadIdx.x, lane = tid & 63, w = tid >> 6;
  int base = c * SCH2 + tid * 16;
  int s = 0;
  #pragma unroll
  for (int q = 0; q < 16; q += 4) {
    if (base + q + 3 < n) {
      int4 v = *(const int4*)(arr + base + q);
      s += v.x + v.y + v.z + v.w;
    } else {
      #pragma unroll
      for (int j = 0; j < 4; ++j) s += (base + q + j < n) ? arr[base + q + j] : 0;
    }
  }
  #pragma unroll
  for (int d = 1; d < 64; d <<= 1) s += __shfl_xor(s, d);
  if (lane == 0) wsum[w] = s;
  __syncthreads();
  if (tid == 0) {
    int tot = 0;
    #pragma unroll
    for (int j = 0; j < 16; ++j) tot += wsum[j];
    bsum[b] = tot;
  }
}

__global__ __launch_bounds__(128) void k_scan_p2(int* __restrict__ bsum,
                                                 int* __restrict__ off_um, int* __restrict__ off_mu) {
  int tid = threadIdx.x;
  int wv = tid >> 6, lane = tid & 63;
  if (wv == 0) {
    int v = (lane < NCA) ? bsum[lane] : 0;
    int s = v;
    #pragma unroll
    for (int d = 1; d < 64; d <<= 1) { int t = __shfl_up(s, d); if (lane >= d) s += t; }
    if (lane < NCA) bsum[lane] = s - v;
  } else {
    int v = (lane < NCB) ? bsum[NCA + lane] : 0;
    int s = v;
    #pragma unroll
    for (int d = 1; d < 64; d <<= 1) { int t = __shfl_up(s, d); if (lane >= d) s += t; }
    if (lane < NCB) bsum[NCA + lane] = s - v;
  }
  if (tid == 0) { off_um[NMV] = NEV; off_mu[NUV] = NEV; }
}

// in-place: counts -> exclusive base; also emits off[c] = base[c*REP]
__global__ __launch_bounds__(1024) void k_scan_p3(int* __restrict__ cntA, int nA, int* __restrict__ offA,
                                                  int* __restrict__ cntB, int nB, int* __restrict__ offB,
                                                  const int* __restrict__ bsum) {
  int b = blockIdx.x;
  int* arr; int n; int c; int* offo;
  if (b < NCA) { arr = cntA; n = nA; c = b; offo = offA; }
  else         { arr = cntB; n = nB; c = b - NCA; offo = offB; }
  int carry = bsum[b];
  __shared__ int wsum[16];
  int tid = threadIdx.x, lane = tid & 63, w = tid >> 6;
  int base = c * SCH2 + tid * 16;
  int v[16];
  #pragma unroll
  for (int q = 0; q < 16; q += 4) {
    if (base + q + 3 < n) {
      int4 t = *(const int4*)(arr + base + q);
      v[q] = t.x; v[q + 1] = t.y; v[q + 2] = t.z; v[q + 3] = t.w;
    } else {
      #pragma unroll
      for (int j = 0; j < 4; ++j) v[q + j] = (base + q + j < n) ? arr[base + q + j] : 0;
    }
  }
  int tsum = 0;
  #pragma unroll
  for (int q = 0; q < 16; ++q) tsum += v[q];
  int sc = tsum;
  #pragma unroll
  for (int d = 1; d < 64; d <<= 1) { int t = __shfl_up(sc, d); if (lane >= d) sc += t; }
  if (lane == 63) wsum[w] = sc;
  __syncthreads();
  if (w == 0 && lane < 16) {
    int ws_ = wsum[lane];
    #pragma unroll
    for (int d = 1; d < 16; d <<= 1) { int t = __shfl_up(ws_, d, 16); if (lane >= d) ws_ += t; }
    wsum[lane] = ws_;
  }
  __syncthreads();
  int run = sc - tsum + (w ? wsum[w - 1] : 0) + carry;
  #pragma unroll
  for (int q = 0; q < 16; ++q) {
    int idx = base + q;
    if (idx < n) {
      arr[idx] = run;
      if ((idx & (REP - 1)) == 0) offo[idx / REP] = run;
      run += v[q];
    }
  }
}

// ---------------- atomic-free scatter (replica base + precomputed rank) ----------------
__global__ __launch_bounds__(256) void k_scatter2(
    const int* __restrict__ col_um, const int* __restrict__ row_um,
    const int* __restrict__ rank_um, const int* __restrict__ base_um, int* __restrict__ srow_um,
    const int* __restrict__ col_mu, const int* __restrict__ row_mu,
    const int* __restrict__ rank_mu, const int* __restrict__ base_mu, int* __restrict__ srow_mu) {
  int bid = blockIdx.x;
  int i = (bid * 256 + threadIdx.x) * 4;
  if (i >= 2 * NEV) return;
  int r = bid & (REP - 1);
  bool um = i < NEV;
  const int* col = um ? col_um : col_mu;
  const int* row = um ? row_um : row_mu;
  const int* rank = um ? rank_um : rank_mu;
  const int* basep = um ? base_um : base_mu;
  int* srow = um ? srow_um : srow_mu;
  int lo = um ? i : i - NEV;
  int4 c = *(const int4*)(col + lo);
  int4 rr = *(const int4*)(row + lo);
  int4 k = *(const int4*)(rank + lo);
  srow[basep[c.x * REP + r] + k.x] = rr.x;
  srow[basep[c.y * REP + r] + k.y] = rr.y;
  srow[basep[c.z * REP + r] + k.z] = rr.z;
  srow[basep[c.w * REP + r] + k.w] = rr.w;
}

// ---------------- x_user -> bf16 (halves layer-1 gather traffic) ----------------
__global__ __launch_bounds__(256) void k_xub(const float* __restrict__ in, u32* __restrict__ o, int n8) {
  int stride = gridDim.x * 256;
  for (int i = blockIdx.x * 256 + threadIdx.x; i < n8; i += stride) {
    float4 a = *(const float4*)(in + (size_t)i * 8);
    float4 b = *(const float4*)(in + (size_t)i * 8 + 4);
    u32x4 r;
    r[0] = (u32)bf16r(a.x) | ((u32)bf16r(a.y) << 16);
    r[1] = (u32)bf16r(a.z) | ((u32)bf16r(a.w) << 16);
    r[2] = (u32)bf16r(b.x) | ((u32)bf16r(b.y) << 16);
    r[3] = (u32)bf16r(b.z) | ((u32)bf16r(b.w) << 16);
    *(u32x4*)(o + (size_t)i * 4) = r;
  }
}

// ---------------- merged layer-1 segment-mean ----------------
__global__ __launch_bounds__(256) void k_agg_l1(
    const int* __restrict__ off_um, const int* __restrict__ srow_um,
    const u32* __restrict__ xub, float* __restrict__ agg_m,
    const int* __restrict__ off_mu, const int* __restrict__ srow_mu,
    const float* __restrict__ xm, float* __restrict__ agg_u) {
  int bid = blockIdx.x, tid = threadIdx.x;
  int lane = tid & 63;
  int half = lane >> 5, f = lane & 31;
  if (bid < MBLK) {
    int wid = (bid * 256 + tid) >> 6;
    int s = off_um[wid], t = off_um[wid + 1];
    float ax[4] = {}, ay[4] = {};
    int j = s + half;
    for (; j + 8 <= t; j += 8) {
      int r[4];
      #pragma unroll
      for (int q = 0; q < 4; ++q) r[q] = srow_um[j + 2 * q];
      u32 v[4];
      #pragma unroll
      for (int q = 0; q < 4; ++q) v[q] = xub[(size_t)r[q] * 32 + f];
      #pragma unroll
      for (int q = 0; q < 4; ++q) { ax[q] += bflo(v[q]); ay[q] += bfhi(v[q]); }
    }
    for (; j < t; j += 2) {
      u32 v = xub[(size_t)srow_um[j] * 32 + f];
      ax[0] += bflo(v); ay[0] += bfhi(v);
    }
    float sx = (ax[0] + ax[1]) + (ax[2] + ax[3]);
    float sy = (ay[0] + ay[1]) + (ay[2] + ay[3]);
    sx += __shfl_xor(sx, 32);
    sy += __shfl_xor(sy, 32);
    if (half == 0) {
      float inv = 1.f / (float)max(t - s, 1);
      ((float2*)agg_m)[(size_t)wid * 32 + f] = make_float2(sx * inv, sy * inv);
    }
  } else {
    int wid = ((bid - MBLK) * 256 + tid) >> 6;
    int s = off_mu[wid], t = off_mu[wid + 1];
    float a[4] = {};
    int j = s + half;
    for (; j + 8 <= t; j += 8) {
      int r[4];
      #pragma unroll
      for (int q = 0; q < 4; ++q) r[q] = srow_mu[j + 2 * q];
      #pragma unroll
      for (int q = 0; q < 4; ++q) a[q] += xm[(size_t)r[q] * 32 + f];
    }
    for (; j < t; j += 2) a[0] += xm[(size_t)srow_mu[j] * 32 + f];
    float acc = (a[0] + a[1]) + (a[2] + a[3]);
    acc += __shfl_xor(acc, 32);
    if (half == 0) agg_u[(size_t)wid * 32 + f] = acc / (float)max(t - s, 1);
  }
}

// ---------------- merged layer-2 segment-mean (bf16 gather, fp32 accum, bf16 out) ----------------
__global__ __launch_bounds__(256) void k_agg_l2(
    const int* __restrict__ off_um, const int* __restrict__ srow_um,
    const u16* __restrict__ h_u, u16* __restrict__ aggb_m,
    const int* __restrict__ off_mu, const int* __restrict__ srow_mu,
    const u16* __restrict__ h_m, u16* __restrict__ aggb_u) {
  int bid = blockIdx.x, tid = threadIdx.x;
  int lane = tid & 63;
  const int* off; const int* srow; const u32* x; u32* ag; int wid;
  if (bid < MBLK) {
    off = off_um; srow = srow_um; x = (const u32*)h_u; ag = (u32*)aggb_m;
    wid = (bid * 256 + tid) >> 6;
  } else {
    off = off_mu; srow = srow_mu; x = (const u32*)h_m; ag = (u32*)aggb_u;
    wid = ((bid - MBLK) * 256 + tid) >> 6;
  }
  int s = off[wid], t = off[wid + 1];
  float ax[4] = {}, ay[4] = {};
  int j = s;
  for (; j + 8 <= t; j += 8) {
    int r[8];
    #pragma unroll
    for (int q = 0; q < 8; ++q) r[q] = srow[j + q];
    u32 v[8];
    #pragma unroll
    for (int q = 0; q < 8; ++q) v[q] = x[(size_t)r[q] * 64 + lane];
    #pragma unroll
    for (int q = 0; q < 8; ++q) { ax[q & 3] += bflo(v[q]); ay[q & 3] += bfhi(v[q]); }
  }
  for (; j < t; ++j) {
    u32 v = x[(size_t)srow[j] * 64 + lane];
    ax[0] += bflo(v); ay[0] += bfhi(v);
  }
  float sx = (ax[0] + ax[1]) + (ax[2] + ax[3]);
  float sy = (ay[0] + ay[1]) + (ay[2] + ay[3]);
  float inv = 1.f / (float)max(t - s, 1);
  ag[(size_t)wid * 64 + lane] = (u32)bf16r(sx * inv) | ((u32)bf16r(sy * inv) << 16);
}

// ---------------- layer-1 dual GEMM body (fp32 in, bf16 out) ----------------
template <int KA, int KB>
__device__ inline void gemm1_body(const float* __restrict__ A, const float* __restrict__ B,
                                  const float* __restrict__ Wa, const float* __restrict__ Wb,
                                  const float* __restrict__ bias, u16* __restrict__ outb,
                                  int m0, float* At, float* Bt) {
  int tid = threadIdx.x;
  {
    int m = tid & 31, kq = tid >> 5;
    const float* Ar = A + (size_t)(m0 + m) * KA;
    for (int k0 = kq * 4; k0 < KA; k0 += 32) {
      float4 v = *(const float4*)(Ar + k0);
      At[(k0 + 0) * 32 + m] = v.x; At[(k0 + 1) * 32 + m] = v.y;
      At[(k0 + 2) * 32 + m] = v.z; At[(k0 + 3) * 32 + m] = v.w;
    }
    const float* Br = B + (size_t)(m0 + m) * KB;
    for (int k0 = kq * 4; k0 < KB; k0 += 32) {
      float4 v = *(const float4*)(Br + k0);
      Bt[(k0 + 0) * 32 + m] = v.x; Bt[(k0 + 1) * 32 + m] = v.y;
      Bt[(k0 + 2) * 32 + m] = v.z; Bt[(k0 + 3) * 32 + m] = v.w;
    }
  }
  __syncthreads();
  int tx = tid & 31, ty = tid >> 5;
  float acc[4][4] = {};
  #pragma unroll 4
  for (int k = 0; k < KA; ++k) {
    float4 wv = *(const float4*)(Wa + k * 128 + tx * 4);
    float4 av = *(const float4*)(&At[k * 32 + ty * 4]);
    float am[4] = {av.x, av.y, av.z, av.w};
    float wo[4] = {wv.x, wv.y, wv.z, wv.w};
    #pragma unroll
    for (int mi = 0; mi < 4; ++mi)
      #pragma unroll
      for (int oi = 0; oi < 4; ++oi) acc[mi][oi] += am[mi] * wo[oi];
  }
  #pragma unroll 4
  for (int k = 0; k < KB; ++k) {
    float4 wv = *(const float4*)(Wb + k * 128 + tx * 4);
    float4 av = *(const float4*)(&Bt[k * 32 + ty * 4]);
    float am[4] = {av.x, av.y, av.z, av.w};
    float wo[4] = {wv.x, wv.y, wv.z, wv.w};
    #pragma unroll
    for (int mi = 0; mi < 4; ++mi)
      #pragma unroll
      for (int oi = 0; oi < 4; ++oi) acc[mi][oi] += am[mi] * wo[oi];
  }
  float4 bv = *(const float4*)(bias + tx * 4);
  float bb[4] = {bv.x, bv.y, bv.z, bv.w};
  #pragma unroll
  for (int mi = 0; mi < 4; ++mi) {
    u16x4 o;
    #pragma unroll
    for (int oi = 0; oi < 4; ++oi) {
      float v = acc[mi][oi] + bb[oi];
      v = v > 0.f ? v : 0.f;  // layer-1 relu
      o[oi] = bf16r(v);
    }
    *(u16x4*)(outb + (size_t)(m0 + ty * 4 + mi) * 128 + tx * 4) = o;
  }
}

// merged layer-1 GEMM: blocks [0,G1MB) merchant <64,32>, rest user <32,64>
__global__ __launch_bounds__(256) void k_gemm1(
    const float* __restrict__ agg_m, const float* __restrict__ x_merch,
    const float* __restrict__ W1l_um, const float* __restrict__ W1r_um,
    const float* __restrict__ b1_um, u16* __restrict__ h_m,
    const float* __restrict__ agg_u, const float* __restrict__ x_user,
    const float* __restrict__ W1l_mu, const float* __restrict__ W1r_mu,
    const float* __restrict__ b1_mu, u16* __restrict__ h_u) {
  __shared__ float At[64 * 32];
  __shared__ float Bt[64 * 32];
  int bid = blockIdx.x;
  if (bid < G1MB)
    gemm1_body<64, 32>(agg_m, x_merch, W1l_um, W1r_um, b1_um, h_m, bid * 32, At, Bt);
  else
    gemm1_body<32, 64>(agg_u, x_user, W1l_mu, W1r_mu, b1_mu, h_u, (bid - G1MB) * 32, At, Bt);
}

// ---------------- combined-weight prep: Wt = (W2 @ Wc1half)^T in bf16, plus folded biases ----------------
__global__ __launch_bounds__(256) void k_prep_comb(
    const float* __restrict__ W2l_um, const float* __restrict__ W2r_um,
    const float* __restrict__ W2l_mu, const float* __restrict__ W2r_mu,
    const float* __restrict__ b2_um, const float* __restrict__ b2_mu,
    const float* __restrict__ Wc1, const float* __restrict__ bc1,
    u16* __restrict__ WtA_u, u16* __restrict__ WtB_u,
    u16* __restrict__ WtA_m, u16* __restrict__ WtB_m,
    float* __restrict__ bias_u, float* __restrict__ bias_m) {
  int t = blockIdx.x * 256 + threadIdx.x;
  if (t < 65536) {
    int mat = t >> 14, rem = t & 16383;
    int o = rem >> 7, k = rem & 127;
    const float* W2 = mat == 0 ? W2l_mu : mat == 1 ? W2r_mu : mat == 2 ? W2l_um : W2r_um;
    const float* wc = Wc1 + (mat >= 2 ? 128 * 128 : 0) + o;
    float s = 0.f;
    #pragma unroll 4
    for (int j = 0; j < 128; ++j) s += W2[k * 128 + j] * wc[j * 128];
    u16* dst = mat == 0 ? WtA_u : mat == 1 ? WtB_u : mat == 2 ? WtA_m : WtB_m;
    dst[o * 128 + k] = bf16r(s);
  } else if (t < 65536 + 256) {
    int r = t - 65536;
    int o = r & 127;
    if (r < 128) {
      float s = 0.f;
      for (int j = 0; j < 128; ++j) s += b2_mu[j] * Wc1[j * 128 + o];
      bias_u[o] = s;
    } else {
      float s = bc1[o];  // fold bc1 into merchant-side bias
      for (int j = 0; j < 128; ++j) s += b2_um[j] * Wc1[(128 + j) * 128 + o];
      bias_m[o] = s;
    }
  }
}

// ---------------- merged layer-2 GEMM (bf16 MFMA): outb = bf16(aggb@Wtl + hb@Wtr + bias) ----------------
__global__ __launch_bounds__(256) void k_gemm2_mfma(
    const u16* __restrict__ aggb_m, const u16* __restrict__ h_m,
    const u16* __restrict__ WtA_m, const u16* __restrict__ WtB_m,
    const float* __restrict__ bias_m, u16* __restrict__ pm_b,
    const u16* __restrict__ aggb_u, const u16* __restrict__ h_u,
    const u16* __restrict__ WtA_u, const u16* __restrict__ WtB_u,
    const float* __restrict__ bias_u, u16* __restrict__ pu_b) {
  __shared__ u16 Zs[64 * 256];  // 32KB
  int tid = threadIdx.x;
  int bid = blockIdx.x;
  const u16 *aggb, *hb, *Wtl, *Wtr; const float* bias; u16* zb; int nd, r0;
  if (bid < G2MB) {
    aggb = aggb_m; hb = h_m; Wtl = WtA_m; Wtr = WtB_m; bias = bias_m; zb = pm_b;
    nd = NMV; r0 = bid * 64;
  } else {
    aggb = aggb_u; hb = h_u; Wtl = WtA_u; Wtr = WtB_u; bias = bias_u; zb = pu_b;
    nd = NUV; r0 = (bid - G2MB) * 64;
  }
  {
    int half = (tid >> 4) & 1;
    const u16* tab = half ? hb : aggb;
    #pragma unroll
    for (int it = 0; it < 8; ++it) {
      int q = tid + it * 256;
      int rl = q >> 5;
      int cc = (q & 15) ^ (rl & 7);
      int r = r0 + rl; r = r < nd ? r : nd - 1;
      const u16* src = tab + (size_t)r * 128 + cc * 8;
      u16* dst = Zs + (tid >> 6) * 512 + it * 2048;
      GLOAD_LDS16(src, dst);
    }
  }
  __syncthreads();
  int l = tid & 63, wv = tid >> 6;
  int lg = l >> 4, lr = l & 15;
  f32x4 acc[4][2];
  #pragma unroll
  for (int mt = 0; mt < 4; ++mt)
    #pragma unroll
    for (int c = 0; c < 2; ++c) acc[mt][c] = (f32x4){0.f, 0.f, 0.f, 0.f};
  #pragma unroll
  for (int cti = 0; cti < 2; ++cti) {
    int o = (wv * 2 + cti) * 16 + lr;
    const u16* wpl = Wtl + (size_t)o * 128 + lg * 8;
    const u16* wpr = Wtr + (size_t)o * 128 + lg * 8;
    s16x8 b[8];
    #pragma unroll
    for (int ks = 0; ks < 4; ++ks) b[ks] = *(const s16x8*)(wpl + ks * 32);
    #pragma unroll
    for (int ks = 0; ks < 4; ++ks) b[ks + 4] = *(const s16x8*)(wpr + ks * 32);
    #pragma unroll
    for (int mt = 0; mt < 4; ++mt) {
      int rl = mt * 16 + lr;
      int rb = rl * 512, sw = (rl & 7) << 4;
      #pragma unroll
      for (int ks = 0; ks < 8; ++ks) {
        s16x8 a = *(const s16x8*)((const char*)Zs + ((rb + ks * 64 + lg * 16) ^ sw));
        acc[mt][cti] = __builtin_amdgcn_mfma_f32_16x16x32_bf16(a, b[ks], acc[mt][cti], 0, 0, 0);
      }
    }
  }
  float bv[2];
  #pragma unroll
  for (int cti = 0; cti < 2; ++cti) bv[cti] = bias[(wv * 2 + cti) * 16 + lr];
  #pragma unroll
  for (int mt = 0; mt < 4; ++mt)
    #pragma unroll
    for (int cti = 0; cti < 2; ++cti) {
      int o = (wv * 2 + cti) * 16 + lr;
      #pragma unroll
      for (int rg = 0; rg < 4; ++rg) {
        int r = r0 + mt * 16 + lg * 4 + rg;
        if (r < nd) zb[(size_t)r * 128 + o] = bf16r(acc[mt][cti][rg] + bv[cti]);
      }
    }
}

// ---------------- edge op: out[e] = Wc2 . relu(pu[row_t[e]] + pm[col_t[e]]) + bc2 ----------------
__global__ __launch_bounds__(256) void k_edge(
    const u32* __restrict__ pu, const u32* __restrict__ pm,
    const int* __restrict__ row_t, const int* __restrict__ col_t,
    const float* __restrict__ Wc2, const float* __restrict__ bc2,
    float* __restrict__ out) {
  __shared__ float res[256];
  int tid = threadIdx.x, l = tid & 63, wv = tid >> 6;
  int lr = l & 15, g = l >> 4;
  float w2v[8];
  #pragma unroll
  for (int q = 0; q < 8; ++q) w2v[q] = Wc2[lr * 8 + q];
  int base = blockIdx.x * 256 + wv * 64;
  #pragma unroll 2
  for (int it = 0; it < 16; ++it) {
    int e = base + it * 4 + g;
    int ec = e < ETV ? e : ETV - 1;
    int r = row_t[ec], c = col_t[ec];
    u32x4 a = *(const u32x4*)(pu + (size_t)r * 64 + lr * 4);
    u32x4 b = *(const u32x4*)(pm + (size_t)c * 64 + lr * 4);
    float p = 0.f;
    #pragma unroll
    for (int q = 0; q < 4; ++q) {
      float h0 = bflo(a[q]) + bflo(b[q]);
      float h1 = bfhi(a[q]) + bfhi(b[q]);
      h0 = h0 > 0.f ? h0 : 0.f;
      h1 = h1 > 0.f ? h1 : 0.f;
      p += h0 * w2v[2 * q] + h1 * w2v[2 * q + 1];
    }
    p += __shfl_xor(p, 1); p += __shfl_xor(p, 2);
    p += __shfl_xor(p, 4); p += __shfl_xor(p, 8);
    if (lr == 0) res[wv * 64 + it * 4 + g] = p;
  }
  __syncthreads();
  int eo = blockIdx.x * 256 + tid;
  if (eo < ETV) out[eo] = res[tid] + bc2[0];
}

extern "C" void kernel_launch(void* const* d_in, const int* in_sizes, int n_in,
                              void* d_out, int out_size, void* d_ws, size_t ws_size,
                              hipStream_t stream) {
  const float* x_user  = (const float*)d_in[0];
  const float* x_merch = (const float*)d_in[1];
  const int* row_um = (const int*)d_in[2]; const int* col_um = (const int*)d_in[3];
  const int* row_mu = (const int*)d_in[4]; const int* col_mu = (const int*)d_in[5];
  const int* row_t  = (const int*)d_in[6]; const int* col_t  = (const int*)d_in[7];
  const float* W1l_um = (const float*)d_in[8];  const float* W1r_um = (const float*)d_in[9];  const float* b1_um = (const float*)d_in[10];
  const float* W1l_mu = (const float*)d_in[11]; const float* W1r_mu = (const float*)d_in[12]; const float* b1_mu = (const float*)d_in[13];
  const float* W2l_um = (const float*)d_in[14]; const float* W2r_um = (const float*)d_in[15]; const float* b2_um = (const float*)d_in[16];
  const float* W2l_mu = (const float*)d_in[17]; const float* W2r_mu = (const float*)d_in[18]; const float* b2_mu = (const float*)d_in[19];
  const float* Wc1 = (const float*)d_in[20]; const float* bc1 = (const float*)d_in[21];
  const float* Wc2 = (const float*)d_in[22]; const float* bc2 = (const float*)d_in[23];
  float* out = (float*)d_out;

  char* ws = (char*)d_ws;
  size_t p = 0;
  auto alloc = [&](size_t bytes) -> char* {
    char* r = ws + p;
    p = (p + bytes + 255) & ~(size_t)255;
    return r;
  };
  int* cnt_um = (int*)alloc((size_t)NMV * REP * 4);      // privatized counts -> bases
  int* cnt_mu = (int*)alloc((size_t)NUV * REP * 4);
  size_t zero_end = p;
  int* off_um = (int*)alloc((size_t)(NMV + 1) * 4);
  int* off_mu = (int*)alloc((size_t)(NUV + 1) * 4);
  int* bsum = (int*)alloc((size_t)(NCA + NCB) * 4);
  int* rank_um = (int*)alloc((size_t)NEV * 4);
  int* rank_mu = (int*)alloc((size_t)NEV * 4);
  int* srow_um = (int*)alloc((size_t)NEV * 4);
  int* srow_mu = (int*)alloc((size_t)NEV * 4);
  u32* xub = (u32*)alloc((size_t)NUV * 32 * 4);          // x_user in bf16 (packed pairs)
  float* agg_m = (float*)alloc((size_t)NMV * 64 * 4);    // layer1 merchant agg (fp32, 64 feats)
  float* agg_u = (float*)alloc((size_t)NUV * 32 * 4);    // layer1 user agg (fp32, 32 feats)
  u16* h_m   = (u16*)alloc((size_t)NMV * 128 * 2);       // bf16 hidden
  u16* h_u   = (u16*)alloc((size_t)NUV * 128 * 2);
  u16* aggb_m = (u16*)alloc((size_t)NMV * 128 * 2);      // layer2 agg (bf16)
  u16* aggb_u = (u16*)alloc((size_t)NUV * 128 * 2);
  u16* pm_b  = (u16*)alloc((size_t)NMV * 128 * 2);       // folded classifier projections (bf16)
  u16* pu_b  = (u16*)alloc((size_t)NUV * 128 * 2);
  u16* WtA_u = (u16*)alloc((size_t)128 * 128 * 2);
  u16* WtB_u = (u16*)alloc((size_t)128 * 128 * 2);
  u16* WtA_m = (u16*)alloc((size_t)128 * 128 * 2);
  u16* WtB_m = (u16*)alloc((size_t)128 * 128 * 2);
  float* bias_u = (float*)alloc(128 * 4);
  float* bias_m = (float*)alloc(128 * 4);
  if (p > ws_size) return;  // workspace too small: fail loudly via absmax

  hipMemsetAsync(d_ws, 0, zero_end, stream);
  k_prep_comb<<<257, 256, 0, stream>>>(W2l_um, W2r_um, W2l_mu, W2r_mu, b2_um, b2_mu, Wc1, bc1,
                                       WtA_u, WtB_u, WtA_m, WtB_m, bias_u, bias_m);
  k_xub<<<1024, 256, 0, stream>>>(x_user, xub, NUV * 64 / 8);
  // CSR build: replica-privatized hist+rank, 3-phase scan, atomic-free scatter
  k_hist_rank_p<<<HGRID, 256, 0, stream>>>(col_um, cnt_um, rank_um, col_mu, cnt_mu, rank_mu);
  k_scan_p1<<<NCA + NCB, 1024, 0, stream>>>(cnt_um, NMV * REP, cnt_mu, NUV * REP, bsum);
  k_scan_p2<<<1, 128, 0, stream>>>(bsum, off_um, off_mu);
  k_scan_p3<<<NCA + NCB, 1024, 0, stream>>>(cnt_um, NMV * REP, off_um,
                                            cnt_mu, NUV * REP, off_mu, bsum);
  k_scatter2<<<HGRID, 256, 0, stream>>>(col_um, row_um, rank_um, cnt_um, srow_um,
                                        col_mu, row_mu, rank_mu, cnt_mu, srow_mu);
  // layer 1 (merged aggs, merged dual GEMMs; bf16 h out)
  k_agg_l1<<<MBLK + NUV / 4, 256, 0, stream>>>(off_um, srow_um, xub, agg_m,
                                               off_mu, srow_mu, x_merch, agg_u);
  k_gemm1<<<G1MB + NUV / 32, 256, 0, stream>>>(agg_m, x_merch, W1l_um, W1r_um, b1_um, h_m,
                                               agg_u, x_user, W1l_mu, W1r_mu, b1_mu, h_u);
  // layer 2 (merged aggs, merged MFMA GEMMs with folded classifier weights)
  k_agg_l2<<<MBLK + NUV / 4, 256, 0, stream>>>(off_um, srow_um, h_u, aggb_m,
                                               off_mu, srow_mu, h_m, aggb_u);
  k_gemm2_mfma<<<G2MB + (NUV + 63) / 64, 256, 0, stream>>>(
      aggb_m, h_m, WtA_m, WtB_m, bias_m, pm_b,
      aggb_u, h_u, WtA_u, WtB_u, bias_u, pu_b);
  // edge classifier: gather + relu + dot
  k_edge<<<(ETV + 255) / 256, 256, 0, stream>>>((const u32*)pu_b, (const u32*)pm_b,
                                                row_t, col_t, Wc2, bc2, out);
}

// Round 10
// 395.159 us; speedup vs baseline: 5.2908x; 1.0717x over previous
//
#include <hip/hip_runtime.h>
#include <hip/hip_bf16.h>

// Hetero-SAGE: replica-privatized CSR build + wide-lane gather aggregation +
// bf16-MFMA GEMMs with folded classifier (layer-2 linear => z@Wc1 folded).
#define NUV 100000
#define NMV 20000
#define NEV 1000000
#define ETV 500000

#define REP 8                     // histogram replicas (contention /8)
#define SCH2 16384                // scan elements per block (1024 thr x 16)
#define NCA 10                    // ceil(8*NMV/SCH2)
#define NCB 49                    // ceil(8*NUV/SCH2)
#define HGRID 1954                // ceil(2*NEV/4/256)
#define MBLK 5000                 // merchant agg blocks (NMV/4)
#define G1MB 625                  // merchant layer-1 gemm blocks (NMV/32)
#define G2MB 313                  // merchant layer-2 gemm blocks (ceil(NMV/64))

typedef unsigned short u16;
typedef unsigned int u32;
typedef __attribute__((ext_vector_type(8))) short s16x8;
typedef __attribute__((ext_vector_type(4))) float f32x4;
typedef __attribute__((ext_vector_type(4))) unsigned short u16x4;
typedef __attribute__((ext_vector_type(4))) unsigned int u32x4;

__device__ inline u16 bf16r(float f) {  // RTNE float->bf16
  u32 b = __builtin_bit_cast(u32, f);
  u32 r = b + 0x7fffu + ((b >> 16) & 1u);
  return (u16)(r >> 16);
}
__device__ inline float bflo(u32 v) { return __builtin_bit_cast(float, v << 16); }
__device__ inline float bfhi(u32 v) { return __builtin_bit_cast(float, v & 0xffff0000u); }

#define GLOAD_LDS16(src, dst) \
  __builtin_amdgcn_global_load_lds((const __attribute__((address_space(1))) void*)(src), \
                                   (__attribute__((address_space(3))) void*)(dst), 16, 0, 0)

// ---------------- CSR: replica-privatized histogram + rank ----------------
__global__ __launch_bounds__(256) void k_hist_rank_p(
    const int* __restrict__ col_um, int* __restrict__ cnt_um, int* __restrict__ rank_um,
    const int* __restrict__ col_mu, int* __restrict__ cnt_mu, int* __restrict__ rank_mu) {
  int bid = blockIdx.x;
  int i = (bid * 256 + threadIdx.x) * 4;
  if (i >= 2 * NEV) return;
  int r = bid & (REP - 1);
  bool um = i < NEV;
  const int* col = um ? col_um : col_mu;
  int* cnt = um ? cnt_um : cnt_mu;
  int* rank = um ? rank_um : rank_mu;
  int lo = um ? i : i - NEV;
  int4 c = *(const int4*)(col + lo);
  int4 k;
  k.x = atomicAdd(&cnt[c.x * REP + r], 1);
  k.y = atomicAdd(&cnt[c.y * REP + r], 1);
  k.z = atomicAdd(&cnt[c.z * REP + r], 1);
  k.w = atomicAdd(&cnt[c.w * REP + r], 1);
  *(int4*)(rank + lo) = k;
}

// ---- 3-phase scan over (dest,replica)-ordered count arrays ----
__global__ __launch_bounds__(1024) void k_scan_p1(const int* __restrict__ cntA, int nA,
                                                  const int* __restrict__ cntB, int nB,
                                                  int* __restrict__ bsum) {
  int b = blockIdx.x;
  const int* arr; int n; int c;
  if (b < NCA) { arr = cntA; n = nA; c = b; }
  else         { arr = cntB; n = nB; c = b - NCA; }
  __shared__ int wsum[16];
  int tid = threadIdx.x, lane = tid & 63, w = tid >> 6;
  int base = c * SCH2 + tid * 16;
  int s = 0;
  #pragma unroll
  for (int q = 0; q < 16; q += 4) {
    if (base + q + 3 < n) {
      int4 v = *(const int4*)(arr + base + q);
      s += v.x + v.y + v.z + v.w;
    } else {
      #pragma unroll
      for (int j = 0; j < 4; ++j) s += (base + q + j < n) ? arr[base + q + j] : 0;
    }
  }
  #pragma unroll
  for (int d = 1; d < 64; d <<= 1) s += __shfl_xor(s, d);
  if (lane == 0) wsum[w] = s;
  __syncthreads();
  if (tid == 0) {
    int tot = 0;
    #pragma unroll
    for (int j = 0; j < 16; ++j) tot += wsum[j];
    bsum[b] = tot;
  }
}

__global__ __launch_bounds__(128) void k_scan_p2(int* __restrict__ bsum,
                                                 int* __restrict__ off_um, int* __restrict__ off_mu) {
  int tid = threadIdx.x;
  int wv = tid >> 6, lane = tid & 63;
  if (wv == 0) {
    int v = (lane < NCA) ? bsum[lane] : 0;
    int s = v;
    #pragma unroll
    for (int d = 1; d < 64; d <<= 1) { int t = __shfl_up(s, d); if (lane >= d) s += t; }
    if (lane < NCA) bsum[lane] = s - v;
  } else {
    int v = (lane < NCB) ? bsum[NCA + lane] : 0;
    int s = v;
    #pragma unroll
    for (int d = 1; d < 64; d <<= 1) { int t = __shfl_up(s, d); if (lane >= d) s += t; }
    if (lane < NCB) bsum[NCA + lane] = s - v;
  }
  if (tid == 0) { off_um[NMV] = NEV; off_mu[NUV] = NEV; }
}

// in-place: counts -> exclusive base; also emits off[c] = base[c*REP]
__global__ __launch_bounds__(1024) void k_scan_p3(int* __restrict__ cntA, int nA, int* __restrict__ offA,
                                                  int* __restrict__ cntB, int nB, int* __restrict__ offB,
                                                  const int* __restrict__ bsum) {
  int b = blockIdx.x;
  int* arr; int n; int c; int* offo;
  if (b < NCA) { arr = cntA; n = nA; c = b; offo = offA; }
  else         { arr = cntB; n = nB; c = b - NCA; offo = offB; }
  int carry = bsum[b];
  __shared__ int wsum[16];
  int tid = threadIdx.x, lane = tid & 63, w = tid >> 6;
  int base = c * SCH2 + tid * 16;
  int v[16];
  #pragma unroll
  for (int q = 0; q < 16; q += 4) {
    if (base + q + 3 < n) {
      int4 t = *(const int4*)(arr + base + q);
      v[q] = t.x; v[q + 1] = t.y; v[q + 2] = t.z; v[q + 3] = t.w;
    } else {
      #pragma unroll
      for (int j = 0; j < 4; ++j) v[q + j] = (base + q + j < n) ? arr[base + q + j] : 0;
    }
  }
  int tsum = 0;
  #pragma unroll
  for (int q = 0; q < 16; ++q) tsum += v[q];
  int sc = tsum;
  #pragma unroll
  for (int d = 1; d < 64; d <<= 1) { int t = __shfl_up(sc, d); if (lane >= d) sc += t; }
  if (lane == 63) wsum[w] = sc;
  __syncthreads();
  if (w == 0 && lane < 16) {
    int ws_ = wsum[lane];
    #pragma unroll
    for (int d = 1; d < 16; d <<= 1) { int t = __shfl_up(ws_, d, 16); if (lane >= d) ws_ += t; }
    wsum[lane] = ws_;
  }
  __syncthreads();
  int run = sc - tsum + (w ? wsum[w - 1] : 0) + carry;
  #pragma unroll
  for (int q = 0; q < 16; ++q) {
    int idx = base + q;
    if (idx < n) {
      arr[idx] = run;
      if ((idx & (REP - 1)) == 0) offo[idx / REP] = run;
      run += v[q];
    }
  }
}

// ---------------- atomic-free scatter (replica base + precomputed rank) ----------------
__global__ __launch_bounds__(256) void k_scatter2(
    const int* __restrict__ col_um, const int* __restrict__ row_um,
    const int* __restrict__ rank_um, const int* __restrict__ base_um, int* __restrict__ srow_um,
    const int* __restrict__ col_mu, const int* __restrict__ row_mu,
    const int* __restrict__ rank_mu, const int* __restrict__ base_mu, int* __restrict__ srow_mu) {
  int bid = blockIdx.x;
  int i = (bid * 256 + threadIdx.x) * 4;
  if (i >= 2 * NEV) return;
  int r = bid & (REP - 1);
  bool um = i < NEV;
  const int* col = um ? col_um : col_mu;
  const int* row = um ? row_um : row_mu;
  const int* rank = um ? rank_um : rank_mu;
  const int* basep = um ? base_um : base_mu;
  int* srow = um ? srow_um : srow_mu;
  int lo = um ? i : i - NEV;
  int4 c = *(const int4*)(col + lo);
  int4 rr = *(const int4*)(row + lo);
  int4 k = *(const int4*)(rank + lo);
  srow[basep[c.x * REP + r] + k.x] = rr.x;
  srow[basep[c.y * REP + r] + k.y] = rr.y;
  srow[basep[c.z * REP + r] + k.z] = rr.z;
  srow[basep[c.w * REP + r] + k.w] = rr.w;
}

// ---------------- x_user -> bf16 (halves layer-1 gather traffic) ----------------
__global__ __launch_bounds__(256) void k_xub(const float* __restrict__ in, u32* __restrict__ o, int n8) {
  int stride = gridDim.x * 256;
  for (int i = blockIdx.x * 256 + threadIdx.x; i < n8; i += stride) {
    float4 a = *(const float4*)(in + (size_t)i * 8);
    float4 b = *(const float4*)(in + (size_t)i * 8 + 4);
    u32x4 r;
    r[0] = (u32)bf16r(a.x) | ((u32)bf16r(a.y) << 16);
    r[1] = (u32)bf16r(a.z) | ((u32)bf16r(a.w) << 16);
    r[2] = (u32)bf16r(b.x) | ((u32)bf16r(b.y) << 16);
    r[3] = (u32)bf16r(b.z) | ((u32)bf16r(b.w) << 16);
    *(u32x4*)(o + (size_t)i * 4) = r;
  }
}

// ---------------- merged layer-1 segment-mean (wide-lane gathers) ----------------
// merchant: 8 lanes x u32x4 per 128B bf16 row -> 8 edges per wave-instruction.
// user:     8 lanes x float4 per 128B fp32 row -> 8 edges per wave-instruction.
__global__ __launch_bounds__(256) void k_agg_l1(
    const int* __restrict__ off_um, const int* __restrict__ srow_um,
    const u32* __restrict__ xub, float* __restrict__ agg_m,
    const int* __restrict__ off_mu, const int* __restrict__ srow_mu,
    const float* __restrict__ xm, float* __restrict__ agg_u) {
  int bid = blockIdx.x, tid = threadIdx.x;
  int l = tid & 63, g = l >> 3, lr = l & 7;
  if (bid < MBLK) {
    int wid = (bid * 256 + tid) >> 6;
    int s = off_um[wid], t = off_um[wid + 1];
    float a[8] = {};
    int j = s;
    for (; j + 16 <= t; j += 16) {
      int r0 = srow_um[j + g], r1 = srow_um[j + 8 + g];
      u32x4 v0 = *(const u32x4*)(xub + (size_t)r0 * 32 + lr * 4);
      u32x4 v1 = *(const u32x4*)(xub + (size_t)r1 * 32 + lr * 4);
      #pragma unroll
      for (int k = 0; k < 4; ++k) {
        a[2 * k] += bflo(v0[k]) + bflo(v1[k]);
        a[2 * k + 1] += bfhi(v0[k]) + bfhi(v1[k]);
      }
    }
    for (; j + 8 <= t; j += 8) {
      int r0 = srow_um[j + g];
      u32x4 v0 = *(const u32x4*)(xub + (size_t)r0 * 32 + lr * 4);
      #pragma unroll
      for (int k = 0; k < 4; ++k) { a[2 * k] += bflo(v0[k]); a[2 * k + 1] += bfhi(v0[k]); }
    }
    if (g < t - j) {
      int r0 = srow_um[j + g];
      u32x4 v0 = *(const u32x4*)(xub + (size_t)r0 * 32 + lr * 4);
      #pragma unroll
      for (int k = 0; k < 4; ++k) { a[2 * k] += bflo(v0[k]); a[2 * k + 1] += bfhi(v0[k]); }
    }
    #pragma unroll
    for (int k = 0; k < 8; ++k) {
      a[k] += __shfl_xor(a[k], 8);
      a[k] += __shfl_xor(a[k], 16);
      a[k] += __shfl_xor(a[k], 32);
    }
    if (g == 0) {
      float inv = 1.f / (float)max(t - s, 1);
      float4 o0 = make_float4(a[0] * inv, a[1] * inv, a[2] * inv, a[3] * inv);
      float4 o1 = make_float4(a[4] * inv, a[5] * inv, a[6] * inv, a[7] * inv);
      *(float4*)(agg_m + (size_t)wid * 64 + lr * 8) = o0;
      *(float4*)(agg_m + (size_t)wid * 64 + lr * 8 + 4) = o1;
    }
  } else {
    int wid = ((bid - MBLK) * 256 + tid) >> 6;
    int s = off_mu[wid], t = off_mu[wid + 1];
    float a[4] = {};
    int j = s;
    for (; j + 16 <= t; j += 16) {
      int r0 = srow_mu[j + g], r1 = srow_mu[j + 8 + g];
      float4 v0 = *(const float4*)(xm + (size_t)r0 * 32 + lr * 4);
      float4 v1 = *(const float4*)(xm + (size_t)r1 * 32 + lr * 4);
      a[0] += v0.x + v1.x; a[1] += v0.y + v1.y;
      a[2] += v0.z + v1.z; a[3] += v0.w + v1.w;
    }
    for (; j + 8 <= t; j += 8) {
      int r0 = srow_mu[j + g];
      float4 v0 = *(const float4*)(xm + (size_t)r0 * 32 + lr * 4);
      a[0] += v0.x; a[1] += v0.y; a[2] += v0.z; a[3] += v0.w;
    }
    if (g < t - j) {
      int r0 = srow_mu[j + g];
      float4 v0 = *(const float4*)(xm + (size_t)r0 * 32 + lr * 4);
      a[0] += v0.x; a[1] += v0.y; a[2] += v0.z; a[3] += v0.w;
    }
    #pragma unroll
    for (int k = 0; k < 4; ++k) {
      a[k] += __shfl_xor(a[k], 8);
      a[k] += __shfl_xor(a[k], 16);
      a[k] += __shfl_xor(a[k], 32);
    }
    if (g == 0) {
      float inv = 1.f / (float)max(t - s, 1);
      *(float4*)(agg_u + (size_t)wid * 32 + lr * 4) =
          make_float4(a[0] * inv, a[1] * inv, a[2] * inv, a[3] * inv);
    }
  }
}

// ---------------- merged layer-2 segment-mean (wide-lane bf16 gather) ----------------
// 16 lanes x u32x4 per 256B row -> 4 edges per wave-instruction, 2-deep unroll.
__global__ __launch_bounds__(256) void k_agg_l2(
    const int* __restrict__ off_um, const int* __restrict__ srow_um,
    const u16* __restrict__ h_u, u16* __restrict__ aggb_m,
    const int* __restrict__ off_mu, const int* __restrict__ srow_mu,
    const u16* __restrict__ h_m, u16* __restrict__ aggb_u) {
  int bid = blockIdx.x, tid = threadIdx.x;
  const int* off; const int* srow; const u32* x; u32* ag; int wid;
  if (bid < MBLK) {
    off = off_um; srow = srow_um; x = (const u32*)h_u; ag = (u32*)aggb_m;
    wid = (bid * 256 + tid) >> 6;
  } else {
    off = off_mu; srow = srow_mu; x = (const u32*)h_m; ag = (u32*)aggb_u;
    wid = ((bid - MBLK) * 256 + tid) >> 6;
  }
  int l = tid & 63, g = l >> 4, lr = l & 15;
  int s = off[wid], t = off[wid + 1];
  float a[8] = {};
  int j = s;
  for (; j + 8 <= t; j += 8) {
    int r0 = srow[j + g], r1 = srow[j + 4 + g];
    u32x4 v0 = *(const u32x4*)(x + (size_t)r0 * 64 + lr * 4);
    u32x4 v1 = *(const u32x4*)(x + (size_t)r1 * 64 + lr * 4);
    #pragma unroll
    for (int k = 0; k < 4; ++k) {
      a[2 * k] += bflo(v0[k]) + bflo(v1[k]);
      a[2 * k + 1] += bfhi(v0[k]) + bfhi(v1[k]);
    }
  }
  for (; j + 4 <= t; j += 4) {
    int r0 = srow[j + g];
    u32x4 v0 = *(const u32x4*)(x + (size_t)r0 * 64 + lr * 4);
    #pragma unroll
    for (int k = 0; k < 4; ++k) { a[2 * k] += bflo(v0[k]); a[2 * k + 1] += bfhi(v0[k]); }
  }
  if (g < t - j) {
    int r0 = srow[j + g];
    u32x4 v0 = *(const u32x4*)(x + (size_t)r0 * 64 + lr * 4);
    #pragma unroll
    for (int k = 0; k < 4; ++k) { a[2 * k] += bflo(v0[k]); a[2 * k + 1] += bfhi(v0[k]); }
  }
  #pragma unroll
  for (int k = 0; k < 8; ++k) {
    a[k] += __shfl_xor(a[k], 16);
    a[k] += __shfl_xor(a[k], 32);
  }
  if (g == 0) {
    float inv = 1.f / (float)max(t - s, 1);
    u32x4 o;
    #pragma unroll
    for (int k = 0; k < 4; ++k)
      o[k] = (u32)bf16r(a[2 * k] * inv) | ((u32)bf16r(a[2 * k + 1] * inv) << 16);
    *(u32x4*)(ag + (size_t)wid * 64 + lr * 4) = o;
  }
}

// ---------------- layer-1 dual GEMM body (fp32 in, bf16 out) ----------------
template <int KA, int KB>
__device__ inline void gemm1_body(const float* __restrict__ A, const float* __restrict__ B,
                                  const float* __restrict__ Wa, const float* __restrict__ Wb,
                                  const float* __restrict__ bias, u16* __restrict__ outb,
                                  int m0, float* At, float* Bt) {
  int tid = threadIdx.x;
  {
    int m = tid & 31, kq = tid >> 5;
    const float* Ar = A + (size_t)(m0 + m) * KA;
    for (int k0 = kq * 4; k0 < KA; k0 += 32) {
      float4 v = *(const float4*)(Ar + k0);
      At[(k0 + 0) * 32 + m] = v.x; At[(k0 + 1) * 32 + m] = v.y;
      At[(k0 + 2) * 32 + m] = v.z; At[(k0 + 3) * 32 + m] = v.w;
    }
    const float* Br = B + (size_t)(m0 + m) * KB;
    for (int k0 = kq * 4; k0 < KB; k0 += 32) {
      float4 v = *(const float4*)(Br + k0);
      Bt[(k0 + 0) * 32 + m] = v.x; Bt[(k0 + 1) * 32 + m] = v.y;
      Bt[(k0 + 2) * 32 + m] = v.z; Bt[(k0 + 3) * 32 + m] = v.w;
    }
  }
  __syncthreads();
  int tx = tid & 31, ty = tid >> 5;
  float acc[4][4] = {};
  #pragma unroll 4
  for (int k = 0; k < KA; ++k) {
    float4 wv = *(const float4*)(Wa + k * 128 + tx * 4);
    float4 av = *(const float4*)(&At[k * 32 + ty * 4]);
    float am[4] = {av.x, av.y, av.z, av.w};
    float wo[4] = {wv.x, wv.y, wv.z, wv.w};
    #pragma unroll
    for (int mi = 0; mi < 4; ++mi)
      #pragma unroll
      for (int oi = 0; oi < 4; ++oi) acc[mi][oi] += am[mi] * wo[oi];
  }
  #pragma unroll 4
  for (int k = 0; k < KB; ++k) {
    float4 wv = *(const float4*)(Wb + k * 128 + tx * 4);
    float4 av = *(const float4*)(&Bt[k * 32 + ty * 4]);
    float am[4] = {av.x, av.y, av.z, av.w};
    float wo[4] = {wv.x, wv.y, wv.z, wv.w};
    #pragma unroll
    for (int mi = 0; mi < 4; ++mi)
      #pragma unroll
      for (int oi = 0; oi < 4; ++oi) acc[mi][oi] += am[mi] * wo[oi];
  }
  float4 bv = *(const float4*)(bias + tx * 4);
  float bb[4] = {bv.x, bv.y, bv.z, bv.w};
  #pragma unroll
  for (int mi = 0; mi < 4; ++mi) {
    u16x4 o;
    #pragma unroll
    for (int oi = 0; oi < 4; ++oi) {
      float v = acc[mi][oi] + bb[oi];
      v = v > 0.f ? v : 0.f;  // layer-1 relu
      o[oi] = bf16r(v);
    }
    *(u16x4*)(outb + (size_t)(m0 + ty * 4 + mi) * 128 + tx * 4) = o;
  }
}

// merged layer-1 GEMM: blocks [0,G1MB) merchant <64,32>, rest user <32,64>
__global__ __launch_bounds__(256) void k_gemm1(
    const float* __restrict__ agg_m, const float* __restrict__ x_merch,
    const float* __restrict__ W1l_um, const float* __restrict__ W1r_um,
    const float* __restrict__ b1_um, u16* __restrict__ h_m,
    const float* __restrict__ agg_u, const float* __restrict__ x_user,
    const float* __restrict__ W1l_mu, const float* __restrict__ W1r_mu,
    const float* __restrict__ b1_mu, u16* __restrict__ h_u) {
  __shared__ float At[64 * 32];
  __shared__ float Bt[64 * 32];
  int bid = blockIdx.x;
  if (bid < G1MB)
    gemm1_body<64, 32>(agg_m, x_merch, W1l_um, W1r_um, b1_um, h_m, bid * 32, At, Bt);
  else
    gemm1_body<32, 64>(agg_u, x_user, W1l_mu, W1r_mu, b1_mu, h_u, (bid - G1MB) * 32, At, Bt);
}

// ---------------- combined-weight prep: Wt = (W2 @ Wc1half)^T in bf16, plus folded biases ----------------
__global__ __launch_bounds__(256) void k_prep_comb(
    const float* __restrict__ W2l_um, const float* __restrict__ W2r_um,
    const float* __restrict__ W2l_mu, const float* __restrict__ W2r_mu,
    const float* __restrict__ b2_um, const float* __restrict__ b2_mu,
    const float* __restrict__ Wc1, const float* __restrict__ bc1,
    u16* __restrict__ WtA_u, u16* __restrict__ WtB_u,
    u16* __restrict__ WtA_m, u16* __restrict__ WtB_m,
    float* __restrict__ bias_u, float* __restrict__ bias_m) {
  int t = blockIdx.x * 256 + threadIdx.x;
  if (t < 65536) {
    int mat = t >> 14, rem = t & 16383;
    int o = rem >> 7, k = rem & 127;
    const float* W2 = mat == 0 ? W2l_mu : mat == 1 ? W2r_mu : mat == 2 ? W2l_um : W2r_um;
    const float* wc = Wc1 + (mat >= 2 ? 128 * 128 : 0) + o;
    float s = 0.f;
    #pragma unroll 4
    for (int j = 0; j < 128; ++j) s += W2[k * 128 + j] * wc[j * 128];
    u16* dst = mat == 0 ? WtA_u : mat == 1 ? WtB_u : mat == 2 ? WtA_m : WtB_m;
    dst[o * 128 + k] = bf16r(s);
  } else if (t < 65536 + 256) {
    int r = t - 65536;
    int o = r & 127;
    if (r < 128) {
      float s = 0.f;
      for (int j = 0; j < 128; ++j) s += b2_mu[j] * Wc1[j * 128 + o];
      bias_u[o] = s;
    } else {
      float s = bc1[o];  // fold bc1 into merchant-side bias
      for (int j = 0; j < 128; ++j) s += b2_um[j] * Wc1[(128 + j) * 128 + o];
      bias_m[o] = s;
    }
  }
}

// ---------------- merged layer-2 GEMM (bf16 MFMA): outb = bf16(aggb@Wtl + hb@Wtr + bias) ----------------
__global__ __launch_bounds__(256) void k_gemm2_mfma(
    const u16* __restrict__ aggb_m, const u16* __restrict__ h_m,
    const u16* __restrict__ WtA_m, const u16* __restrict__ WtB_m,
    const float* __restrict__ bias_m, u16* __restrict__ pm_b,
    const u16* __restrict__ aggb_u, const u16* __restrict__ h_u,
    const u16* __restrict__ WtA_u, const u16* __restrict__ WtB_u,
    const float* __restrict__ bias_u, u16* __restrict__ pu_b) {
  __shared__ u16 Zs[64 * 256];  // 32KB
  int tid = threadIdx.x;
  int bid = blockIdx.x;
  const u16 *aggb, *hb, *Wtl, *Wtr; const float* bias; u16* zb; int nd, r0;
  if (bid < G2MB) {
    aggb = aggb_m; hb = h_m; Wtl = WtA_m; Wtr = WtB_m; bias = bias_m; zb = pm_b;
    nd = NMV; r0 = bid * 64;
  } else {
    aggb = aggb_u; hb = h_u; Wtl = WtA_u; Wtr = WtB_u; bias = bias_u; zb = pu_b;
    nd = NUV; r0 = (bid - G2MB) * 64;
  }
  {
    int half = (tid >> 4) & 1;
    const u16* tab = half ? hb : aggb;
    #pragma unroll
    for (int it = 0; it < 8; ++it) {
      int q = tid + it * 256;
      int rl = q >> 5;
      int cc = (q & 15) ^ (rl & 7);
      int r = r0 + rl; r = r < nd ? r : nd - 1;
      const u16* src = tab + (size_t)r * 128 + cc * 8;
      u16* dst = Zs + (tid >> 6) * 512 + it * 2048;
      GLOAD_LDS16(src, dst);
    }
  }
  __syncthreads();
  int l = tid & 63, wv = tid >> 6;
  int lg = l >> 4, lr = l & 15;
  f32x4 acc[4][2];
  #pragma unroll
  for (int mt = 0; mt < 4; ++mt)
    #pragma unroll
    for (int c = 0; c < 2; ++c) acc[mt][c] = (f32x4){0.f, 0.f, 0.f, 0.f};
  #pragma unroll
  for (int cti = 0; cti < 2; ++cti) {
    int o = (wv * 2 + cti) * 16 + lr;
    const u16* wpl = Wtl + (size_t)o * 128 + lg * 8;
    const u16* wpr = Wtr + (size_t)o * 128 + lg * 8;
    s16x8 b[8];
    #pragma unroll
    for (int ks = 0; ks < 4; ++ks) b[ks] = *(const s16x8*)(wpl + ks * 32);
    #pragma unroll
    for (int ks = 0; ks < 4; ++ks) b[ks + 4] = *(const s16x8*)(wpr + ks * 32);
    #pragma unroll
    for (int mt = 0; mt < 4; ++mt) {
      int rl = mt * 16 + lr;
      int rb = rl * 512, sw = (rl & 7) << 4;
      #pragma unroll
      for (int ks = 0; ks < 8; ++ks) {
        s16x8 a = *(const s16x8*)((const char*)Zs + ((rb + ks * 64 + lg * 16) ^ sw));
        acc[mt][cti] = __builtin_amdgcn_mfma_f32_16x16x32_bf16(a, b[ks], acc[mt][cti], 0, 0, 0);
      }
    }
  }
  float bv[2];
  #pragma unroll
  for (int cti = 0; cti < 2; ++cti) bv[cti] = bias[(wv * 2 + cti) * 16 + lr];
  #pragma unroll
  for (int mt = 0; mt < 4; ++mt)
    #pragma unroll
    for (int cti = 0; cti < 2; ++cti) {
      int o = (wv * 2 + cti) * 16 + lr;
      #pragma unroll
      for (int rg = 0; rg < 4; ++rg) {
        int r = r0 + mt * 16 + lg * 4 + rg;
        if (r < nd) zb[(size_t)r * 128 + o] = bf16r(acc[mt][cti][rg] + bv[cti]);
      }
    }
}

// ---------------- edge op: out[e] = Wc2 . relu(pu[row_t[e]] + pm[col_t[e]]) + bc2 ----------------
__global__ __launch_bounds__(256) void k_edge(
    const u32* __restrict__ pu, const u32* __restrict__ pm,
    const int* __restrict__ row_t, const int* __restrict__ col_t,
    const float* __restrict__ Wc2, const float* __restrict__ bc2,
    float* __restrict__ out) {
  __shared__ float res[256];
  int tid = threadIdx.x, l = tid & 63, wv = tid >> 6;
  int lr = l & 15, g = l >> 4;
  float w2v[8];
  #pragma unroll
  for (int q = 0; q < 8; ++q) w2v[q] = Wc2[lr * 8 + q];
  int base = blockIdx.x * 256 + wv * 64;
  #pragma unroll 2
  for (int it = 0; it < 16; ++it) {
    int e = base + it * 4 + g;
    int ec = e < ETV ? e : ETV - 1;
    int r = row_t[ec], c = col_t[ec];
    u32x4 a = *(const u32x4*)(pu + (size_t)r * 64 + lr * 4);
    u32x4 b = *(const u32x4*)(pm + (size_t)c * 64 + lr * 4);
    float p = 0.f;
    #pragma unroll
    for (int q = 0; q < 4; ++q) {
      float h0 = bflo(a[q]) + bflo(b[q]);
      float h1 = bfhi(a[q]) + bfhi(b[q]);
      h0 = h0 > 0.f ? h0 : 0.f;
      h1 = h1 > 0.f ? h1 : 0.f;
      p += h0 * w2v[2 * q] + h1 * w2v[2 * q + 1];
    }
    p += __shfl_xor(p, 1); p += __shfl_xor(p, 2);
    p += __shfl_xor(p, 4); p += __shfl_xor(p, 8);
    if (lr == 0) res[wv * 64 + it * 4 + g] = p;
  }
  __syncthreads();
  int eo = blockIdx.x * 256 + tid;
  if (eo < ETV) out[eo] = res[tid] + bc2[0];
}

extern "C" void kernel_launch(void* const* d_in, const int* in_sizes, int n_in,
                              void* d_out, int out_size, void* d_ws, size_t ws_size,
                              hipStream_t stream) {
  const float* x_user  = (const float*)d_in[0];
  const float* x_merch = (const float*)d_in[1];
  const int* row_um = (const int*)d_in[2]; const int* col_um = (const int*)d_in[3];
  const int* row_mu = (const int*)d_in[4]; const int* col_mu = (const int*)d_in[5];
  const int* row_t  = (const int*)d_in[6]; const int* col_t  = (const int*)d_in[7];
  const float* W1l_um = (const float*)d_in[8];  const float* W1r_um = (const float*)d_in[9];  const float* b1_um = (const float*)d_in[10];
  const float* W1l_mu = (const float*)d_in[11]; const float* W1r_mu = (const float*)d_in[12]; const float* b1_mu = (const float*)d_in[13];
  const float* W2l_um = (const float*)d_in[14]; const float* W2r_um = (const float*)d_in[15]; const float* b2_um = (const float*)d_in[16];
  const float* W2l_mu = (const float*)d_in[17]; const float* W2r_mu = (const float*)d_in[18]; const float* b2_mu = (const float*)d_in[19];
  const float* Wc1 = (const float*)d_in[20]; const float* bc1 = (const float*)d_in[21];
  const float* Wc2 = (const float*)d_in[22]; const float* bc2 = (const float*)d_in[23];
  float* out = (float*)d_out;

  char* ws = (char*)d_ws;
  size_t p = 0;
  auto alloc = [&](size_t bytes) -> char* {
    char* r = ws + p;
    p = (p + bytes + 255) & ~(size_t)255;
    return r;
  };
  int* cnt_um = (int*)alloc((size_t)NMV * REP * 4);      // privatized counts -> bases
  int* cnt_mu = (int*)alloc((size_t)NUV * REP * 4);
  size_t zero_end = p;
  int* off_um = (int*)alloc((size_t)(NMV + 1) * 4);
  int* off_mu = (int*)alloc((size_t)(NUV + 1) * 4);
  int* bsum = (int*)alloc((size_t)(NCA + NCB) * 4);
  int* rank_um = (int*)alloc((size_t)NEV * 4);
  int* rank_mu = (int*)alloc((size_t)NEV * 4);
  int* srow_um = (int*)alloc((size_t)NEV * 4);
  int* srow_mu = (int*)alloc((size_t)NEV * 4);
  u32* xub = (u32*)alloc((size_t)NUV * 32 * 4);          // x_user in bf16 (packed pairs)
  float* agg_m = (float*)alloc((size_t)NMV * 64 * 4);    // layer1 merchant agg (fp32, 64 feats)
  float* agg_u = (float*)alloc((size_t)NUV * 32 * 4);    // layer1 user agg (fp32, 32 feats)
  u16* h_m   = (u16*)alloc((size_t)NMV * 128 * 2);       // bf16 hidden
  u16* h_u   = (u16*)alloc((size_t)NUV * 128 * 2);
  u16* aggb_m = (u16*)alloc((size_t)NMV * 128 * 2);      // layer2 agg (bf16)
  u16* aggb_u = (u16*)alloc((size_t)NUV * 128 * 2);
  u16* pm_b  = (u16*)alloc((size_t)NMV * 128 * 2);       // folded classifier projections (bf16)
  u16* pu_b  = (u16*)alloc((size_t)NUV * 128 * 2);
  u16* WtA_u = (u16*)alloc((size_t)128 * 128 * 2);
  u16* WtB_u = (u16*)alloc((size_t)128 * 128 * 2);
  u16* WtA_m = (u16*)alloc((size_t)128 * 128 * 2);
  u16* WtB_m = (u16*)alloc((size_t)128 * 128 * 2);
  float* bias_u = (float*)alloc(128 * 4);
  float* bias_m = (float*)alloc(128 * 4);
  if (p > ws_size) return;  // workspace too small: fail loudly via absmax

  hipMemsetAsync(d_ws, 0, zero_end, stream);
  k_prep_comb<<<257, 256, 0, stream>>>(W2l_um, W2r_um, W2l_mu, W2r_mu, b2_um, b2_mu, Wc1, bc1,
                                       WtA_u, WtB_u, WtA_m, WtB_m, bias_u, bias_m);
  k_xub<<<1024, 256, 0, stream>>>(x_user, xub, NUV * 64 / 8);
  // CSR build: replica-privatized hist+rank, 3-phase scan, atomic-free scatter
  k_hist_rank_p<<<HGRID, 256, 0, stream>>>(col_um, cnt_um, rank_um, col_mu, cnt_mu, rank_mu);
  k_scan_p1<<<NCA + NCB, 1024, 0, stream>>>(cnt_um, NMV * REP, cnt_mu, NUV * REP, bsum);
  k_scan_p2<<<1, 128, 0, stream>>>(bsum, off_um, off_mu);
  k_scan_p3<<<NCA + NCB, 1024, 0, stream>>>(cnt_um, NMV * REP, off_um,
                                            cnt_mu, NUV * REP, off_mu, bsum);
  k_scatter2<<<HGRID, 256, 0, stream>>>(col_um, row_um, rank_um, cnt_um, srow_um,
                                        col_mu, row_mu, rank_mu, cnt_mu, srow_mu);
  // layer 1 (merged wide-lane aggs, merged dual GEMMs; bf16 h out)
  k_agg_l1<<<MBLK + NUV / 4, 256, 0, stream>>>(off_um, srow_um, xub, agg_m,
                                               off_mu, srow_mu, x_merch, agg_u);
  k_gemm1<<<G1MB + NUV / 32, 256, 0, stream>>>(agg_m, x_merch, W1l_um, W1r_um, b1_um, h_m,
                                               agg_u, x_user, W1l_mu, W1r_mu, b1_mu, h_u);
  // layer 2 (merged wide-lane aggs, merged MFMA GEMMs with folded classifier weights)
  k_agg_l2<<<MBLK + NUV / 4, 256, 0, stream>>>(off_um, srow_um, h_u, aggb_m,
                                               off_mu, srow_mu, h_m, aggb_u);
  k_gemm2_mfma<<<G2MB + (NUV + 63) / 64, 256, 0, stream>>>(
      aggb_m, h_m, WtA_m, WtB_m, bias_m, pm_b,
      aggb_u, h_u, WtA_u, WtB_u, bias_u, pu_b);
  // edge classifier: gather + relu + dot
  k_edge<<<(ETV + 255) / 256, 256, 0, stream>>>((const u32*)pu_b, (const u32*)pm_b,
                                                row_t, col_t, Wc2, bc2, out);
}

// Round 11
// 394.572 us; speedup vs baseline: 5.2987x; 1.0015x over previous
//
#include <hip/hip_runtime.h>
#include <hip/hip_bf16.h>

// Hetero-SAGE: XCD-local-atomic CSR build + wide-lane gather aggregation +
// bf16-MFMA GEMMs with folded classifier (layer-2 linear => z@Wc1 folded).
#define NUV 100000
#define NMV 20000
#define NEV 1000000
#define ETV 500000

#define REP 8                     // histogram replicas = XCDs
#define SCH2 16384                // scan elements per block (1024 thr x 16)
#define NCA 10                    // ceil(8*NMV/SCH2)
#define NCB 49                    // ceil(8*NUV/SCH2)
#define HGRID 1954                // ceil(2*NEV/4/256)
#define MBLK 5000                 // merchant agg blocks (NMV/4)
#define G1MB 625                  // merchant layer-1 gemm blocks (NMV/32)
#define G2MB 313                  // merchant layer-2 gemm blocks (ceil(NMV/64))

typedef unsigned short u16;
typedef unsigned int u32;
typedef __attribute__((ext_vector_type(8))) short s16x8;
typedef __attribute__((ext_vector_type(4))) float f32x4;
typedef __attribute__((ext_vector_type(4))) unsigned short u16x4;
typedef __attribute__((ext_vector_type(4))) unsigned int u32x4;

__device__ inline u16 bf16r(float f) {  // RTNE float->bf16
  u32 b = __builtin_bit_cast(u32, f);
  u32 r = b + 0x7fffu + ((b >> 16) & 1u);
  return (u16)(r >> 16);
}
__device__ inline float bflo(u32 v) { return __builtin_bit_cast(float, v << 16); }
__device__ inline float bfhi(u32 v) { return __builtin_bit_cast(float, v & 0xffff0000u); }

// physical XCD id (0..7 on MI355X); constant for a block's lifetime
__device__ inline int xcc_id() {
  unsigned x;
  asm volatile("s_getreg_b32 %0, hwreg(HW_REG_XCC_ID, 0, 8)" : "=s"(x));
  return (int)(x & 7u);
}

#define GLOAD_LDS16(src, dst) \
  __builtin_amdgcn_global_load_lds((const __attribute__((address_space(1))) void*)(src), \
                                   (__attribute__((address_space(3))) void*)(dst), 16, 0, 0)

// ---------------- CSR: XCD-private histogram + rank (L2-local atomics) ----------------
// Replica r = physical XCD id. Slot cnt[c*REP+r] is only touched by blocks on XCD r,
// so a workgroup-scope (non-coherent-point) atomic RMW at that XCD's L2 is sufficient.
// rank value packs the replica in bits 24..26 for the scatter kernel.
__global__ __launch_bounds__(256) void k_hist_rank_p(
    const int* __restrict__ col_um, int* __restrict__ cnt_um, int* __restrict__ rank_um,
    const int* __restrict__ col_mu, int* __restrict__ cnt_mu, int* __restrict__ rank_mu) {
  int i = (blockIdx.x * 256 + threadIdx.x) * 4;
  if (i >= 2 * NEV) return;
  int r = xcc_id();
  u32 rtag = (u32)r << 24;
  bool um = i < NEV;
  const int* col = um ? col_um : col_mu;
  int* cnt = um ? cnt_um : cnt_mu;
  int* rank = um ? rank_um : rank_mu;
  int lo = um ? i : i - NEV;
  int4 c = *(const int4*)(col + lo);
  u32 k0 = (u32)__hip_atomic_fetch_add(&cnt[c.x * REP + r], 1, __ATOMIC_RELAXED, __HIP_MEMORY_SCOPE_WORKGROUP);
  u32 k1 = (u32)__hip_atomic_fetch_add(&cnt[c.y * REP + r], 1, __ATOMIC_RELAXED, __HIP_MEMORY_SCOPE_WORKGROUP);
  u32 k2 = (u32)__hip_atomic_fetch_add(&cnt[c.z * REP + r], 1, __ATOMIC_RELAXED, __HIP_MEMORY_SCOPE_WORKGROUP);
  u32 k3 = (u32)__hip_atomic_fetch_add(&cnt[c.w * REP + r], 1, __ATOMIC_RELAXED, __HIP_MEMORY_SCOPE_WORKGROUP);
  int4 k;
  k.x = (int)(k0 | rtag); k.y = (int)(k1 | rtag);
  k.z = (int)(k2 | rtag); k.w = (int)(k3 | rtag);
  *(int4*)(rank + lo) = k;
}

// ---- 3-phase scan over (dest,replica)-ordered count arrays ----
__global__ __launch_bounds__(1024) void k_scan_p1(const int* __restrict__ cntA, int nA,
                                                  const int* __restrict__ cntB, int nB,
                                                  int* __restrict__ bsum) {
  int b = blockIdx.x;
  const int* arr; int n; int c;
  if (b < NCA) { arr = cntA; n = nA; c = b; }
  else         { arr = cntB; n = nB; c = b - NCA; }
  __shared__ int wsum[16];
  int tid = threadIdx.x, lane = tid & 63, w = tid >> 6;
  int base = c * SCH2 + tid * 16;
  int s = 0;
  #pragma unroll
  for (int q = 0; q < 16; q += 4) {
    if (base + q + 3 < n) {
      int4 v = *(const int4*)(arr + base + q);
      s += v.x + v.y + v.z + v.w;
    } else {
      #pragma unroll
      for (int j = 0; j < 4; ++j) s += (base + q + j < n) ? arr[base + q + j] : 0;
    }
  }
  #pragma unroll
  for (int d = 1; d < 64; d <<= 1) s += __shfl_xor(s, d);
  if (lane == 0) wsum[w] = s;
  __syncthreads();
  if (tid == 0) {
    int tot = 0;
    #pragma unroll
    for (int j = 0; j < 16; ++j) tot += wsum[j];
    bsum[b] = tot;
  }
}

__global__ __launch_bounds__(128) void k_scan_p2(int* __restrict__ bsum,
                                                 int* __restrict__ off_um, int* __restrict__ off_mu) {
  int tid = threadIdx.x;
  int wv = tid >> 6, lane = tid & 63;
  if (wv == 0) {
    int v = (lane < NCA) ? bsum[lane] : 0;
    int s = v;
    #pragma unroll
    for (int d = 1; d < 64; d <<= 1) { int t = __shfl_up(s, d); if (lane >= d) s += t; }
    if (lane < NCA) bsum[lane] = s - v;
  } else {
    int v = (lane < NCB) ? bsum[NCA + lane] : 0;
    int s = v;
    #pragma unroll
    for (int d = 1; d < 64; d <<= 1) { int t = __shfl_up(s, d); if (lane >= d) s += t; }
    if (lane < NCB) bsum[NCA + lane] = s - v;
  }
  if (tid == 0) { off_um[NMV] = NEV; off_mu[NUV] = NEV; }
}

// in-place: counts -> exclusive base; also emits off[c] = base[c*REP]
__global__ __launch_bounds__(1024) void k_scan_p3(int* __restrict__ cntA, int nA, int* __restrict__ offA,
                                                  int* __restrict__ cntB, int nB, int* __restrict__ offB,
                                                  const int* __restrict__ bsum) {
  int b = blockIdx.x;
  int* arr; int n; int c; int* offo;
  if (b < NCA) { arr = cntA; n = nA; c = b; offo = offA; }
  else         { arr = cntB; n = nB; c = b - NCA; offo = offB; }
  int carry = bsum[b];
  __shared__ int wsum[16];
  int tid = threadIdx.x, lane = tid & 63, w = tid >> 6;
  int base = c * SCH2 + tid * 16;
  int v[16];
  #pragma unroll
  for (int q = 0; q < 16; q += 4) {
    if (base + q + 3 < n) {
      int4 t = *(const int4*)(arr + base + q);
      v[q] = t.x; v[q + 1] = t.y; v[q + 2] = t.z; v[q + 3] = t.w;
    } else {
      #pragma unroll
      for (int j = 0; j < 4; ++j) v[q + j] = (base + q + j < n) ? arr[base + q + j] : 0;
    }
  }
  int tsum = 0;
  #pragma unroll
  for (int q = 0; q < 16; ++q) tsum += v[q];
  int sc = tsum;
  #pragma unroll
  for (int d = 1; d < 64; d <<= 1) { int t = __shfl_up(sc, d); if (lane >= d) sc += t; }
  if (lane == 63) wsum[w] = sc;
  __syncthreads();
  if (w == 0 && lane < 16) {
    int ws_ = wsum[lane];
    #pragma unroll
    for (int d = 1; d < 16; d <<= 1) { int t = __shfl_up(ws_, d, 16); if (lane >= d) ws_ += t; }
    wsum[lane] = ws_;
  }
  __syncthreads();
  int run = sc - tsum + (w ? wsum[w - 1] : 0) + carry;
  #pragma unroll
  for (int q = 0; q < 16; ++q) {
    int idx = base + q;
    if (idx < n) {
      arr[idx] = run;
      if ((idx & (REP - 1)) == 0) offo[idx / REP] = run;
      run += v[q];
    }
  }
}

// ---------------- atomic-free scatter (replica base + packed rank) ----------------
__global__ __launch_bounds__(256) void k_scatter2(
    const int* __restrict__ col_um, const int* __restrict__ row_um,
    const int* __restrict__ rank_um, const int* __restrict__ base_um, int* __restrict__ srow_um,
    const int* __restrict__ col_mu, const int* __restrict__ row_mu,
    const int* __restrict__ rank_mu, const int* __restrict__ base_mu, int* __restrict__ srow_mu) {
  int i = (blockIdx.x * 256 + threadIdx.x) * 4;
  if (i >= 2 * NEV) return;
  bool um = i < NEV;
  const int* col = um ? col_um : col_mu;
  const int* row = um ? row_um : row_mu;
  const int* rank = um ? rank_um : rank_mu;
  const int* basep = um ? base_um : base_mu;
  int* srow = um ? srow_um : srow_mu;
  int lo = um ? i : i - NEV;
  int4 c = *(const int4*)(col + lo);
  int4 rr = *(const int4*)(row + lo);
  int4 k = *(const int4*)(rank + lo);
  u32 kx = (u32)k.x, ky = (u32)k.y, kz = (u32)k.z, kw = (u32)k.w;
  srow[basep[c.x * REP + (kx >> 24)] + (int)(kx & 0xFFFFFF)] = rr.x;
  srow[basep[c.y * REP + (ky >> 24)] + (int)(ky & 0xFFFFFF)] = rr.y;
  srow[basep[c.z * REP + (kz >> 24)] + (int)(kz & 0xFFFFFF)] = rr.z;
  srow[basep[c.w * REP + (kw >> 24)] + (int)(kw & 0xFFFFFF)] = rr.w;
}

// ---------------- x_user -> bf16 (halves layer-1 gather traffic) ----------------
__global__ __launch_bounds__(256) void k_xub(const float* __restrict__ in, u32* __restrict__ o, int n8) {
  int stride = gridDim.x * 256;
  for (int i = blockIdx.x * 256 + threadIdx.x; i < n8; i += stride) {
    float4 a = *(const float4*)(in + (size_t)i * 8);
    float4 b = *(const float4*)(in + (size_t)i * 8 + 4);
    u32x4 r;
    r[0] = (u32)bf16r(a.x) | ((u32)bf16r(a.y) << 16);
    r[1] = (u32)bf16r(a.z) | ((u32)bf16r(a.w) << 16);
    r[2] = (u32)bf16r(b.x) | ((u32)bf16r(b.y) << 16);
    r[3] = (u32)bf16r(b.z) | ((u32)bf16r(b.w) << 16);
    *(u32x4*)(o + (size_t)i * 4) = r;
  }
}

// ---------------- merged layer-1 segment-mean (wide-lane gathers) ----------------
__global__ __launch_bounds__(256) void k_agg_l1(
    const int* __restrict__ off_um, const int* __restrict__ srow_um,
    const u32* __restrict__ xub, float* __restrict__ agg_m,
    const int* __restrict__ off_mu, const int* __restrict__ srow_mu,
    const float* __restrict__ xm, float* __restrict__ agg_u) {
  int bid = blockIdx.x, tid = threadIdx.x;
  int l = tid & 63, g = l >> 3, lr = l & 7;
  if (bid < MBLK) {
    int wid = (bid * 256 + tid) >> 6;
    int s = off_um[wid], t = off_um[wid + 1];
    float a[8] = {};
    int j = s;
    for (; j + 16 <= t; j += 16) {
      int r0 = srow_um[j + g], r1 = srow_um[j + 8 + g];
      u32x4 v0 = *(const u32x4*)(xub + (size_t)r0 * 32 + lr * 4);
      u32x4 v1 = *(const u32x4*)(xub + (size_t)r1 * 32 + lr * 4);
      #pragma unroll
      for (int k = 0; k < 4; ++k) {
        a[2 * k] += bflo(v0[k]) + bflo(v1[k]);
        a[2 * k + 1] += bfhi(v0[k]) + bfhi(v1[k]);
      }
    }
    for (; j + 8 <= t; j += 8) {
      int r0 = srow_um[j + g];
      u32x4 v0 = *(const u32x4*)(xub + (size_t)r0 * 32 + lr * 4);
      #pragma unroll
      for (int k = 0; k < 4; ++k) { a[2 * k] += bflo(v0[k]); a[2 * k + 1] += bfhi(v0[k]); }
    }
    if (g < t - j) {
      int r0 = srow_um[j + g];
      u32x4 v0 = *(const u32x4*)(xub + (size_t)r0 * 32 + lr * 4);
      #pragma unroll
      for (int k = 0; k < 4; ++k) { a[2 * k] += bflo(v0[k]); a[2 * k + 1] += bfhi(v0[k]); }
    }
    #pragma unroll
    for (int k = 0; k < 8; ++k) {
      a[k] += __shfl_xor(a[k], 8);
      a[k] += __shfl_xor(a[k], 16);
      a[k] += __shfl_xor(a[k], 32);
    }
    if (g == 0) {
      float inv = 1.f / (float)max(t - s, 1);
      float4 o0 = make_float4(a[0] * inv, a[1] * inv, a[2] * inv, a[3] * inv);
      float4 o1 = make_float4(a[4] * inv, a[5] * inv, a[6] * inv, a[7] * inv);
      *(float4*)(agg_m + (size_t)wid * 64 + lr * 8) = o0;
      *(float4*)(agg_m + (size_t)wid * 64 + lr * 8 + 4) = o1;
    }
  } else {
    int wid = ((bid - MBLK) * 256 + tid) >> 6;
    int s = off_mu[wid], t = off_mu[wid + 1];
    float a[4] = {};
    int j = s;
    for (; j + 16 <= t; j += 16) {
      int r0 = srow_mu[j + g], r1 = srow_mu[j + 8 + g];
      float4 v0 = *(const float4*)(xm + (size_t)r0 * 32 + lr * 4);
      float4 v1 = *(const float4*)(xm + (size_t)r1 * 32 + lr * 4);
      a[0] += v0.x + v1.x; a[1] += v0.y + v1.y;
      a[2] += v0.z + v1.z; a[3] += v0.w + v1.w;
    }
    for (; j + 8 <= t; j += 8) {
      int r0 = srow_mu[j + g];
      float4 v0 = *(const float4*)(xm + (size_t)r0 * 32 + lr * 4);
      a[0] += v0.x; a[1] += v0.y; a[2] += v0.z; a[3] += v0.w;
    }
    if (g < t - j) {
      int r0 = srow_mu[j + g];
      float4 v0 = *(const float4*)(xm + (size_t)r0 * 32 + lr * 4);
      a[0] += v0.x; a[1] += v0.y; a[2] += v0.z; a[3] += v0.w;
    }
    #pragma unroll
    for (int k = 0; k < 4; ++k) {
      a[k] += __shfl_xor(a[k], 8);
      a[k] += __shfl_xor(a[k], 16);
      a[k] += __shfl_xor(a[k], 32);
    }
    if (g == 0) {
      float inv = 1.f / (float)max(t - s, 1);
      *(float4*)(agg_u + (size_t)wid * 32 + lr * 4) =
          make_float4(a[0] * inv, a[1] * inv, a[2] * inv, a[3] * inv);
    }
  }
}

// ---------------- merged layer-2 segment-mean (wide-lane bf16 gather) ----------------
__global__ __launch_bounds__(256) void k_agg_l2(
    const int* __restrict__ off_um, const int* __restrict__ srow_um,
    const u16* __restrict__ h_u, u16* __restrict__ aggb_m,
    const int* __restrict__ off_mu, const int* __restrict__ srow_mu,
    const u16* __restrict__ h_m, u16* __restrict__ aggb_u) {
  int bid = blockIdx.x, tid = threadIdx.x;
  const int* off; const int* srow; const u32* x; u32* ag; int wid;
  if (bid < MBLK) {
    off = off_um; srow = srow_um; x = (const u32*)h_u; ag = (u32*)aggb_m;
    wid = (bid * 256 + tid) >> 6;
  } else {
    off = off_mu; srow = srow_mu; x = (const u32*)h_m; ag = (u32*)aggb_u;
    wid = ((bid - MBLK) * 256 + tid) >> 6;
  }
  int l = tid & 63, g = l >> 4, lr = l & 15;
  int s = off[wid], t = off[wid + 1];
  float a[8] = {};
  int j = s;
  for (; j + 8 <= t; j += 8) {
    int r0 = srow[j + g], r1 = srow[j + 4 + g];
    u32x4 v0 = *(const u32x4*)(x + (size_t)r0 * 64 + lr * 4);
    u32x4 v1 = *(const u32x4*)(x + (size_t)r1 * 64 + lr * 4);
    #pragma unroll
    for (int k = 0; k < 4; ++k) {
      a[2 * k] += bflo(v0[k]) + bflo(v1[k]);
      a[2 * k + 1] += bfhi(v0[k]) + bfhi(v1[k]);
    }
  }
  for (; j + 4 <= t; j += 4) {
    int r0 = srow[j + g];
    u32x4 v0 = *(const u32x4*)(x + (size_t)r0 * 64 + lr * 4);
    #pragma unroll
    for (int k = 0; k < 4; ++k) { a[2 * k] += bflo(v0[k]); a[2 * k + 1] += bfhi(v0[k]); }
  }
  if (g < t - j) {
    int r0 = srow[j + g];
    u32x4 v0 = *(const u32x4*)(x + (size_t)r0 * 64 + lr * 4);
    #pragma unroll
    for (int k = 0; k < 4; ++k) { a[2 * k] += bflo(v0[k]); a[2 * k + 1] += bfhi(v0[k]); }
  }
  #pragma unroll
  for (int k = 0; k < 8; ++k) {
    a[k] += __shfl_xor(a[k], 16);
    a[k] += __shfl_xor(a[k], 32);
  }
  if (g == 0) {
    float inv = 1.f / (float)max(t - s, 1);
    u32x4 o;
    #pragma unroll
    for (int k = 0; k < 4; ++k)
      o[k] = (u32)bf16r(a[2 * k] * inv) | ((u32)bf16r(a[2 * k + 1] * inv) << 16);
    *(u32x4*)(ag + (size_t)wid * 64 + lr * 4) = o;
  }
}

// ---------------- layer-1 dual GEMM body (fp32 in, bf16 out) ----------------
template <int KA, int KB>
__device__ inline void gemm1_body(const float* __restrict__ A, const float* __restrict__ B,
                                  const float* __restrict__ Wa, const float* __restrict__ Wb,
                                  const float* __restrict__ bias, u16* __restrict__ outb,
                                  int m0, float* At, float* Bt) {
  int tid = threadIdx.x;
  {
    int m = tid & 31, kq = tid >> 5;
    const float* Ar = A + (size_t)(m0 + m) * KA;
    for (int k0 = kq * 4; k0 < KA; k0 += 32) {
      float4 v = *(const float4*)(Ar + k0);
      At[(k0 + 0) * 32 + m] = v.x; At[(k0 + 1) * 32 + m] = v.y;
      At[(k0 + 2) * 32 + m] = v.z; At[(k0 + 3) * 32 + m] = v.w;
    }
    const float* Br = B + (size_t)(m0 + m) * KB;
    for (int k0 = kq * 4; k0 < KB; k0 += 32) {
      float4 v = *(const float4*)(Br + k0);
      Bt[(k0 + 0) * 32 + m] = v.x; Bt[(k0 + 1) * 32 + m] = v.y;
      Bt[(k0 + 2) * 32 + m] = v.z; Bt[(k0 + 3) * 32 + m] = v.w;
    }
  }
  __syncthreads();
  int tx = tid & 31, ty = tid >> 5;
  float acc[4][4] = {};
  #pragma unroll 4
  for (int k = 0; k < KA; ++k) {
    float4 wv = *(const float4*)(Wa + k * 128 + tx * 4);
    float4 av = *(const float4*)(&At[k * 32 + ty * 4]);
    float am[4] = {av.x, av.y, av.z, av.w};
    float wo[4] = {wv.x, wv.y, wv.z, wv.w};
    #pragma unroll
    for (int mi = 0; mi < 4; ++mi)
      #pragma unroll
      for (int oi = 0; oi < 4; ++oi) acc[mi][oi] += am[mi] * wo[oi];
  }
  #pragma unroll 4
  for (int k = 0; k < KB; ++k) {
    float4 wv = *(const float4*)(Wb + k * 128 + tx * 4);
    float4 av = *(const float4*)(&Bt[k * 32 + ty * 4]);
    float am[4] = {av.x, av.y, av.z, av.w};
    float wo[4] = {wv.x, wv.y, wv.z, wv.w};
    #pragma unroll
    for (int mi = 0; mi < 4; ++mi)
      #pragma unroll
      for (int oi = 0; oi < 4; ++oi) acc[mi][oi] += am[mi] * wo[oi];
  }
  float4 bv = *(const float4*)(bias + tx * 4);
  float bb[4] = {bv.x, bv.y, bv.z, bv.w};
  #pragma unroll
  for (int mi = 0; mi < 4; ++mi) {
    u16x4 o;
    #pragma unroll
    for (int oi = 0; oi < 4; ++oi) {
      float v = acc[mi][oi] + bb[oi];
      v = v > 0.f ? v : 0.f;  // layer-1 relu
      o[oi] = bf16r(v);
    }
    *(u16x4*)(outb + (size_t)(m0 + ty * 4 + mi) * 128 + tx * 4) = o;
  }
}

// merged layer-1 GEMM: blocks [0,G1MB) merchant <64,32>, rest user <32,64>
__global__ __launch_bounds__(256) void k_gemm1(
    const float* __restrict__ agg_m, const float* __restrict__ x_merch,
    const float* __restrict__ W1l_um, const float* __restrict__ W1r_um,
    const float* __restrict__ b1_um, u16* __restrict__ h_m,
    const float* __restrict__ agg_u, const float* __restrict__ x_user,
    const float* __restrict__ W1l_mu, const float* __restrict__ W1r_mu,
    const float* __restrict__ b1_mu, u16* __restrict__ h_u) {
  __shared__ float At[64 * 32];
  __shared__ float Bt[64 * 32];
  int bid = blockIdx.x;
  if (bid < G1MB)
    gemm1_body<64, 32>(agg_m, x_merch, W1l_um, W1r_um, b1_um, h_m, bid * 32, At, Bt);
  else
    gemm1_body<32, 64>(agg_u, x_user, W1l_mu, W1r_mu, b1_mu, h_u, (bid - G1MB) * 32, At, Bt);
}

// ---------------- combined-weight prep: Wt = (W2 @ Wc1half)^T in bf16, plus folded biases ----------------
__global__ __launch_bounds__(256) void k_prep_comb(
    const float* __restrict__ W2l_um, const float* __restrict__ W2r_um,
    const float* __restrict__ W2l_mu, const float* __restrict__ W2r_mu,
    const float* __restrict__ b2_um, const float* __restrict__ b2_mu,
    const float* __restrict__ Wc1, const float* __restrict__ bc1,
    u16* __restrict__ WtA_u, u16* __restrict__ WtB_u,
    u16* __restrict__ WtA_m, u16* __restrict__ WtB_m,
    float* __restrict__ bias_u, float* __restrict__ bias_m) {
  int t = blockIdx.x * 256 + threadIdx.x;
  if (t < 65536) {
    int mat = t >> 14, rem = t & 16383;
    int o = rem >> 7, k = rem & 127;
    const float* W2 = mat == 0 ? W2l_mu : mat == 1 ? W2r_mu : mat == 2 ? W2l_um : W2r_um;
    const float* wc = Wc1 + (mat >= 2 ? 128 * 128 : 0) + o;
    float s = 0.f;
    #pragma unroll 4
    for (int j = 0; j < 128; ++j) s += W2[k * 128 + j] * wc[j * 128];
    u16* dst = mat == 0 ? WtA_u : mat == 1 ? WtB_u : mat == 2 ? WtA_m : WtB_m;
    dst[o * 128 + k] = bf16r(s);
  } else if (t < 65536 + 256) {
    int r = t - 65536;
    int o = r & 127;
    if (r < 128) {
      float s = 0.f;
      for (int j = 0; j < 128; ++j) s += b2_mu[j] * Wc1[j * 128 + o];
      bias_u[o] = s;
    } else {
      float s = bc1[o];  // fold bc1 into merchant-side bias
      for (int j = 0; j < 128; ++j) s += b2_um[j] * Wc1[(128 + j) * 128 + o];
      bias_m[o] = s;
    }
  }
}

// ---------------- merged layer-2 GEMM (bf16 MFMA): outb = bf16(aggb@Wtl + hb@Wtr + bias) ----------------
__global__ __launch_bounds__(256) void k_gemm2_mfma(
    const u16* __restrict__ aggb_m, const u16* __restrict__ h_m,
    const u16* __restrict__ WtA_m, const u16* __restrict__ WtB_m,
    const float* __restrict__ bias_m, u16* __restrict__ pm_b,
    const u16* __restrict__ aggb_u, const u16* __restrict__ h_u,
    const u16* __restrict__ WtA_u, const u16* __restrict__ WtB_u,
    const float* __restrict__ bias_u, u16* __restrict__ pu_b) {
  __shared__ u16 Zs[64 * 256];  // 32KB
  int tid = threadIdx.x;
  int bid = blockIdx.x;
  const u16 *aggb, *hb, *Wtl, *Wtr; const float* bias; u16* zb; int nd, r0;
  if (bid < G2MB) {
    aggb = aggb_m; hb = h_m; Wtl = WtA_m; Wtr = WtB_m; bias = bias_m; zb = pm_b;
    nd = NMV; r0 = bid * 64;
  } else {
    aggb = aggb_u; hb = h_u; Wtl = WtA_u; Wtr = WtB_u; bias = bias_u; zb = pu_b;
    nd = NUV; r0 = (bid - G2MB) * 64;
  }
  {
    int half = (tid >> 4) & 1;
    const u16* tab = half ? hb : aggb;
    #pragma unroll
    for (int it = 0; it < 8; ++it) {
      int q = tid + it * 256;
      int rl = q >> 5;
      int cc = (q & 15) ^ (rl & 7);
      int r = r0 + rl; r = r < nd ? r : nd - 1;
      const u16* src = tab + (size_t)r * 128 + cc * 8;
      u16* dst = Zs + (tid >> 6) * 512 + it * 2048;
      GLOAD_LDS16(src, dst);
    }
  }
  __syncthreads();
  int l = tid & 63, wv = tid >> 6;
  int lg = l >> 4, lr = l & 15;
  f32x4 acc[4][2];
  #pragma unroll
  for (int mt = 0; mt < 4; ++mt)
    #pragma unroll
    for (int c = 0; c < 2; ++c) acc[mt][c] = (f32x4){0.f, 0.f, 0.f, 0.f};
  #pragma unroll
  for (int cti = 0; cti < 2; ++cti) {
    int o = (wv * 2 + cti) * 16 + lr;
    const u16* wpl = Wtl + (size_t)o * 128 + lg * 8;
    const u16* wpr = Wtr + (size_t)o * 128 + lg * 8;
    s16x8 b[8];
    #pragma unroll
    for (int ks = 0; ks < 4; ++ks) b[ks] = *(const s16x8*)(wpl + ks * 32);
    #pragma unroll
    for (int ks = 0; ks < 4; ++ks) b[ks + 4] = *(const s16x8*)(wpr + ks * 32);
    #pragma unroll
    for (int mt = 0; mt < 4; ++mt) {
      int rl = mt * 16 + lr;
      int rb = rl * 512, sw = (rl & 7) << 4;
      #pragma unroll
      for (int ks = 0; ks < 8; ++ks) {
        s16x8 a = *(const s16x8*)((const char*)Zs + ((rb + ks * 64 + lg * 16) ^ sw));
        acc[mt][cti] = __builtin_amdgcn_mfma_f32_16x16x32_bf16(a, b[ks], acc[mt][cti], 0, 0, 0);
      }
    }
  }
  float bv[2];
  #pragma unroll
  for (int cti = 0; cti < 2; ++cti) bv[cti] = bias[(wv * 2 + cti) * 16 + lr];
  #pragma unroll
  for (int mt = 0; mt < 4; ++mt)
    #pragma unroll
    for (int cti = 0; cti < 2; ++cti) {
      int o = (wv * 2 + cti) * 16 + lr;
      #pragma unroll
      for (int rg = 0; rg < 4; ++rg) {
        int r = r0 + mt * 16 + lg * 4 + rg;
        if (r < nd) zb[(size_t)r * 128 + o] = bf16r(acc[mt][cti][rg] + bv[cti]);
      }
    }
}

// ---------------- edge op: out[e] = Wc2 . relu(pu[row_t[e]] + pm[col_t[e]]) + bc2 ----------------
__global__ __launch_bounds__(256) void k_edge(
    const u32* __restrict__ pu, const u32* __restrict__ pm,
    const int* __restrict__ row_t, const int* __restrict__ col_t,
    const float* __restrict__ Wc2, const float* __restrict__ bc2,
    float* __restrict__ out) {
  __shared__ float res[256];
  int tid = threadIdx.x, l = tid & 63, wv = tid >> 6;
  int lr = l & 15, g = l >> 4;
  float w2v[8];
  #pragma unroll
  for (int q = 0; q < 8; ++q) w2v[q] = Wc2[lr * 8 + q];
  int base = blockIdx.x * 256 + wv * 64;
  #pragma unroll 2
  for (int it = 0; it < 16; ++it) {
    int e = base + it * 4 + g;
    int ec = e < ETV ? e : ETV - 1;
    int r = row_t[ec], c = col_t[ec];
    u32x4 a = *(const u32x4*)(pu + (size_t)r * 64 + lr * 4);
    u32x4 b = *(const u32x4*)(pm + (size_t)c * 64 + lr * 4);
    float p = 0.f;
    #pragma unroll
    for (int q = 0; q < 4; ++q) {
      float h0 = bflo(a[q]) + bflo(b[q]);
      float h1 = bfhi(a[q]) + bfhi(b[q]);
      h0 = h0 > 0.f ? h0 : 0.f;
      h1 = h1 > 0.f ? h1 : 0.f;
      p += h0 * w2v[2 * q] + h1 * w2v[2 * q + 1];
    }
    p += __shfl_xor(p, 1); p += __shfl_xor(p, 2);
    p += __shfl_xor(p, 4); p += __shfl_xor(p, 8);
    if (lr == 0) res[wv * 64 + it * 4 + g] = p;
  }
  __syncthreads();
  int eo = blockIdx.x * 256 + tid;
  if (eo < ETV) out[eo] = res[tid] + bc2[0];
}

extern "C" void kernel_launch(void* const* d_in, const int* in_sizes, int n_in,
                              void* d_out, int out_size, void* d_ws, size_t ws_size,
                              hipStream_t stream) {
  const float* x_user  = (const float*)d_in[0];
  const float* x_merch = (const float*)d_in[1];
  const int* row_um = (const int*)d_in[2]; const int* col_um = (const int*)d_in[3];
  const int* row_mu = (const int*)d_in[4]; const int* col_mu = (const int*)d_in[5];
  const int* row_t  = (const int*)d_in[6]; const int* col_t  = (const int*)d_in[7];
  const float* W1l_um = (const float*)d_in[8];  const float* W1r_um = (const float*)d_in[9];  const float* b1_um = (const float*)d_in[10];
  const float* W1l_mu = (const float*)d_in[11]; const float* W1r_mu = (const float*)d_in[12]; const float* b1_mu = (const float*)d_in[13];
  const float* W2l_um = (const float*)d_in[14]; const float* W2r_um = (const float*)d_in[15]; const float* b2_um = (const float*)d_in[16];
  const float* W2l_mu = (const float*)d_in[17]; const float* W2r_mu = (const float*)d_in[18]; const float* b2_mu = (const float*)d_in[19];
  const float* Wc1 = (const float*)d_in[20]; const float* bc1 = (const float*)d_in[21];
  const float* Wc2 = (const float*)d_in[22]; const float* bc2 = (const float*)d_in[23];
  float* out = (float*)d_out;

  char* ws = (char*)d_ws;
  size_t p = 0;
  auto alloc = [&](size_t bytes) -> char* {
    char* r = ws + p;
    p = (p + bytes + 255) & ~(size_t)255;
    return r;
  };
  int* cnt_um = (int*)alloc((size_t)NMV * REP * 4);      // XCD-private counts -> bases
  int* cnt_mu = (int*)alloc((size_t)NUV * REP * 4);
  size_t zero_end = p;
  int* off_um = (int*)alloc((size_t)(NMV + 1) * 4);
  int* off_mu = (int*)alloc((size_t)(NUV + 1) * 4);
  int* bsum = (int*)alloc((size_t)(NCA + NCB) * 4);
  int* rank_um = (int*)alloc((size_t)NEV * 4);
  int* rank_mu = (int*)alloc((size_t)NEV * 4);
  int* srow_um = (int*)alloc((size_t)NEV * 4);
  int* srow_mu = (int*)alloc((size_t)NEV * 4);
  u32* xub = (u32*)alloc((size_t)NUV * 32 * 4);          // x_user in bf16 (packed pairs)
  float* agg_m = (float*)alloc((size_t)NMV * 64 * 4);    // layer1 merchant agg (fp32, 64 feats)
  float* agg_u = (float*)alloc((size_t)NUV * 32 * 4);    // layer1 user agg (fp32, 32 feats)
  u16* h_m   = (u16*)alloc((size_t)NMV * 128 * 2);       // bf16 hidden
  u16* h_u   = (u16*)alloc((size_t)NUV * 128 * 2);
  u16* aggb_m = (u16*)alloc((size_t)NMV * 128 * 2);      // layer2 agg (bf16)
  u16* aggb_u = (u16*)alloc((size_t)NUV * 128 * 2);
  u16* pm_b  = (u16*)alloc((size_t)NMV * 128 * 2);       // folded classifier projections (bf16)
  u16* pu_b  = (u16*)alloc((size_t)NUV * 128 * 2);
  u16* WtA_u = (u16*)alloc((size_t)128 * 128 * 2);
  u16* WtB_u = (u16*)alloc((size_t)128 * 128 * 2);
  u16* WtA_m = (u16*)alloc((size_t)128 * 128 * 2);
  u16* WtB_m = (u16*)alloc((size_t)128 * 128 * 2);
  float* bias_u = (float*)alloc(128 * 4);
  float* bias_m = (float*)alloc(128 * 4);
  if (p > ws_size) return;  // workspace too small: fail loudly via absmax

  hipMemsetAsync(d_ws, 0, zero_end, stream);
  k_prep_comb<<<257, 256, 0, stream>>>(W2l_um, W2r_um, W2l_mu, W2r_mu, b2_um, b2_mu, Wc1, bc1,
                                       WtA_u, WtB_u, WtA_m, WtB_m, bias_u, bias_m);
  k_xub<<<1024, 256, 0, stream>>>(x_user, xub, NUV * 64 / 8);
  // CSR build: XCD-private hist+rank (L2-local atomics), 3-phase scan, atomic-free scatter
  k_hist_rank_p<<<HGRID, 256, 0, stream>>>(col_um, cnt_um, rank_um, col_mu, cnt_mu, rank_mu);
  k_scan_p1<<<NCA + NCB, 1024, 0, stream>>>(cnt_um, NMV * REP, cnt_mu, NUV * REP, bsum);
  k_scan_p2<<<1, 128, 0, stream>>>(bsum, off_um, off_mu);
  k_scan_p3<<<NCA + NCB, 1024, 0, stream>>>(cnt_um, NMV * REP, off_um,
                                            cnt_mu, NUV * REP, off_mu, bsum);
  k_scatter2<<<HGRID, 256, 0, stream>>>(col_um, row_um, rank_um, cnt_um, srow_um,
                                        col_mu, row_mu, rank_mu, cnt_mu, srow_mu);
  // layer 1 (merged wide-lane aggs, merged dual GEMMs; bf16 h out)
  k_agg_l1<<<MBLK + NUV / 4, 256, 0, stream>>>(off_um, srow_um, xub, agg_m,
                                               off_mu, srow_mu, x_merch, agg_u);
  k_gemm1<<<G1MB + NUV / 32, 256, 0, stream>>>(agg_m, x_merch, W1l_um, W1r_um, b1_um, h_m,
                                               agg_u, x_user, W1l_mu, W1r_mu, b1_mu, h_u);
  // layer 2 (merged wide-lane aggs, merged MFMA GEMMs with folded classifier weights)
  k_agg_l2<<<MBLK + NUV / 4, 256, 0, stream>>>(off_um, srow_um, h_u, aggb_m,
                                               off_mu, srow_mu, h_m, aggb_u);
  k_gemm2_mfma<<<G2MB + (NUV + 63) / 64, 256, 0, stream>>>(
      aggb_m, h_m, WtA_m, WtB_m, bias_m, pm_b,
      aggb_u, h_u, WtA_u, WtB_u, bias_u, pu_b);
  // edge classifier: gather + relu + dot
  k_edge<<<(ETV + 255) / 256, 256, 0, stream>>>((const u32*)pu_b, (const u32*)pm_b,
                                                row_t, col_t, Wc2, bc2, out);
}

// Round 12
// 377.192 us; speedup vs baseline: 5.5428x; 1.0461x over previous
//
#include <hip/hip_runtime.h>
#include <hip/hip_bf16.h>

// Hetero-SAGE: plane-major XCD-private CSR build + wide-lane gather aggregation +
// bf16-MFMA GEMMs with folded classifier (layer-2 linear => z@Wc1 folded).
#define NUV 100000
#define NMV 20000
#define NEV 1000000
#define ETV 500000

#define REP 8                     // histogram replicas = XCDs (plane-major layout)
#define NCA 5                     // ceil(NMV/4096)
#define NCB 25                    // ceil(NUV/4096)
#define HGRID 1954                // ceil(2*NEV/4/256)
#define MBLK 5000                 // merchant agg blocks (NMV/4)
#define G1MB 625                  // merchant layer-1 gemm blocks (NMV/32)
#define G2MB 313                  // merchant layer-2 gemm blocks (ceil(NMV/64))

typedef unsigned short u16;
typedef unsigned int u32;
typedef __attribute__((ext_vector_type(8))) short s16x8;
typedef __attribute__((ext_vector_type(4))) float f32x4;
typedef __attribute__((ext_vector_type(4))) unsigned short u16x4;
typedef __attribute__((ext_vector_type(4))) unsigned int u32x4;

__device__ inline u16 bf16r(float f) {  // RTNE float->bf16
  u32 b = __builtin_bit_cast(u32, f);
  u32 r = b + 0x7fffu + ((b >> 16) & 1u);
  return (u16)(r >> 16);
}
__device__ inline float bflo(u32 v) { return __builtin_bit_cast(float, v << 16); }
__device__ inline float bfhi(u32 v) { return __builtin_bit_cast(float, v & 0xffff0000u); }

// physical XCD id (0..7 on MI355X); constant for a block's lifetime
__device__ inline int xcc_id() {
  unsigned x;
  asm volatile("s_getreg_b32 %0, hwreg(HW_REG_XCC_ID, 0, 8)" : "=s"(x));
  return (int)(x & 7u);
}

#define GLOAD_LDS16(src, dst) \
  __builtin_amdgcn_global_load_lds((const __attribute__((address_space(1))) void*)(src), \
                                   (__attribute__((address_space(3))) void*)(dst), 16, 0, 0)

// ---------------- CSR: XCD-private plane-major histogram + rank ----------------
// cnt layout: cnt[r*N + c], r = physical XCD id. Each plane's lines are touched by
// exactly one XCD -> atomics stay in that XCD's L2 (no cross-XCD line migration).
// rank packs the replica in bits 24..26 for the scatter kernel.
__global__ __launch_bounds__(256) void k_hist_rank_p(
    const int* __restrict__ col_um, int* __restrict__ cnt_um, int* __restrict__ rank_um,
    const int* __restrict__ col_mu, int* __restrict__ cnt_mu, int* __restrict__ rank_mu) {
  int i = (blockIdx.x * 256 + threadIdx.x) * 4;
  if (i >= 2 * NEV) return;
  int r = xcc_id();
  u32 rtag = (u32)r << 24;
  bool um = i < NEV;
  const int* col = um ? col_um : col_mu;
  int* cnt = (um ? cnt_um : cnt_mu) + r * (um ? NMV : NUV);
  int* rank = um ? rank_um : rank_mu;
  int lo = um ? i : i - NEV;
  int4 c = *(const int4*)(col + lo);
  u32 k0 = (u32)atomicAdd(&cnt[c.x], 1);
  u32 k1 = (u32)atomicAdd(&cnt[c.y], 1);
  u32 k2 = (u32)atomicAdd(&cnt[c.z], 1);
  u32 k3 = (u32)atomicAdd(&cnt[c.w], 1);
  int4 k;
  k.x = (int)(k0 | rtag); k.y = (int)(k1 | rtag);
  k.z = (int)(k2 | rtag); k.w = (int)(k3 | rtag);
  *(int4*)(rank + lo) = k;
}

// ---- S1: per-dest totals T[c] = sum_r cnt[r][c], plus per-chunk block sums ----
__global__ __launch_bounds__(1024) void k_scan_s1(const int* __restrict__ cnt_um,
                                                  const int* __restrict__ cnt_mu,
                                                  int* __restrict__ T, int* __restrict__ bsum) {
  int b = blockIdx.x;
  const int* cnt; int N; int c0; int* Tout;
  if (b < NCA) { cnt = cnt_um; N = NMV; c0 = b * 4096; Tout = T; }
  else         { cnt = cnt_mu; N = NUV; c0 = (b - NCA) * 4096; Tout = T + NMV; }
  __shared__ int wsum[16];
  int tid = threadIdx.x, lane = tid & 63, w = tid >> 6;
  int c = c0 + tid * 4;
  int4 s = make_int4(0, 0, 0, 0);
  if (c < N) {
    #pragma unroll
    for (int r = 0; r < REP; ++r) {
      int4 v = *(const int4*)(cnt + (size_t)r * N + c);
      s.x += v.x; s.y += v.y; s.z += v.z; s.w += v.w;
    }
    *(int4*)(Tout + c) = s;
  }
  int tot = s.x + s.y + s.z + s.w;
  #pragma unroll
  for (int d = 1; d < 64; d <<= 1) tot += __shfl_xor(tot, d);
  if (lane == 0) wsum[w] = tot;
  __syncthreads();
  if (tid == 0) {
    int a = 0;
    #pragma unroll
    for (int j = 0; j < 16; ++j) a += wsum[j];
    bsum[b] = a;
  }
}

// ---- S2: scan the 30 chunk sums (two segments), set sentinels ----
__global__ __launch_bounds__(128) void k_scan_s2(int* __restrict__ bsum,
                                                 int* __restrict__ off_um, int* __restrict__ off_mu) {
  int tid = threadIdx.x;
  int wv = tid >> 6, lane = tid & 63;
  if (wv == 0) {
    int v = (lane < NCA) ? bsum[lane] : 0;
    int s = v;
    #pragma unroll
    for (int d = 1; d < 64; d <<= 1) { int t = __shfl_up(s, d); if (lane >= d) s += t; }
    if (lane < NCA) bsum[lane] = s - v;
  } else {
    int v = (lane < NCB) ? bsum[NCA + lane] : 0;
    int s = v;
    #pragma unroll
    for (int d = 1; d < 64; d <<= 1) { int t = __shfl_up(s, d); if (lane >= d) s += t; }
    if (lane < NCB) bsum[NCA + lane] = s - v;
  }
  if (tid == 0) { off_um[NMV] = NEV; off_mu[NUV] = NEV; }
}

// ---- S3: off[c] = exclusive scan of T; planes rewritten in place as bases:
//          base[r][c] = off[c] + sum_{r'<r} cnt[r'][c]  (all coalesced int4) ----
__global__ __launch_bounds__(1024) void k_scan_s3(int* __restrict__ cnt_um, int* __restrict__ off_um,
                                                  int* __restrict__ cnt_mu, int* __restrict__ off_mu,
                                                  const int* __restrict__ T, const int* __restrict__ bsum) {
  int b = blockIdx.x;
  int* cnt; int N; int c0; int* offo; const int* Tin;
  if (b < NCA) { cnt = cnt_um; N = NMV; c0 = b * 4096; offo = off_um; Tin = T; }
  else         { cnt = cnt_mu; N = NUV; c0 = (b - NCA) * 4096; offo = off_mu; Tin = T + NMV; }
  int carry = bsum[b];
  __shared__ int wsum[16];
  int tid = threadIdx.x, lane = tid & 63, w = tid >> 6;
  int c = c0 + tid * 4;
  int4 tv = make_int4(0, 0, 0, 0);
  if (c < N) tv = *(const int4*)(Tin + c);
  int p1 = tv.x + tv.y, p2 = p1 + tv.z, p3 = p2 + tv.w;
  int sc = p3;
  #pragma unroll
  for (int d = 1; d < 64; d <<= 1) { int t = __shfl_up(sc, d); if (lane >= d) sc += t; }
  if (lane == 63) wsum[w] = sc;
  __syncthreads();
  if (w == 0 && lane < 16) {
    int ws_ = wsum[lane];
    #pragma unroll
    for (int d = 1; d < 16; d <<= 1) { int t = __shfl_up(ws_, d, 16); if (lane >= d) ws_ += t; }
    wsum[lane] = ws_;
  }
  __syncthreads();
  int ex = sc - p3 + (w ? wsum[w - 1] : 0) + carry;
  if (c < N) {
    *(int4*)(offo + c) = make_int4(ex, ex + tv.x, ex + p1, ex + p2);
    int4 run = make_int4(ex, ex + tv.x, ex + p1, ex + p2);
    #pragma unroll
    for (int r = 0; r < REP; ++r) {
      int4 v = *(const int4*)(cnt + (size_t)r * N + c);
      *(int4*)(cnt + (size_t)r * N + c) = run;
      run.x += v.x; run.y += v.y; run.z += v.z; run.w += v.w;
    }
  }
}

// ---------------- atomic-free scatter (plane base + packed rank) ----------------
__global__ __launch_bounds__(256) void k_scatter2(
    const int* __restrict__ col_um, const int* __restrict__ row_um,
    const int* __restrict__ rank_um, const int* __restrict__ base_um, int* __restrict__ srow_um,
    const int* __restrict__ col_mu, const int* __restrict__ row_mu,
    const int* __restrict__ rank_mu, const int* __restrict__ base_mu, int* __restrict__ srow_mu) {
  int i = (blockIdx.x * 256 + threadIdx.x) * 4;
  if (i >= 2 * NEV) return;
  bool um = i < NEV;
  const int* col = um ? col_um : col_mu;
  const int* row = um ? row_um : row_mu;
  const int* rank = um ? rank_um : rank_mu;
  const int* basep = um ? base_um : base_mu;
  int N = um ? NMV : NUV;
  int* srow = um ? srow_um : srow_mu;
  int lo = um ? i : i - NEV;
  int4 c = *(const int4*)(col + lo);
  int4 rr = *(const int4*)(row + lo);
  int4 k = *(const int4*)(rank + lo);
  u32 kx = (u32)k.x, ky = (u32)k.y, kz = (u32)k.z, kw = (u32)k.w;
  srow[basep[(int)(kx >> 24) * N + c.x] + (int)(kx & 0xFFFFFF)] = rr.x;
  srow[basep[(int)(ky >> 24) * N + c.y] + (int)(ky & 0xFFFFFF)] = rr.y;
  srow[basep[(int)(kz >> 24) * N + c.z] + (int)(kz & 0xFFFFFF)] = rr.z;
  srow[basep[(int)(kw >> 24) * N + c.w] + (int)(kw & 0xFFFFFF)] = rr.w;
}

// ---------------- x_user -> bf16 (halves layer-1 gather traffic) ----------------
__global__ __launch_bounds__(256) void k_xub(const float* __restrict__ in, u32* __restrict__ o, int n8) {
  int stride = gridDim.x * 256;
  for (int i = blockIdx.x * 256 + threadIdx.x; i < n8; i += stride) {
    float4 a = *(const float4*)(in + (size_t)i * 8);
    float4 b = *(const float4*)(in + (size_t)i * 8 + 4);
    u32x4 r;
    r[0] = (u32)bf16r(a.x) | ((u32)bf16r(a.y) << 16);
    r[1] = (u32)bf16r(a.z) | ((u32)bf16r(a.w) << 16);
    r[2] = (u32)bf16r(b.x) | ((u32)bf16r(b.y) << 16);
    r[3] = (u32)bf16r(b.z) | ((u32)bf16r(b.w) << 16);
    *(u32x4*)(o + (size_t)i * 4) = r;
  }
}

// ---------------- merged layer-1 segment-mean (wide-lane gathers) ----------------
__global__ __launch_bounds__(256) void k_agg_l1(
    const int* __restrict__ off_um, const int* __restrict__ srow_um,
    const u32* __restrict__ xub, float* __restrict__ agg_m,
    const int* __restrict__ off_mu, const int* __restrict__ srow_mu,
    const float* __restrict__ xm, float* __restrict__ agg_u) {
  int bid = blockIdx.x, tid = threadIdx.x;
  int l = tid & 63, g = l >> 3, lr = l & 7;
  if (bid < MBLK) {
    int wid = (bid * 256 + tid) >> 6;
    int s = off_um[wid], t = off_um[wid + 1];
    float a[8] = {};
    int j = s;
    for (; j + 16 <= t; j += 16) {
      int r0 = srow_um[j + g], r1 = srow_um[j + 8 + g];
      u32x4 v0 = *(const u32x4*)(xub + (size_t)r0 * 32 + lr * 4);
      u32x4 v1 = *(const u32x4*)(xub + (size_t)r1 * 32 + lr * 4);
      #pragma unroll
      for (int k = 0; k < 4; ++k) {
        a[2 * k] += bflo(v0[k]) + bflo(v1[k]);
        a[2 * k + 1] += bfhi(v0[k]) + bfhi(v1[k]);
      }
    }
    for (; j + 8 <= t; j += 8) {
      int r0 = srow_um[j + g];
      u32x4 v0 = *(const u32x4*)(xub + (size_t)r0 * 32 + lr * 4);
      #pragma unroll
      for (int k = 0; k < 4; ++k) { a[2 * k] += bflo(v0[k]); a[2 * k + 1] += bfhi(v0[k]); }
    }
    if (g < t - j) {
      int r0 = srow_um[j + g];
      u32x4 v0 = *(const u32x4*)(xub + (size_t)r0 * 32 + lr * 4);
      #pragma unroll
      for (int k = 0; k < 4; ++k) { a[2 * k] += bflo(v0[k]); a[2 * k + 1] += bfhi(v0[k]); }
    }
    #pragma unroll
    for (int k = 0; k < 8; ++k) {
      a[k] += __shfl_xor(a[k], 8);
      a[k] += __shfl_xor(a[k], 16);
      a[k] += __shfl_xor(a[k], 32);
    }
    if (g == 0) {
      float inv = 1.f / (float)max(t - s, 1);
      float4 o0 = make_float4(a[0] * inv, a[1] * inv, a[2] * inv, a[3] * inv);
      float4 o1 = make_float4(a[4] * inv, a[5] * inv, a[6] * inv, a[7] * inv);
      *(float4*)(agg_m + (size_t)wid * 64 + lr * 8) = o0;
      *(float4*)(agg_m + (size_t)wid * 64 + lr * 8 + 4) = o1;
    }
  } else {
    int wid = ((bid - MBLK) * 256 + tid) >> 6;
    int s = off_mu[wid], t = off_mu[wid + 1];
    float a[4] = {};
    int j = s;
    for (; j + 16 <= t; j += 16) {
      int r0 = srow_mu[j + g], r1 = srow_mu[j + 8 + g];
      float4 v0 = *(const float4*)(xm + (size_t)r0 * 32 + lr * 4);
      float4 v1 = *(const float4*)(xm + (size_t)r1 * 32 + lr * 4);
      a[0] += v0.x + v1.x; a[1] += v0.y + v1.y;
      a[2] += v0.z + v1.z; a[3] += v0.w + v1.w;
    }
    for (; j + 8 <= t; j += 8) {
      int r0 = srow_mu[j + g];
      float4 v0 = *(const float4*)(xm + (size_t)r0 * 32 + lr * 4);
      a[0] += v0.x; a[1] += v0.y; a[2] += v0.z; a[3] += v0.w;
    }
    if (g < t - j) {
      int r0 = srow_mu[j + g];
      float4 v0 = *(const float4*)(xm + (size_t)r0 * 32 + lr * 4);
      a[0] += v0.x; a[1] += v0.y; a[2] += v0.z; a[3] += v0.w;
    }
    #pragma unroll
    for (int k = 0; k < 4; ++k) {
      a[k] += __shfl_xor(a[k], 8);
      a[k] += __shfl_xor(a[k], 16);
      a[k] += __shfl_xor(a[k], 32);
    }
    if (g == 0) {
      float inv = 1.f / (float)max(t - s, 1);
      *(float4*)(agg_u + (size_t)wid * 32 + lr * 4) =
          make_float4(a[0] * inv, a[1] * inv, a[2] * inv, a[3] * inv);
    }
  }
}

// ---------------- merged layer-2 segment-mean (wide-lane bf16 gather) ----------------
__global__ __launch_bounds__(256) void k_agg_l2(
    const int* __restrict__ off_um, const int* __restrict__ srow_um,
    const u16* __restrict__ h_u, u16* __restrict__ aggb_m,
    const int* __restrict__ off_mu, const int* __restrict__ srow_mu,
    const u16* __restrict__ h_m, u16* __restrict__ aggb_u) {
  int bid = blockIdx.x, tid = threadIdx.x;
  const int* off; const int* srow; const u32* x; u32* ag; int wid;
  if (bid < MBLK) {
    off = off_um; srow = srow_um; x = (const u32*)h_u; ag = (u32*)aggb_m;
    wid = (bid * 256 + tid) >> 6;
  } else {
    off = off_mu; srow = srow_mu; x = (const u32*)h_m; ag = (u32*)aggb_u;
    wid = ((bid - MBLK) * 256 + tid) >> 6;
  }
  int l = tid & 63, g = l >> 4, lr = l & 15;
  int s = off[wid], t = off[wid + 1];
  float a[8] = {};
  int j = s;
  for (; j + 8 <= t; j += 8) {
    int r0 = srow[j + g], r1 = srow[j + 4 + g];
    u32x4 v0 = *(const u32x4*)(x + (size_t)r0 * 64 + lr * 4);
    u32x4 v1 = *(const u32x4*)(x + (size_t)r1 * 64 + lr * 4);
    #pragma unroll
    for (int k = 0; k < 4; ++k) {
      a[2 * k] += bflo(v0[k]) + bflo(v1[k]);
      a[2 * k + 1] += bfhi(v0[k]) + bfhi(v1[k]);
    }
  }
  for (; j + 4 <= t; j += 4) {
    int r0 = srow[j + g];
    u32x4 v0 = *(const u32x4*)(x + (size_t)r0 * 64 + lr * 4);
    #pragma unroll
    for (int k = 0; k < 4; ++k) { a[2 * k] += bflo(v0[k]); a[2 * k + 1] += bfhi(v0[k]); }
  }
  if (g < t - j) {
    int r0 = srow[j + g];
    u32x4 v0 = *(const u32x4*)(x + (size_t)r0 * 64 + lr * 4);
    #pragma unroll
    for (int k = 0; k < 4; ++k) { a[2 * k] += bflo(v0[k]); a[2 * k + 1] += bfhi(v0[k]); }
  }
  #pragma unroll
  for (int k = 0; k < 8; ++k) {
    a[k] += __shfl_xor(a[k], 16);
    a[k] += __shfl_xor(a[k], 32);
  }
  if (g == 0) {
    float inv = 1.f / (float)max(t - s, 1);
    u32x4 o;
    #pragma unroll
    for (int k = 0; k < 4; ++k)
      o[k] = (u32)bf16r(a[2 * k] * inv) | ((u32)bf16r(a[2 * k + 1] * inv) << 16);
    *(u32x4*)(ag + (size_t)wid * 64 + lr * 4) = o;
  }
}

// ---------------- layer-1 dual GEMM body (fp32 in, bf16 out) ----------------
template <int KA, int KB>
__device__ inline void gemm1_body(const float* __restrict__ A, const float* __restrict__ B,
                                  const float* __restrict__ Wa, const float* __restrict__ Wb,
                                  const float* __restrict__ bias, u16* __restrict__ outb,
                                  int m0, float* At, float* Bt) {
  int tid = threadIdx.x;
  {
    int m = tid & 31, kq = tid >> 5;
    const float* Ar = A + (size_t)(m0 + m) * KA;
    for (int k0 = kq * 4; k0 < KA; k0 += 32) {
      float4 v = *(const float4*)(Ar + k0);
      At[(k0 + 0) * 32 + m] = v.x; At[(k0 + 1) * 32 + m] = v.y;
      At[(k0 + 2) * 32 + m] = v.z; At[(k0 + 3) * 32 + m] = v.w;
    }
    const float* Br = B + (size_t)(m0 + m) * KB;
    for (int k0 = kq * 4; k0 < KB; k0 += 32) {
      float4 v = *(const float4*)(Br + k0);
      Bt[(k0 + 0) * 32 + m] = v.x; Bt[(k0 + 1) * 32 + m] = v.y;
      Bt[(k0 + 2) * 32 + m] = v.z; Bt[(k0 + 3) * 32 + m] = v.w;
    }
  }
  __syncthreads();
  int tx = tid & 31, ty = tid >> 5;
  float acc[4][4] = {};
  #pragma unroll 4
  for (int k = 0; k < KA; ++k) {
    float4 wv = *(const float4*)(Wa + k * 128 + tx * 4);
    float4 av = *(const float4*)(&At[k * 32 + ty * 4]);
    float am[4] = {av.x, av.y, av.z, av.w};
    float wo[4] = {wv.x, wv.y, wv.z, wv.w};
    #pragma unroll
    for (int mi = 0; mi < 4; ++mi)
      #pragma unroll
      for (int oi = 0; oi < 4; ++oi) acc[mi][oi] += am[mi] * wo[oi];
  }
  #pragma unroll 4
  for (int k = 0; k < KB; ++k) {
    float4 wv = *(const float4*)(Wb + k * 128 + tx * 4);
    float4 av = *(const float4*)(&Bt[k * 32 + ty * 4]);
    float am[4] = {av.x, av.y, av.z, av.w};
    float wo[4] = {wv.x, wv.y, wv.z, wv.w};
    #pragma unroll
    for (int mi = 0; mi < 4; ++mi)
      #pragma unroll
      for (int oi = 0; oi < 4; ++oi) acc[mi][oi] += am[mi] * wo[oi];
  }
  float4 bv = *(const float4*)(bias + tx * 4);
  float bb[4] = {bv.x, bv.y, bv.z, bv.w};
  #pragma unroll
  for (int mi = 0; mi < 4; ++mi) {
    u16x4 o;
    #pragma unroll
    for (int oi = 0; oi < 4; ++oi) {
      float v = acc[mi][oi] + bb[oi];
      v = v > 0.f ? v : 0.f;  // layer-1 relu
      o[oi] = bf16r(v);
    }
    *(u16x4*)(outb + (size_t)(m0 + ty * 4 + mi) * 128 + tx * 4) = o;
  }
}

// merged layer-1 GEMM: blocks [0,G1MB) merchant <64,32>, rest user <32,64>
__global__ __launch_bounds__(256) void k_gemm1(
    const float* __restrict__ agg_m, const float* __restrict__ x_merch,
    const float* __restrict__ W1l_um, const float* __restrict__ W1r_um,
    const float* __restrict__ b1_um, u16* __restrict__ h_m,
    const float* __restrict__ agg_u, const float* __restrict__ x_user,
    const float* __restrict__ W1l_mu, const float* __restrict__ W1r_mu,
    const float* __restrict__ b1_mu, u16* __restrict__ h_u) {
  __shared__ float At[64 * 32];
  __shared__ float Bt[64 * 32];
  int bid = blockIdx.x;
  if (bid < G1MB)
    gemm1_body<64, 32>(agg_m, x_merch, W1l_um, W1r_um, b1_um, h_m, bid * 32, At, Bt);
  else
    gemm1_body<32, 64>(agg_u, x_user, W1l_mu, W1r_mu, b1_mu, h_u, (bid - G1MB) * 32, At, Bt);
}

// ---------------- combined-weight prep: Wt = (W2 @ Wc1half)^T in bf16, plus folded biases ----------------
__global__ __launch_bounds__(256) void k_prep_comb(
    const float* __restrict__ W2l_um, const float* __restrict__ W2r_um,
    const float* __restrict__ W2l_mu, const float* __restrict__ W2r_mu,
    const float* __restrict__ b2_um, const float* __restrict__ b2_mu,
    const float* __restrict__ Wc1, const float* __restrict__ bc1,
    u16* __restrict__ WtA_u, u16* __restrict__ WtB_u,
    u16* __restrict__ WtA_m, u16* __restrict__ WtB_m,
    float* __restrict__ bias_u, float* __restrict__ bias_m) {
  int t = blockIdx.x * 256 + threadIdx.x;
  if (t < 65536) {
    int mat = t >> 14, rem = t & 16383;
    int o = rem >> 7, k = rem & 127;
    const float* W2 = mat == 0 ? W2l_mu : mat == 1 ? W2r_mu : mat == 2 ? W2l_um : W2r_um;
    const float* wc = Wc1 + (mat >= 2 ? 128 * 128 : 0) + o;
    float s = 0.f;
    #pragma unroll 4
    for (int j = 0; j < 128; ++j) s += W2[k * 128 + j] * wc[j * 128];
    u16* dst = mat == 0 ? WtA_u : mat == 1 ? WtB_u : mat == 2 ? WtA_m : WtB_m;
    dst[o * 128 + k] = bf16r(s);
  } else if (t < 65536 + 256) {
    int r = t - 65536;
    int o = r & 127;
    if (r < 128) {
      float s = 0.f;
      for (int j = 0; j < 128; ++j) s += b2_mu[j] * Wc1[j * 128 + o];
      bias_u[o] = s;
    } else {
      float s = bc1[o];  // fold bc1 into merchant-side bias
      for (int j = 0; j < 128; ++j) s += b2_um[j] * Wc1[(128 + j) * 128 + o];
      bias_m[o] = s;
    }
  }
}

// ---------------- merged layer-2 GEMM (bf16 MFMA): outb = bf16(aggb@Wtl + hb@Wtr + bias) ----------------
__global__ __launch_bounds__(256) void k_gemm2_mfma(
    const u16* __restrict__ aggb_m, const u16* __restrict__ h_m,
    const u16* __restrict__ WtA_m, const u16* __restrict__ WtB_m,
    const float* __restrict__ bias_m, u16* __restrict__ pm_b,
    const u16* __restrict__ aggb_u, const u16* __restrict__ h_u,
    const u16* __restrict__ WtA_u, const u16* __restrict__ WtB_u,
    const float* __restrict__ bias_u, u16* __restrict__ pu_b) {
  __shared__ u16 Zs[64 * 256];  // 32KB
  int tid = threadIdx.x;
  int bid = blockIdx.x;
  const u16 *aggb, *hb, *Wtl, *Wtr; const float* bias; u16* zb; int nd, r0;
  if (bid < G2MB) {
    aggb = aggb_m; hb = h_m; Wtl = WtA_m; Wtr = WtB_m; bias = bias_m; zb = pm_b;
    nd = NMV; r0 = bid * 64;
  } else {
    aggb = aggb_u; hb = h_u; Wtl = WtA_u; Wtr = WtB_u; bias = bias_u; zb = pu_b;
    nd = NUV; r0 = (bid - G2MB) * 64;
  }
  {
    int half = (tid >> 4) & 1;
    const u16* tab = half ? hb : aggb;
    #pragma unroll
    for (int it = 0; it < 8; ++it) {
      int q = tid + it * 256;
      int rl = q >> 5;
      int cc = (q & 15) ^ (rl & 7);
      int r = r0 + rl; r = r < nd ? r : nd - 1;
      const u16* src = tab + (size_t)r * 128 + cc * 8;
      u16* dst = Zs + (tid >> 6) * 512 + it * 2048;
      GLOAD_LDS16(src, dst);
    }
  }
  __syncthreads();
  int l = tid & 63, wv = tid >> 6;
  int lg = l >> 4, lr = l & 15;
  f32x4 acc[4][2];
  #pragma unroll
  for (int mt = 0; mt < 4; ++mt)
    #pragma unroll
    for (int c = 0; c < 2; ++c) acc[mt][c] = (f32x4){0.f, 0.f, 0.f, 0.f};
  #pragma unroll
  for (int cti = 0; cti < 2; ++cti) {
    int o = (wv * 2 + cti) * 16 + lr;
    const u16* wpl = Wtl + (size_t)o * 128 + lg * 8;
    const u16* wpr = Wtr + (size_t)o * 128 + lg * 8;
    s16x8 b[8];
    #pragma unroll
    for (int ks = 0; ks < 4; ++ks) b[ks] = *(const s16x8*)(wpl + ks * 32);
    #pragma unroll
    for (int ks = 0; ks < 4; ++ks) b[ks + 4] = *(const s16x8*)(wpr + ks * 32);
    #pragma unroll
    for (int mt = 0; mt < 4; ++mt) {
      int rl = mt * 16 + lr;
      int rb = rl * 512, sw = (rl & 7) << 4;
      #pragma unroll
      for (int ks = 0; ks < 8; ++ks) {
        s16x8 a = *(const s16x8*)((const char*)Zs + ((rb + ks * 64 + lg * 16) ^ sw));
        acc[mt][cti] = __builtin_amdgcn_mfma_f32_16x16x32_bf16(a, b[ks], acc[mt][cti], 0, 0, 0);
      }
    }
  }
  float bv[2];
  #pragma unroll
  for (int cti = 0; cti < 2; ++cti) bv[cti] = bias[(wv * 2 + cti) * 16 + lr];
  #pragma unroll
  for (int mt = 0; mt < 4; ++mt)
    #pragma unroll
    for (int cti = 0; cti < 2; ++cti) {
      int o = (wv * 2 + cti) * 16 + lr;
      #pragma unroll
      for (int rg = 0; rg < 4; ++rg) {
        int r = r0 + mt * 16 + lg * 4 + rg;
        if (r < nd) zb[(size_t)r * 128 + o] = bf16r(acc[mt][cti][rg] + bv[cti]);
      }
    }
}

// ---------------- edge op: out[e] = Wc2 . relu(pu[row_t[e]] + pm[col_t[e]]) + bc2 ----------------
__global__ __launch_bounds__(256) void k_edge(
    const u32* __restrict__ pu, const u32* __restrict__ pm,
    const int* __restrict__ row_t, const int* __restrict__ col_t,
    const float* __restrict__ Wc2, const float* __restrict__ bc2,
    float* __restrict__ out) {
  __shared__ float res[256];
  int tid = threadIdx.x, l = tid & 63, wv = tid >> 6;
  int lr = l & 15, g = l >> 4;
  float w2v[8];
  #pragma unroll
  for (int q = 0; q < 8; ++q) w2v[q] = Wc2[lr * 8 + q];
  int base = blockIdx.x * 256 + wv * 64;
  #pragma unroll 2
  for (int it = 0; it < 16; ++it) {
    int e = base + it * 4 + g;
    int ec = e < ETV ? e : ETV - 1;
    int r = row_t[ec], c = col_t[ec];
    u32x4 a = *(const u32x4*)(pu + (size_t)r * 64 + lr * 4);
    u32x4 b = *(const u32x4*)(pm + (size_t)c * 64 + lr * 4);
    float p = 0.f;
    #pragma unroll
    for (int q = 0; q < 4; ++q) {
      float h0 = bflo(a[q]) + bflo(b[q]);
      float h1 = bfhi(a[q]) + bfhi(b[q]);
      h0 = h0 > 0.f ? h0 : 0.f;
      h1 = h1 > 0.f ? h1 : 0.f;
      p += h0 * w2v[2 * q] + h1 * w2v[2 * q + 1];
    }
    p += __shfl_xor(p, 1); p += __shfl_xor(p, 2);
    p += __shfl_xor(p, 4); p += __shfl_xor(p, 8);
    if (lr == 0) res[wv * 64 + it * 4 + g] = p;
  }
  __syncthreads();
  int eo = blockIdx.x * 256 + tid;
  if (eo < ETV) out[eo] = res[tid] + bc2[0];
}

extern "C" void kernel_launch(void* const* d_in, const int* in_sizes, int n_in,
                              void* d_out, int out_size, void* d_ws, size_t ws_size,
                              hipStream_t stream) {
  const float* x_user  = (const float*)d_in[0];
  const float* x_merch = (const float*)d_in[1];
  const int* row_um = (const int*)d_in[2]; const int* col_um = (const int*)d_in[3];
  const int* row_mu = (const int*)d_in[4]; const int* col_mu = (const int*)d_in[5];
  const int* row_t  = (const int*)d_in[6]; const int* col_t  = (const int*)d_in[7];
  const float* W1l_um = (const float*)d_in[8];  const float* W1r_um = (const float*)d_in[9];  const float* b1_um = (const float*)d_in[10];
  const float* W1l_mu = (const float*)d_in[11]; const float* W1r_mu = (const float*)d_in[12]; const float* b1_mu = (const float*)d_in[13];
  const float* W2l_um = (const float*)d_in[14]; const float* W2r_um = (const float*)d_in[15]; const float* b2_um = (const float*)d_in[16];
  const float* W2l_mu = (const float*)d_in[17]; const float* W2r_mu = (const float*)d_in[18]; const float* b2_mu = (const float*)d_in[19];
  const float* Wc1 = (const float*)d_in[20]; const float* bc1 = (const float*)d_in[21];
  const float* Wc2 = (const float*)d_in[22]; const float* bc2 = (const float*)d_in[23];
  float* out = (float*)d_out;

  char* ws = (char*)d_ws;
  size_t p = 0;
  auto alloc = [&](size_t bytes) -> char* {
    char* r = ws + p;
    p = (p + bytes + 255) & ~(size_t)255;
    return r;
  };
  int* cnt_um = (int*)alloc((size_t)NMV * REP * 4);      // plane-major XCD-private counts -> bases
  int* cnt_mu = (int*)alloc((size_t)NUV * REP * 4);
  size_t zero_end = p;
  int* off_um = (int*)alloc((size_t)(NMV + 4) * 4);
  int* off_mu = (int*)alloc((size_t)(NUV + 4) * 4);
  int* T    = (int*)alloc((size_t)(NMV + NUV) * 4);
  int* bsum = (int*)alloc((size_t)(NCA + NCB) * 4);
  int* rank_um = (int*)alloc((size_t)NEV * 4);
  int* rank_mu = (int*)alloc((size_t)NEV * 4);
  int* srow_um = (int*)alloc((size_t)NEV * 4);
  int* srow_mu = (int*)alloc((size_t)NEV * 4);
  u32* xub = (u32*)alloc((size_t)NUV * 32 * 4);          // x_user in bf16 (packed pairs)
  float* agg_m = (float*)alloc((size_t)NMV * 64 * 4);    // layer1 merchant agg (fp32, 64 feats)
  float* agg_u = (float*)alloc((size_t)NUV * 32 * 4);    // layer1 user agg (fp32, 32 feats)
  u16* h_m   = (u16*)alloc((size_t)NMV * 128 * 2);       // bf16 hidden
  u16* h_u   = (u16*)alloc((size_t)NUV * 128 * 2);
  u16* aggb_m = (u16*)alloc((size_t)NMV * 128 * 2);      // layer2 agg (bf16)
  u16* aggb_u = (u16*)alloc((size_t)NUV * 128 * 2);
  u16* pm_b  = (u16*)alloc((size_t)NMV * 128 * 2);       // folded classifier projections (bf16)
  u16* pu_b  = (u16*)alloc((size_t)NUV * 128 * 2);
  u16* WtA_u = (u16*)alloc((size_t)128 * 128 * 2);
  u16* WtB_u = (u16*)alloc((size_t)128 * 128 * 2);
  u16* WtA_m = (u16*)alloc((size_t)128 * 128 * 2);
  u16* WtB_m = (u16*)alloc((size_t)128 * 128 * 2);
  float* bias_u = (float*)alloc(128 * 4);
  float* bias_m = (float*)alloc(128 * 4);
  if (p > ws_size) return;  // workspace too small: fail loudly via absmax

  hipMemsetAsync(d_ws, 0, zero_end, stream);
  k_prep_comb<<<257, 256, 0, stream>>>(W2l_um, W2r_um, W2l_mu, W2r_mu, b2_um, b2_mu, Wc1, bc1,
                                       WtA_u, WtB_u, WtA_m, WtB_m, bias_u, bias_m);
  k_xub<<<1024, 256, 0, stream>>>(x_user, xub, NUV * 64 / 8);
  // CSR build: plane-major XCD-private hist+rank, totals/scan/base, atomic-free scatter
  k_hist_rank_p<<<HGRID, 256, 0, stream>>>(col_um, cnt_um, rank_um, col_mu, cnt_mu, rank_mu);
  k_scan_s1<<<NCA + NCB, 1024, 0, stream>>>(cnt_um, cnt_mu, T, bsum);
  k_scan_s2<<<1, 128, 0, stream>>>(bsum, off_um, off_mu);
  k_scan_s3<<<NCA + NCB, 1024, 0, stream>>>(cnt_um, off_um, cnt_mu, off_mu, T, bsum);
  k_scatter2<<<HGRID, 256, 0, stream>>>(col_um, row_um, rank_um, cnt_um, srow_um,
                                        col_mu, row_mu, rank_mu, cnt_mu, srow_mu);
  // layer 1 (merged wide-lane aggs, merged dual GEMMs; bf16 h out)
  k_agg_l1<<<MBLK + NUV / 4, 256, 0, stream>>>(off_um, srow_um, xub, agg_m,
                                               off_mu, srow_mu, x_merch, agg_u);
  k_gemm1<<<G1MB + NUV / 32, 256, 0, stream>>>(agg_m, x_merch, W1l_um, W1r_um, b1_um, h_m,
                                               agg_u, x_user, W1l_mu, W1r_mu, b1_mu, h_u);
  // layer 2 (merged wide-lane aggs, merged MFMA GEMMs with folded classifier weights)
  k_agg_l2<<<MBLK + NUV / 4, 256, 0, stream>>>(off_um, srow_um, h_u, aggb_m,
                                               off_mu, srow_mu, h_m, aggb_u);
  k_gemm2_mfma<<<G2MB + (NUV + 63) / 64, 256, 0, stream>>>(
      aggb_m, h_m, WtA_m, WtB_m, bias_m, pm_b,
      aggb_u, h_u, WtA_u, WtB_u, bias_u, pu_b);
  // edge classifier: gather + relu + dot
  k_edge<<<(ETV + 255) / 256, 256, 0, stream>>>((const u32*)pu_b, (const u32*)pm_b,
                                                row_t, col_t, Wc2, bc2, out);
}

// Round 13
// 336.921 us; speedup vs baseline: 6.2053x; 1.1195x over previous
//
#include <hip/hip_runtime.h>
#include <hip/hip_bf16.h>

// Hetero-SAGE: LDS-histogram CSR build (zero global atomics) + wide-lane gather
// aggregation + bf16-MFMA GEMMs with folded classifier (z@Wc1 folded into layer 2).
#define NUV 100000
#define NMV 20000
#define NEV 1000000
#define ETV 500000

#define CHK 8192                  // edges per histogram chunk (2^13)
#define NCH 123                   // ceil(NEV/CHK)
#define WNM 5000                  // merchant hist words (20000 dests / 4 per word)
#define WNU 25000                 // user hist words (100000 / 4)
#define NCA 5                     // merchant scan chunks (4096 dests each)
#define NCB 25                    // user scan chunks
#define HGRID 1954                // ceil(2*NEV/4/256)
#define MBLK 5000                 // merchant agg blocks (NMV/4)
#define G1MB 625                  // merchant layer-1 gemm blocks (NMV/32)
#define G2MB 313                  // merchant layer-2 gemm blocks (ceil(NMV/64))

typedef unsigned short u16;
typedef unsigned int u32;
typedef __attribute__((ext_vector_type(8))) short s16x8;
typedef __attribute__((ext_vector_type(4))) float f32x4;
typedef __attribute__((ext_vector_type(4))) unsigned short u16x4;
typedef __attribute__((ext_vector_type(4))) unsigned int u32x4;

__device__ inline u16 bf16r(float f) {  // RTNE float->bf16
  u32 b = __builtin_bit_cast(u32, f);
  u32 r = b + 0x7fffu + ((b >> 16) & 1u);
  return (u16)(r >> 16);
}
__device__ inline float bflo(u32 v) { return __builtin_bit_cast(float, v << 16); }
__device__ inline float bfhi(u32 v) { return __builtin_bit_cast(float, v & 0xffff0000u); }

#define GLOAD_LDS16(src, dst) \
  __builtin_amdgcn_global_load_lds((const __attribute__((address_space(1))) void*)(src), \
                                   (__attribute__((address_space(3))) void*)(dst), 16, 0, 0)

// ---------------- CSR: chunk-local LDS histogram + rank (NO global atomics) ------
// Byte counters packed 4-per-word in LDS. rank = returned byte (chunk-local rank
// within (chunk,dest)); 4 edge-ranks packed per u32 in rankp.
__global__ __launch_bounds__(512) void k_hist_lds(
    const int* __restrict__ col_um, u32* __restrict__ rankp_um, u32* __restrict__ cnt_um,
    const int* __restrict__ col_mu, u32* __restrict__ rankp_mu, u32* __restrict__ cnt_mu) {
  __shared__ u32 hist[WNU];  // 100KB (merchant blocks use first WNM words)
  int bid = blockIdx.x, tid = threadIdx.x;
  bool um = bid < NCH;
  const int* col = um ? col_um : col_mu;
  u32* rankp = um ? rankp_um : rankp_mu;
  u32* cntp = um ? cnt_um : cnt_mu;
  int Wn = um ? WNM : WNU;
  int blk = um ? bid : bid - NCH;
  int e0 = blk * CHK;
  for (int i = tid; i < Wn; i += 512) hist[i] = 0;
  __syncthreads();
  #pragma unroll
  for (int it = 0; it < CHK / 2048; ++it) {
    int li = e0 + (it * 512 + tid) * 4;
    if (li < NEV) {  // NEV % 4 == 0 -> int4 safe
      int4 c = *(const int4*)(col + li);
      int cc[4] = {c.x, c.y, c.z, c.w};
      u32 pk = 0;
      #pragma unroll
      for (int q = 0; q < 4; ++q) {
        int d = cc[q];
        int sh = 8 * (d & 3);
        u32 old = atomicAdd(&hist[d >> 2], 1u << sh);
        pk |= ((old >> sh) & 0xFFu) << (8 * q);
      }
      rankp[li >> 2] = pk;
    }
  }
  __syncthreads();
  u32* dst = cntp + (size_t)blk * Wn;
  for (int i = tid; i < Wn; i += 512) dst[i] = hist[i];
}

// ---- S1: per-dest prefix over chunks (bytes) + per-dest totals T + chunk sums ----
__global__ __launch_bounds__(1024) void k_scan_s1(
    const u32* __restrict__ cnt_um, u32* __restrict__ pre_um,
    const u32* __restrict__ cnt_mu, u32* __restrict__ pre_mu,
    int* __restrict__ T, int* __restrict__ bsum) {
  int b = blockIdx.x;
  const u32* cnt; u32* pre; int Wn; int w0; int* Tout;
  if (b < NCA) { cnt = cnt_um; pre = pre_um; Wn = WNM; w0 = b * 1024; Tout = T; }
  else         { cnt = cnt_mu; pre = pre_mu; Wn = WNU; w0 = (b - NCA) * 1024; Tout = T + NMV; }
  __shared__ int wsum[16];
  int tid = threadIdx.x, lane = tid & 63, w = tid >> 6;
  int wd = w0 + tid;
  int r0 = 0, r1 = 0, r2 = 0, r3 = 0;
  if (wd < Wn) {
    #pragma unroll 4
    for (int bb = 0; bb < NCH; ++bb) {
      u32 v = cnt[(size_t)bb * Wn + wd];
      pre[(size_t)bb * Wn + wd] =
          (u32)r0 | ((u32)r1 << 8) | ((u32)r2 << 16) | ((u32)r3 << 24);
      r0 += v & 0xFF; r1 += (v >> 8) & 0xFF; r2 += (v >> 16) & 0xFF; r3 += (v >> 24) & 0xFF;
    }
    *(int4*)(Tout + wd * 4) = make_int4(r0, r1, r2, r3);
  }
  int tot = r0 + r1 + r2 + r3;
  #pragma unroll
  for (int d = 1; d < 64; d <<= 1) tot += __shfl_xor(tot, d);
  if (lane == 0) wsum[w] = tot;
  __syncthreads();
  if (tid == 0) {
    int a = 0;
    #pragma unroll
    for (int j = 0; j < 16; ++j) a += wsum[j];
    bsum[b] = a;
  }
}

// ---- S2: scan the 30 chunk sums (two segments), set sentinels ----
__global__ __launch_bounds__(128) void k_scan_s2(int* __restrict__ bsum,
                                                 int* __restrict__ off_um, int* __restrict__ off_mu) {
  int tid = threadIdx.x;
  int wv = tid >> 6, lane = tid & 63;
  if (wv == 0) {
    int v = (lane < NCA) ? bsum[lane] : 0;
    int s = v;
    #pragma unroll
    for (int d = 1; d < 64; d <<= 1) { int t = __shfl_up(s, d); if (lane >= d) s += t; }
    if (lane < NCA) bsum[lane] = s - v;
  } else {
    int v = (lane < NCB) ? bsum[NCA + lane] : 0;
    int s = v;
    #pragma unroll
    for (int d = 1; d < 64; d <<= 1) { int t = __shfl_up(s, d); if (lane >= d) s += t; }
    if (lane < NCB) bsum[NCA + lane] = s - v;
  }
  if (tid == 0) { off_um[NMV] = NEV; off_mu[NUV] = NEV; }
}

// ---- S3: off[c] = exclusive scan of T (per 4096-dest chunk, carry from bsum) ----
__global__ __launch_bounds__(1024) void k_scan_s3(int* __restrict__ off_um,
                                                  int* __restrict__ off_mu,
                                                  const int* __restrict__ T,
                                                  const int* __restrict__ bsum) {
  int b = blockIdx.x;
  int N; int c0; int* offo; const int* Tin;
  if (b < NCA) { N = NMV; c0 = b * 4096; offo = off_um; Tin = T; }
  else         { N = NUV; c0 = (b - NCA) * 4096; offo = off_mu; Tin = T + NMV; }
  int carry = bsum[b];
  __shared__ int wsum[16];
  int tid = threadIdx.x, lane = tid & 63, w = tid >> 6;
  int c = c0 + tid * 4;
  int4 tv = make_int4(0, 0, 0, 0);
  if (c < N) tv = *(const int4*)(Tin + c);
  int p1 = tv.x + tv.y, p2 = p1 + tv.z, p3 = p2 + tv.w;
  int sc = p3;
  #pragma unroll
  for (int d = 1; d < 64; d <<= 1) { int t = __shfl_up(sc, d); if (lane >= d) sc += t; }
  if (lane == 63) wsum[w] = sc;
  __syncthreads();
  if (w == 0 && lane < 16) {
    int ws_ = wsum[lane];
    #pragma unroll
    for (int d = 1; d < 16; d <<= 1) { int t = __shfl_up(ws_, d, 16); if (lane >= d) ws_ += t; }
    wsum[lane] = ws_;
  }
  __syncthreads();
  int ex = sc - p3 + (w ? wsum[w - 1] : 0) + carry;
  if (c < N) *(int4*)(offo + c) = make_int4(ex, ex + tv.x, ex + p1, ex + p2);
}

// ---------------- atomic-free scatter: pos = off[c] + pre2d[chunk][c] + rank ------
__global__ __launch_bounds__(256) void k_scatter3(
    const int* __restrict__ col_um, const int* __restrict__ row_um,
    const u32* __restrict__ rankp_um, const u32* __restrict__ pre_um,
    const int* __restrict__ off_um, int* __restrict__ srow_um,
    const int* __restrict__ col_mu, const int* __restrict__ row_mu,
    const u32* __restrict__ rankp_mu, const u32* __restrict__ pre_mu,
    const int* __restrict__ off_mu, int* __restrict__ srow_mu) {
  int i = (blockIdx.x * 256 + threadIdx.x) * 4;
  if (i >= 2 * NEV) return;
  bool um = i < NEV;
  const int* col = um ? col_um : col_mu;
  const int* row = um ? row_um : row_mu;
  const u32* rankp = um ? rankp_um : rankp_mu;
  const u32* pre = um ? pre_um : pre_mu;
  const int* off = um ? off_um : off_mu;
  int Wn = um ? WNM : WNU;
  int* srow = um ? srow_um : srow_mu;
  int lo = um ? i : i - NEV;
  int blk = lo >> 13;  // CHK = 8192
  const u32* prep = pre + (size_t)blk * Wn;
  int4 c = *(const int4*)(col + lo);
  int4 rr = *(const int4*)(row + lo);
  u32 pk = rankp[lo >> 2];
  int cc[4] = {c.x, c.y, c.z, c.w}, rv[4] = {rr.x, rr.y, rr.z, rr.w};
  #pragma unroll
  for (int q = 0; q < 4; ++q) {
    int d = cc[q];
    int prefix = (int)((prep[d >> 2] >> (8 * (d & 3))) & 0xFF);
    int rank = (int)((pk >> (8 * q)) & 0xFF);
    srow[off[d] + prefix + rank] = rv[q];
  }
}

// ---------------- x_user -> bf16 (halves layer-1 gather traffic) ----------------
__global__ __launch_bounds__(256) void k_xub(const float* __restrict__ in, u32* __restrict__ o, int n8) {
  int stride = gridDim.x * 256;
  for (int i = blockIdx.x * 256 + threadIdx.x; i < n8; i += stride) {
    float4 a = *(const float4*)(in + (size_t)i * 8);
    float4 b = *(const float4*)(in + (size_t)i * 8 + 4);
    u32x4 r;
    r[0] = (u32)bf16r(a.x) | ((u32)bf16r(a.y) << 16);
    r[1] = (u32)bf16r(a.z) | ((u32)bf16r(a.w) << 16);
    r[2] = (u32)bf16r(b.x) | ((u32)bf16r(b.y) << 16);
    r[3] = (u32)bf16r(b.z) | ((u32)bf16r(b.w) << 16);
    *(u32x4*)(o + (size_t)i * 4) = r;
  }
}

// ---------------- merged layer-1 segment-mean (wide-lane gathers) ----------------
__global__ __launch_bounds__(256) void k_agg_l1(
    const int* __restrict__ off_um, const int* __restrict__ srow_um,
    const u32* __restrict__ xub, float* __restrict__ agg_m,
    const int* __restrict__ off_mu, const int* __restrict__ srow_mu,
    const float* __restrict__ xm, float* __restrict__ agg_u) {
  int bid = blockIdx.x, tid = threadIdx.x;
  int l = tid & 63, g = l >> 3, lr = l & 7;
  if (bid < MBLK) {
    int wid = (bid * 256 + tid) >> 6;
    int s = off_um[wid], t = off_um[wid + 1];
    float a[8] = {};
    int j = s;
    for (; j + 16 <= t; j += 16) {
      int r0 = srow_um[j + g], r1 = srow_um[j + 8 + g];
      u32x4 v0 = *(const u32x4*)(xub + (size_t)r0 * 32 + lr * 4);
      u32x4 v1 = *(const u32x4*)(xub + (size_t)r1 * 32 + lr * 4);
      #pragma unroll
      for (int k = 0; k < 4; ++k) {
        a[2 * k] += bflo(v0[k]) + bflo(v1[k]);
        a[2 * k + 1] += bfhi(v0[k]) + bfhi(v1[k]);
      }
    }
    for (; j + 8 <= t; j += 8) {
      int r0 = srow_um[j + g];
      u32x4 v0 = *(const u32x4*)(xub + (size_t)r0 * 32 + lr * 4);
      #pragma unroll
      for (int k = 0; k < 4; ++k) { a[2 * k] += bflo(v0[k]); a[2 * k + 1] += bfhi(v0[k]); }
    }
    if (g < t - j) {
      int r0 = srow_um[j + g];
      u32x4 v0 = *(const u32x4*)(xub + (size_t)r0 * 32 + lr * 4);
      #pragma unroll
      for (int k = 0; k < 4; ++k) { a[2 * k] += bflo(v0[k]); a[2 * k + 1] += bfhi(v0[k]); }
    }
    #pragma unroll
    for (int k = 0; k < 8; ++k) {
      a[k] += __shfl_xor(a[k], 8);
      a[k] += __shfl_xor(a[k], 16);
      a[k] += __shfl_xor(a[k], 32);
    }
    if (g == 0) {
      float inv = 1.f / (float)max(t - s, 1);
      float4 o0 = make_float4(a[0] * inv, a[1] * inv, a[2] * inv, a[3] * inv);
      float4 o1 = make_float4(a[4] * inv, a[5] * inv, a[6] * inv, a[7] * inv);
      *(float4*)(agg_m + (size_t)wid * 64 + lr * 8) = o0;
      *(float4*)(agg_m + (size_t)wid * 64 + lr * 8 + 4) = o1;
    }
  } else {
    int wid = ((bid - MBLK) * 256 + tid) >> 6;
    int s = off_mu[wid], t = off_mu[wid + 1];
    float a[4] = {};
    int j = s;
    for (; j + 16 <= t; j += 16) {
      int r0 = srow_mu[j + g], r1 = srow_mu[j + 8 + g];
      float4 v0 = *(const float4*)(xm + (size_t)r0 * 32 + lr * 4);
      float4 v1 = *(const float4*)(xm + (size_t)r1 * 32 + lr * 4);
      a[0] += v0.x + v1.x; a[1] += v0.y + v1.y;
      a[2] += v0.z + v1.z; a[3] += v0.w + v1.w;
    }
    for (; j + 8 <= t; j += 8) {
      int r0 = srow_mu[j + g];
      float4 v0 = *(const float4*)(xm + (size_t)r0 * 32 + lr * 4);
      a[0] += v0.x; a[1] += v0.y; a[2] += v0.z; a[3] += v0.w;
    }
    if (g < t - j) {
      int r0 = srow_mu[j + g];
      float4 v0 = *(const float4*)(xm + (size_t)r0 * 32 + lr * 4);
      a[0] += v0.x; a[1] += v0.y; a[2] += v0.z; a[3] += v0.w;
    }
    #pragma unroll
    for (int k = 0; k < 4; ++k) {
      a[k] += __shfl_xor(a[k], 8);
      a[k] += __shfl_xor(a[k], 16);
      a[k] += __shfl_xor(a[k], 32);
    }
    if (g == 0) {
      float inv = 1.f / (float)max(t - s, 1);
      *(float4*)(agg_u + (size_t)wid * 32 + lr * 4) =
          make_float4(a[0] * inv, a[1] * inv, a[2] * inv, a[3] * inv);
    }
  }
}

// ---------------- merged layer-2 segment-mean (wide-lane bf16 gather) ----------------
__global__ __launch_bounds__(256) void k_agg_l2(
    const int* __restrict__ off_um, const int* __restrict__ srow_um,
    const u16* __restrict__ h_u, u16* __restrict__ aggb_m,
    const int* __restrict__ off_mu, const int* __restrict__ srow_mu,
    const u16* __restrict__ h_m, u16* __restrict__ aggb_u) {
  int bid = blockIdx.x, tid = threadIdx.x;
  const int* off; const int* srow; const u32* x; u32* ag; int wid;
  if (bid < MBLK) {
    off = off_um; srow = srow_um; x = (const u32*)h_u; ag = (u32*)aggb_m;
    wid = (bid * 256 + tid) >> 6;
  } else {
    off = off_mu; srow = srow_mu; x = (const u32*)h_m; ag = (u32*)aggb_u;
    wid = ((bid - MBLK) * 256 + tid) >> 6;
  }
  int l = tid & 63, g = l >> 4, lr = l & 15;
  int s = off[wid], t = off[wid + 1];
  float a[8] = {};
  int j = s;
  for (; j + 8 <= t; j += 8) {
    int r0 = srow[j + g], r1 = srow[j + 4 + g];
    u32x4 v0 = *(const u32x4*)(x + (size_t)r0 * 64 + lr * 4);
    u32x4 v1 = *(const u32x4*)(x + (size_t)r1 * 64 + lr * 4);
    #pragma unroll
    for (int k = 0; k < 4; ++k) {
      a[2 * k] += bflo(v0[k]) + bflo(v1[k]);
      a[2 * k + 1] += bfhi(v0[k]) + bfhi(v1[k]);
    }
  }
  for (; j + 4 <= t; j += 4) {
    int r0 = srow[j + g];
    u32x4 v0 = *(const u32x4*)(x + (size_t)r0 * 64 + lr * 4);
    #pragma unroll
    for (int k = 0; k < 4; ++k) { a[2 * k] += bflo(v0[k]); a[2 * k + 1] += bfhi(v0[k]); }
  }
  if (g < t - j) {
    int r0 = srow[j + g];
    u32x4 v0 = *(const u32x4*)(x + (size_t)r0 * 64 + lr * 4);
    #pragma unroll
    for (int k = 0; k < 4; ++k) { a[2 * k] += bflo(v0[k]); a[2 * k + 1] += bfhi(v0[k]); }
  }
  #pragma unroll
  for (int k = 0; k < 8; ++k) {
    a[k] += __shfl_xor(a[k], 16);
    a[k] += __shfl_xor(a[k], 32);
  }
  if (g == 0) {
    float inv = 1.f / (float)max(t - s, 1);
    u32x4 o;
    #pragma unroll
    for (int k = 0; k < 4; ++k)
      o[k] = (u32)bf16r(a[2 * k] * inv) | ((u32)bf16r(a[2 * k + 1] * inv) << 16);
    *(u32x4*)(ag + (size_t)wid * 64 + lr * 4) = o;
  }
}

// ---------------- layer-1 dual GEMM body (fp32 in, bf16 out) ----------------
template <int KA, int KB>
__device__ inline void gemm1_body(const float* __restrict__ A, const float* __restrict__ B,
                                  const float* __restrict__ Wa, const float* __restrict__ Wb,
                                  const float* __restrict__ bias, u16* __restrict__ outb,
                                  int m0, float* At, float* Bt) {
  int tid = threadIdx.x;
  {
    int m = tid & 31, kq = tid >> 5;
    const float* Ar = A + (size_t)(m0 + m) * KA;
    for (int k0 = kq * 4; k0 < KA; k0 += 32) {
      float4 v = *(const float4*)(Ar + k0);
      At[(k0 + 0) * 32 + m] = v.x; At[(k0 + 1) * 32 + m] = v.y;
      At[(k0 + 2) * 32 + m] = v.z; At[(k0 + 3) * 32 + m] = v.w;
    }
    const float* Br = B + (size_t)(m0 + m) * KB;
    for (int k0 = kq * 4; k0 < KB; k0 += 32) {
      float4 v = *(const float4*)(Br + k0);
      Bt[(k0 + 0) * 32 + m] = v.x; Bt[(k0 + 1) * 32 + m] = v.y;
      Bt[(k0 + 2) * 32 + m] = v.z; Bt[(k0 + 3) * 32 + m] = v.w;
    }
  }
  __syncthreads();
  int tx = tid & 31, ty = tid >> 5;
  float acc[4][4] = {};
  #pragma unroll 4
  for (int k = 0; k < KA; ++k) {
    float4 wv = *(const float4*)(Wa + k * 128 + tx * 4);
    float4 av = *(const float4*)(&At[k * 32 + ty * 4]);
    float am[4] = {av.x, av.y, av.z, av.w};
    float wo[4] = {wv.x, wv.y, wv.z, wv.w};
    #pragma unroll
    for (int mi = 0; mi < 4; ++mi)
      #pragma unroll
      for (int oi = 0; oi < 4; ++oi) acc[mi][oi] += am[mi] * wo[oi];
  }
  #pragma unroll 4
  for (int k = 0; k < KB; ++k) {
    float4 wv = *(const float4*)(Wb + k * 128 + tx * 4);
    float4 av = *(const float4*)(&Bt[k * 32 + ty * 4]);
    float am[4] = {av.x, av.y, av.z, av.w};
    float wo[4] = {wv.x, wv.y, wv.z, wv.w};
    #pragma unroll
    for (int mi = 0; mi < 4; ++mi)
      #pragma unroll
      for (int oi = 0; oi < 4; ++oi) acc[mi][oi] += am[mi] * wo[oi];
  }
  float4 bv = *(const float4*)(bias + tx * 4);
  float bb[4] = {bv.x, bv.y, bv.z, bv.w};
  #pragma unroll
  for (int mi = 0; mi < 4; ++mi) {
    u16x4 o;
    #pragma unroll
    for (int oi = 0; oi < 4; ++oi) {
      float v = acc[mi][oi] + bb[oi];
      v = v > 0.f ? v : 0.f;  // layer-1 relu
      o[oi] = bf16r(v);
    }
    *(u16x4*)(outb + (size_t)(m0 + ty * 4 + mi) * 128 + tx * 4) = o;
  }
}

// merged layer-1 GEMM: blocks [0,G1MB) merchant <64,32>, rest user <32,64>
__global__ __launch_bounds__(256) void k_gemm1(
    const float* __restrict__ agg_m, const float* __restrict__ x_merch,
    const float* __restrict__ W1l_um, const float* __restrict__ W1r_um,
    const float* __restrict__ b1_um, u16* __restrict__ h_m,
    const float* __restrict__ agg_u, const float* __restrict__ x_user,
    const float* __restrict__ W1l_mu, const float* __restrict__ W1r_mu,
    const float* __restrict__ b1_mu, u16* __restrict__ h_u) {
  __shared__ float At[64 * 32];
  __shared__ float Bt[64 * 32];
  int bid = blockIdx.x;
  if (bid < G1MB)
    gemm1_body<64, 32>(agg_m, x_merch, W1l_um, W1r_um, b1_um, h_m, bid * 32, At, Bt);
  else
    gemm1_body<32, 64>(agg_u, x_user, W1l_mu, W1r_mu, b1_mu, h_u, (bid - G1MB) * 32, At, Bt);
}

// ---------------- combined-weight prep: Wt = (W2 @ Wc1half)^T in bf16, plus folded biases ----------------
__global__ __launch_bounds__(256) void k_prep_comb(
    const float* __restrict__ W2l_um, const float* __restrict__ W2r_um,
    const float* __restrict__ W2l_mu, const float* __restrict__ W2r_mu,
    const float* __restrict__ b2_um, const float* __restrict__ b2_mu,
    const float* __restrict__ Wc1, const float* __restrict__ bc1,
    u16* __restrict__ WtA_u, u16* __restrict__ WtB_u,
    u16* __restrict__ WtA_m, u16* __restrict__ WtB_m,
    float* __restrict__ bias_u, float* __restrict__ bias_m) {
  int t = blockIdx.x * 256 + threadIdx.x;
  if (t < 65536) {
    int mat = t >> 14, rem = t & 16383;
    int o = rem >> 7, k = rem & 127;
    const float* W2 = mat == 0 ? W2l_mu : mat == 1 ? W2r_mu : mat == 2 ? W2l_um : W2r_um;
    const float* wc = Wc1 + (mat >= 2 ? 128 * 128 : 0) + o;
    float s = 0.f;
    #pragma unroll 4
    for (int j = 0; j < 128; ++j) s += W2[k * 128 + j] * wc[j * 128];
    u16* dst = mat == 0 ? WtA_u : mat == 1 ? WtB_u : mat == 2 ? WtA_m : WtB_m;
    dst[o * 128 + k] = bf16r(s);
  } else if (t < 65536 + 256) {
    int r = t - 65536;
    int o = r & 127;
    if (r < 128) {
      float s = 0.f;
      for (int j = 0; j < 128; ++j) s += b2_mu[j] * Wc1[j * 128 + o];
      bias_u[o] = s;
    } else {
      float s = bc1[o];  // fold bc1 into merchant-side bias
      for (int j = 0; j < 128; ++j) s += b2_um[j] * Wc1[(128 + j) * 128 + o];
      bias_m[o] = s;
    }
  }
}

// ---------------- merged layer-2 GEMM (bf16 MFMA): outb = bf16(aggb@Wtl + hb@Wtr + bias) ----------------
__global__ __launch_bounds__(256) void k_gemm2_mfma(
    const u16* __restrict__ aggb_m, const u16* __restrict__ h_m,
    const u16* __restrict__ WtA_m, const u16* __restrict__ WtB_m,
    const float* __restrict__ bias_m, u16* __restrict__ pm_b,
    const u16* __restrict__ aggb_u, const u16* __restrict__ h_u,
    const u16* __restrict__ WtA_u, const u16* __restrict__ WtB_u,
    const float* __restrict__ bias_u, u16* __restrict__ pu_b) {
  __shared__ u16 Zs[64 * 256];  // 32KB
  int tid = threadIdx.x;
  int bid = blockIdx.x;
  const u16 *aggb, *hb, *Wtl, *Wtr; const float* bias; u16* zb; int nd, r0;
  if (bid < G2MB) {
    aggb = aggb_m; hb = h_m; Wtl = WtA_m; Wtr = WtB_m; bias = bias_m; zb = pm_b;
    nd = NMV; r0 = bid * 64;
  } else {
    aggb = aggb_u; hb = h_u; Wtl = WtA_u; Wtr = WtB_u; bias = bias_u; zb = pu_b;
    nd = NUV; r0 = (bid - G2MB) * 64;
  }
  {
    int half = (tid >> 4) & 1;
    const u16* tab = half ? hb : aggb;
    #pragma unroll
    for (int it = 0; it < 8; ++it) {
      int q = tid + it * 256;
      int rl = q >> 5;
      int cc = (q & 15) ^ (rl & 7);
      int r = r0 + rl; r = r < nd ? r : nd - 1;
      const u16* src = tab + (size_t)r * 128 + cc * 8;
      u16* dst = Zs + (tid >> 6) * 512 + it * 2048;
      GLOAD_LDS16(src, dst);
    }
  }
  __syncthreads();
  int l = tid & 63, wv = tid >> 6;
  int lg = l >> 4, lr = l & 15;
  f32x4 acc[4][2];
  #pragma unroll
  for (int mt = 0; mt < 4; ++mt)
    #pragma unroll
    for (int c = 0; c < 2; ++c) acc[mt][c] = (f32x4){0.f, 0.f, 0.f, 0.f};
  #pragma unroll
  for (int cti = 0; cti < 2; ++cti) {
    int o = (wv * 2 + cti) * 16 + lr;
    const u16* wpl = Wtl + (size_t)o * 128 + lg * 8;
    const u16* wpr = Wtr + (size_t)o * 128 + lg * 8;
    s16x8 b[8];
    #pragma unroll
    for (int ks = 0; ks < 4; ++ks) b[ks] = *(const s16x8*)(wpl + ks * 32);
    #pragma unroll
    for (int ks = 0; ks < 4; ++ks) b[ks + 4] = *(const s16x8*)(wpr + ks * 32);
    #pragma unroll
    for (int mt = 0; mt < 4; ++mt) {
      int rl = mt * 16 + lr;
      int rb = rl * 512, sw = (rl & 7) << 4;
      #pragma unroll
      for (int ks = 0; ks < 8; ++ks) {
        s16x8 a = *(const s16x8*)((const char*)Zs + ((rb + ks * 64 + lg * 16) ^ sw));
        acc[mt][cti] = __builtin_amdgcn_mfma_f32_16x16x32_bf16(a, b[ks], acc[mt][cti], 0, 0, 0);
      }
    }
  }
  float bv[2];
  #pragma unroll
  for (int cti = 0; cti < 2; ++cti) bv[cti] = bias[(wv * 2 + cti) * 16 + lr];
  #pragma unroll
  for (int mt = 0; mt < 4; ++mt)
    #pragma unroll
    for (int cti = 0; cti < 2; ++cti) {
      int o = (wv * 2 + cti) * 16 + lr;
      #pragma unroll
      for (int rg = 0; rg < 4; ++rg) {
        int r = r0 + mt * 16 + lg * 4 + rg;
        if (r < nd) zb[(size_t)r * 128 + o] = bf16r(acc[mt][cti][rg] + bv[cti]);
      }
    }
}

// ---------------- edge op: out[e] = Wc2 . relu(pu[row_t[e]] + pm[col_t[e]]) + bc2 ----------------
__global__ __launch_bounds__(256) void k_edge(
    const u32* __restrict__ pu, const u32* __restrict__ pm,
    const int* __restrict__ row_t, const int* __restrict__ col_t,
    const float* __restrict__ Wc2, const float* __restrict__ bc2,
    float* __restrict__ out) {
  __shared__ float res[256];
  int tid = threadIdx.x, l = tid & 63, wv = tid >> 6;
  int lr = l & 15, g = l >> 4;
  float w2v[8];
  #pragma unroll
  for (int q = 0; q < 8; ++q) w2v[q] = Wc2[lr * 8 + q];
  int base = blockIdx.x * 256 + wv * 64;
  #pragma unroll 2
  for (int it = 0; it < 16; ++it) {
    int e = base + it * 4 + g;
    int ec = e < ETV ? e : ETV - 1;
    int r = row_t[ec], c = col_t[ec];
    u32x4 a = *(const u32x4*)(pu + (size_t)r * 64 + lr * 4);
    u32x4 b = *(const u32x4*)(pm + (size_t)c * 64 + lr * 4);
    float p = 0.f;
    #pragma unroll
    for (int q = 0; q < 4; ++q) {
      float h0 = bflo(a[q]) + bflo(b[q]);
      float h1 = bfhi(a[q]) + bfhi(b[q]);
      h0 = h0 > 0.f ? h0 : 0.f;
      h1 = h1 > 0.f ? h1 : 0.f;
      p += h0 * w2v[2 * q] + h1 * w2v[2 * q + 1];
    }
    p += __shfl_xor(p, 1); p += __shfl_xor(p, 2);
    p += __shfl_xor(p, 4); p += __shfl_xor(p, 8);
    if (lr == 0) res[wv * 64 + it * 4 + g] = p;
  }
  __syncthreads();
  int eo = blockIdx.x * 256 + tid;
  if (eo < ETV) out[eo] = res[tid] + bc2[0];
}

extern "C" void kernel_launch(void* const* d_in, const int* in_sizes, int n_in,
                              void* d_out, int out_size, void* d_ws, size_t ws_size,
                              hipStream_t stream) {
  const float* x_user  = (const float*)d_in[0];
  const float* x_merch = (const float*)d_in[1];
  const int* row_um = (const int*)d_in[2]; const int* col_um = (const int*)d_in[3];
  const int* row_mu = (const int*)d_in[4]; const int* col_mu = (const int*)d_in[5];
  const int* row_t  = (const int*)d_in[6]; const int* col_t  = (const int*)d_in[7];
  const float* W1l_um = (const float*)d_in[8];  const float* W1r_um = (const float*)d_in[9];  const float* b1_um = (const float*)d_in[10];
  const float* W1l_mu = (const float*)d_in[11]; const float* W1r_mu = (const float*)d_in[12]; const float* b1_mu = (const float*)d_in[13];
  const float* W2l_um = (const float*)d_in[14]; const float* W2r_um = (const float*)d_in[15]; const float* b2_um = (const float*)d_in[16];
  const float* W2l_mu = (const float*)d_in[17]; const float* W2r_mu = (const float*)d_in[18]; const float* b2_mu = (const float*)d_in[19];
  const float* Wc1 = (const float*)d_in[20]; const float* bc1 = (const float*)d_in[21];
  const float* Wc2 = (const float*)d_in[22]; const float* bc2 = (const float*)d_in[23];
  float* out = (float*)d_out;

  char* ws = (char*)d_ws;
  size_t p = 0;
  auto alloc = [&](size_t bytes) -> char* {
    char* r = ws + p;
    p = (p + bytes + 255) & ~(size_t)255;
    return r;
  };
  u32* cnt_um = (u32*)alloc((size_t)NCH * WNM * 4);     // per-chunk byte counters
  u32* cnt_mu = (u32*)alloc((size_t)NCH * WNU * 4);
  u32* pre_um = (u32*)alloc((size_t)NCH * WNM * 4);     // per-chunk byte prefixes
  u32* pre_mu = (u32*)alloc((size_t)NCH * WNU * 4);
  u32* rankp_um = (u32*)alloc((size_t)(NEV / 4) * 4);   // packed chunk-local ranks
  u32* rankp_mu = (u32*)alloc((size_t)(NEV / 4) * 4);
  int* off_um = (int*)alloc((size_t)(NMV + 4) * 4);
  int* off_mu = (int*)alloc((size_t)(NUV + 4) * 4);
  int* T    = (int*)alloc((size_t)(NMV + NUV) * 4);
  int* bsum = (int*)alloc((size_t)(NCA + NCB) * 4);
  int* srow_um = (int*)alloc((size_t)NEV * 4);
  int* srow_mu = (int*)alloc((size_t)NEV * 4);
  u32* xub = (u32*)alloc((size_t)NUV * 32 * 4);          // x_user in bf16 (packed pairs)
  float* agg_m = (float*)alloc((size_t)NMV * 64 * 4);    // layer1 merchant agg (fp32, 64 feats)
  float* agg_u = (float*)alloc((size_t)NUV * 32 * 4);    // layer1 user agg (fp32, 32 feats)
  u16* h_m   = (u16*)alloc((size_t)NMV * 128 * 2);       // bf16 hidden
  u16* h_u   = (u16*)alloc((size_t)NUV * 128 * 2);
  u16* aggb_m = (u16*)alloc((size_t)NMV * 128 * 2);      // layer2 agg (bf16)
  u16* aggb_u = (u16*)alloc((size_t)NUV * 128 * 2);
  u16* pm_b  = (u16*)alloc((size_t)NMV * 128 * 2);       // folded classifier projections (bf16)
  u16* pu_b  = (u16*)alloc((size_t)NUV * 128 * 2);
  u16* WtA_u = (u16*)alloc((size_t)128 * 128 * 2);
  u16* WtB_u = (u16*)alloc((size_t)128 * 128 * 2);
  u16* WtA_m = (u16*)alloc((size_t)128 * 128 * 2);
  u16* WtB_m = (u16*)alloc((size_t)128 * 128 * 2);
  float* bias_u = (float*)alloc(128 * 4);
  float* bias_m = (float*)alloc(128 * 4);
  if (p > ws_size) return;  // workspace too small: fail loudly via absmax

  k_prep_comb<<<257, 256, 0, stream>>>(W2l_um, W2r_um, W2l_mu, W2r_mu, b2_um, b2_mu, Wc1, bc1,
                                       WtA_u, WtB_u, WtA_m, WtB_m, bias_u, bias_m);
  k_xub<<<1024, 256, 0, stream>>>(x_user, xub, NUV * 64 / 8);
  // CSR build: LDS histogram (0 global atomics), byte prefix planes, off scan, scatter
  k_hist_lds<<<2 * NCH, 512, 0, stream>>>(col_um, rankp_um, cnt_um,
                                          col_mu, rankp_mu, cnt_mu);
  k_scan_s1<<<NCA + NCB, 1024, 0, stream>>>(cnt_um, pre_um, cnt_mu, pre_mu, T, bsum);
  k_scan_s2<<<1, 128, 0, stream>>>(bsum, off_um, off_mu);
  k_scan_s3<<<NCA + NCB, 1024, 0, stream>>>(off_um, off_mu, T, bsum);
  k_scatter3<<<HGRID, 256, 0, stream>>>(col_um, row_um, rankp_um, pre_um, off_um, srow_um,
                                        col_mu, row_mu, rankp_mu, pre_mu, off_mu, srow_mu);
  // layer 1 (merged wide-lane aggs, merged dual GEMMs; bf16 h out)
  k_agg_l1<<<MBLK + NUV / 4, 256, 0, stream>>>(off_um, srow_um, xub, agg_m,
                                               off_mu, srow_mu, x_merch, agg_u);
  k_gemm1<<<G1MB + NUV / 32, 256, 0, stream>>>(agg_m, x_merch, W1l_um, W1r_um, b1_um, h_m,
                                               agg_u, x_user, W1l_mu, W1r_mu, b1_mu, h_u);
  // layer 2 (merged wide-lane aggs, merged MFMA GEMMs with folded classifier weights)
  k_agg_l2<<<MBLK + NUV / 4, 256, 0, stream>>>(off_um, srow_um, h_u, aggb_m,
                                               off_mu, srow_mu, h_m, aggb_u);
  k_gemm2_mfma<<<G2MB + (NUV + 63) / 64, 256, 0, stream>>>(
      aggb_m, h_m, WtA_m, WtB_m, bias_m, pm_b,
      aggb_u, h_u, WtA_u, WtB_u, bias_u, pu_b);
  // edge classifier: gather + relu + dot
  k_edge<<<(ETV + 255) / 256, 256, 0, stream>>>((const u32*)pu_b, (const u32*)pm_b,
                                                row_t, col_t, Wc2, bc2, out);
}

// Round 14
// 322.498 us; speedup vs baseline: 6.4828x; 1.0447x over previous
//
#include <hip/hip_runtime.h>
#include <hip/hip_bf16.h>

// Hetero-SAGE: LDS-histogram CSR build (zero global atomics) + deep-ILP wide-lane
// gathers + all-bf16-MFMA GEMMs with folded classifier (z@Wc1 folded into layer 2).
#define NUV 100000
#define NMV 20000
#define NEV 1000000
#define ETV 500000

#define CHK 8192                  // edges per histogram chunk (2^13)
#define NCH 123                   // ceil(NEV/CHK)
#define WNM 5000                  // merchant hist words (20000 dests / 4 per word)
#define WNU 25000                 // user hist words (100000 / 4)
#define NCA 5                     // merchant scan chunks (4096 dests each)
#define NCB 25                    // user scan chunks
#define HGRID 1954                // ceil(2*NEV/4/256)
#define MBLK 5000                 // merchant agg blocks (NMV/4)
#define G1TM 313                  // merchant layer-1 MFMA tiles (ceil(NMV/64))
#define G2MB 313                  // merchant layer-2 gemm blocks (ceil(NMV/64))

typedef unsigned short u16;
typedef unsigned int u32;
typedef __attribute__((ext_vector_type(8))) short s16x8;
typedef __attribute__((ext_vector_type(4))) float f32x4;
typedef __attribute__((ext_vector_type(2))) unsigned int u32x2;
typedef __attribute__((ext_vector_type(4))) unsigned int u32x4;

__device__ inline u16 bf16r(float f) {  // RTNE float->bf16
  u32 b = __builtin_bit_cast(u32, f);
  u32 r = b + 0x7fffu + ((b >> 16) & 1u);
  return (u16)(r >> 16);
}
__device__ inline float bflo(u32 v) { return __builtin_bit_cast(float, v << 16); }
__device__ inline float bfhi(u32 v) { return __builtin_bit_cast(float, v & 0xffff0000u); }

#define GLOAD_LDS16(src, dst) \
  __builtin_amdgcn_global_load_lds((const __attribute__((address_space(1))) void*)(src), \
                                   (__attribute__((address_space(3))) void*)(dst), 16, 0, 0)

// ---------------- CSR: chunk-local LDS histogram + rank (NO global atomics) ------
__global__ __launch_bounds__(512) void k_hist_lds(
    const int* __restrict__ col_um, u32* __restrict__ rankp_um, u32* __restrict__ cnt_um,
    const int* __restrict__ col_mu, u32* __restrict__ rankp_mu, u32* __restrict__ cnt_mu) {
  __shared__ u32 hist[WNU];  // 100KB (merchant blocks use first WNM words)
  int bid = blockIdx.x, tid = threadIdx.x;
  bool um = bid < NCH;
  const int* col = um ? col_um : col_mu;
  u32* rankp = um ? rankp_um : rankp_mu;
  u32* cntp = um ? cnt_um : cnt_mu;
  int Wn = um ? WNM : WNU;
  int blk = um ? bid : bid - NCH;
  int e0 = blk * CHK;
  for (int i = tid; i < Wn; i += 512) hist[i] = 0;
  __syncthreads();
  #pragma unroll
  for (int it = 0; it < CHK / 2048; ++it) {
    int li = e0 + (it * 512 + tid) * 4;
    if (li < NEV) {
      int4 c = *(const int4*)(col + li);
      int cc[4] = {c.x, c.y, c.z, c.w};
      u32 pk = 0;
      #pragma unroll
      for (int q = 0; q < 4; ++q) {
        int d = cc[q];
        int sh = 8 * (d & 3);
        u32 old = atomicAdd(&hist[d >> 2], 1u << sh);
        pk |= ((old >> sh) & 0xFFu) << (8 * q);
      }
      rankp[li >> 2] = pk;
    }
  }
  __syncthreads();
  u32* dst = cntp + (size_t)blk * Wn;
  for (int i = tid; i < Wn; i += 512) dst[i] = hist[i];
}

// ---- S1: per-dest prefix over chunks (bytes) + per-dest totals T + chunk sums ----
__global__ __launch_bounds__(1024) void k_scan_s1(
    const u32* __restrict__ cnt_um, u32* __restrict__ pre_um,
    const u32* __restrict__ cnt_mu, u32* __restrict__ pre_mu,
    int* __restrict__ T, int* __restrict__ bsum) {
  int b = blockIdx.x;
  const u32* cnt; u32* pre; int Wn; int w0; int* Tout;
  if (b < NCA) { cnt = cnt_um; pre = pre_um; Wn = WNM; w0 = b * 1024; Tout = T; }
  else         { cnt = cnt_mu; pre = pre_mu; Wn = WNU; w0 = (b - NCA) * 1024; Tout = T + NMV; }
  __shared__ int wsum[16];
  int tid = threadIdx.x, lane = tid & 63, w = tid >> 6;
  int wd = w0 + tid;
  int r0 = 0, r1 = 0, r2 = 0, r3 = 0;
  if (wd < Wn) {
    #pragma unroll 4
    for (int bb = 0; bb < NCH; ++bb) {
      u32 v = cnt[(size_t)bb * Wn + wd];
      pre[(size_t)bb * Wn + wd] =
          (u32)r0 | ((u32)r1 << 8) | ((u32)r2 << 16) | ((u32)r3 << 24);
      r0 += v & 0xFF; r1 += (v >> 8) & 0xFF; r2 += (v >> 16) & 0xFF; r3 += (v >> 24) & 0xFF;
    }
    *(int4*)(Tout + wd * 4) = make_int4(r0, r1, r2, r3);
  }
  int tot = r0 + r1 + r2 + r3;
  #pragma unroll
  for (int d = 1; d < 64; d <<= 1) tot += __shfl_xor(tot, d);
  if (lane == 0) wsum[w] = tot;
  __syncthreads();
  if (tid == 0) {
    int a = 0;
    #pragma unroll
    for (int j = 0; j < 16; ++j) a += wsum[j];
    bsum[b] = a;
  }
}

// ---- S2: scan the 30 chunk sums (two segments), set sentinels ----
__global__ __launch_bounds__(128) void k_scan_s2(int* __restrict__ bsum,
                                                 int* __restrict__ off_um, int* __restrict__ off_mu) {
  int tid = threadIdx.x;
  int wv = tid >> 6, lane = tid & 63;
  if (wv == 0) {
    int v = (lane < NCA) ? bsum[lane] : 0;
    int s = v;
    #pragma unroll
    for (int d = 1; d < 64; d <<= 1) { int t = __shfl_up(s, d); if (lane >= d) s += t; }
    if (lane < NCA) bsum[lane] = s - v;
  } else {
    int v = (lane < NCB) ? bsum[NCA + lane] : 0;
    int s = v;
    #pragma unroll
    for (int d = 1; d < 64; d <<= 1) { int t = __shfl_up(s, d); if (lane >= d) s += t; }
    if (lane < NCB) bsum[NCA + lane] = s - v;
  }
  if (tid == 0) { off_um[NMV] = NEV; off_mu[NUV] = NEV; }
}

// ---- S3: off[c] = exclusive scan of T (per 4096-dest chunk, carry from bsum) ----
__global__ __launch_bounds__(1024) void k_scan_s3(int* __restrict__ off_um,
                                                  int* __restrict__ off_mu,
                                                  const int* __restrict__ T,
                                                  const int* __restrict__ bsum) {
  int b = blockIdx.x;
  int N; int c0; int* offo; const int* Tin;
  if (b < NCA) { N = NMV; c0 = b * 4096; offo = off_um; Tin = T; }
  else         { N = NUV; c0 = (b - NCA) * 4096; offo = off_mu; Tin = T + NMV; }
  int carry = bsum[b];
  __shared__ int wsum[16];
  int tid = threadIdx.x, lane = tid & 63, w = tid >> 6;
  int c = c0 + tid * 4;
  int4 tv = make_int4(0, 0, 0, 0);
  if (c < N) tv = *(const int4*)(Tin + c);
  int p1 = tv.x + tv.y, p2 = p1 + tv.z, p3 = p2 + tv.w;
  int sc = p3;
  #pragma unroll
  for (int d = 1; d < 64; d <<= 1) { int t = __shfl_up(sc, d); if (lane >= d) sc += t; }
  if (lane == 63) wsum[w] = sc;
  __syncthreads();
  if (w == 0 && lane < 16) {
    int ws_ = wsum[lane];
    #pragma unroll
    for (int d = 1; d < 16; d <<= 1) { int t = __shfl_up(ws_, d, 16); if (lane >= d) ws_ += t; }
    wsum[lane] = ws_;
  }
  __syncthreads();
  int ex = sc - p3 + (w ? wsum[w - 1] : 0) + carry;
  if (c < N) *(int4*)(offo + c) = make_int4(ex, ex + tv.x, ex + p1, ex + p2);
}

// ---------------- atomic-free scatter: pos = off[c] + pre2d[chunk][c] + rank ------
__global__ __launch_bounds__(256) void k_scatter3(
    const int* __restrict__ col_um, const int* __restrict__ row_um,
    const u32* __restrict__ rankp_um, const u32* __restrict__ pre_um,
    const int* __restrict__ off_um, int* __restrict__ srow_um,
    const int* __restrict__ col_mu, const int* __restrict__ row_mu,
    const u32* __restrict__ rankp_mu, const u32* __restrict__ pre_mu,
    const int* __restrict__ off_mu, int* __restrict__ srow_mu) {
  int i = (blockIdx.x * 256 + threadIdx.x) * 4;
  if (i >= 2 * NEV) return;
  bool um = i < NEV;
  const int* col = um ? col_um : col_mu;
  const int* row = um ? row_um : row_mu;
  const u32* rankp = um ? rankp_um : rankp_mu;
  const u32* pre = um ? pre_um : pre_mu;
  const int* off = um ? off_um : off_mu;
  int Wn = um ? WNM : WNU;
  int* srow = um ? srow_um : srow_mu;
  int lo = um ? i : i - NEV;
  int blk = lo >> 13;  // CHK = 8192
  const u32* prep = pre + (size_t)blk * Wn;
  int4 c = *(const int4*)(col + lo);
  int4 rr = *(const int4*)(row + lo);
  u32 pk = rankp[lo >> 2];
  int cc[4] = {c.x, c.y, c.z, c.w}, rv[4] = {rr.x, rr.y, rr.z, rr.w};
  #pragma unroll
  for (int q = 0; q < 4; ++q) {
    int d = cc[q];
    int prefix = (int)((prep[d >> 2] >> (8 * (d & 3))) & 0xFF);
    int rank = (int)((pk >> (8 * q)) & 0xFF);
    srow[off[d] + prefix + rank] = rv[q];
  }
}

// ---------------- weight prep: folded Wt2, folded biases, Wt1 (zero-padded K=128) ----
__global__ __launch_bounds__(256) void k_prep_w(
    const float* __restrict__ W1l_um, const float* __restrict__ W1r_um,
    const float* __restrict__ W1l_mu, const float* __restrict__ W1r_mu,
    const float* __restrict__ W2l_um, const float* __restrict__ W2r_um,
    const float* __restrict__ W2l_mu, const float* __restrict__ W2r_mu,
    const float* __restrict__ b2_um, const float* __restrict__ b2_mu,
    const float* __restrict__ Wc1, const float* __restrict__ bc1,
    u16* __restrict__ WtA_u, u16* __restrict__ WtB_u,
    u16* __restrict__ WtA_m, u16* __restrict__ WtB_m,
    u16* __restrict__ Wt1_m, u16* __restrict__ Wt1_u,
    float* __restrict__ bias_u, float* __restrict__ bias_m) {
  int t = blockIdx.x * 256 + threadIdx.x;
  if (t < 65536) {
    int mat = t >> 14, rem = t & 16383;
    int o = rem >> 7, k = rem & 127;
    const float* W2 = mat == 0 ? W2l_mu : mat == 1 ? W2r_mu : mat == 2 ? W2l_um : W2r_um;
    const float* wc = Wc1 + (mat >= 2 ? 128 * 128 : 0) + o;
    float s = 0.f;
    #pragma unroll 4
    for (int j = 0; j < 128; ++j) s += W2[k * 128 + j] * wc[j * 128];
    u16* dst = mat == 0 ? WtA_u : mat == 1 ? WtB_u : mat == 2 ? WtA_m : WtB_m;
    dst[o * 128 + k] = bf16r(s);
  } else if (t < 65536 + 256) {
    int r = t - 65536;
    int o = r & 127;
    if (r < 128) {
      float s = 0.f;
      for (int j = 0; j < 128; ++j) s += b2_mu[j] * Wc1[j * 128 + o];
      bias_u[o] = s;
    } else {
      float s = bc1[o];  // fold bc1 into merchant-side bias
      for (int j = 0; j < 128; ++j) s += b2_um[j] * Wc1[(128 + j) * 128 + o];
      bias_m[o] = s;
    }
  } else if (t < 65792 + 32768) {
    int idx = t - 65792;
    int mat = idx >> 14, rem = idx & 16383;
    int o = rem >> 7, k = rem & 127;
    if (mat == 0) {  // merchant: cat_m = [agg64 | x_merch32 | pad32]
      float v = k < 64 ? W1l_um[k * 128 + o] : (k < 96 ? W1r_um[(k - 64) * 128 + o] : 0.f);
      Wt1_m[o * 128 + k] = bf16r(v);
    } else {         // user: cat_u = [agg32 | x_user64 | pad32]
      float v = k < 32 ? W1l_mu[k * 128 + o] : (k < 96 ? W1r_mu[(k - 32) * 128 + o] : 0.f);
      Wt1_u[o * 128 + k] = bf16r(v);
    }
  }
}

// ---------------- x prep: fill cat_u cols 32..127 and cat_m cols 64..127 ----------
__global__ __launch_bounds__(256) void k_prep_x(
    const float* __restrict__ x_user, const float* __restrict__ x_merch,
    u32* __restrict__ cat_u, u32* __restrict__ cat_m) {
  int id = blockIdx.x * 256 + threadIdx.x;
  if (id < NUV * 12) {
    int row = id / 12, wg = id % 12;
    if (wg < 8) {
      const float* src = x_user + (size_t)row * 64 + wg * 8;
      float4 a = *(const float4*)src, b = *(const float4*)(src + 4);
      u32x4 r;
      r[0] = (u32)bf16r(a.x) | ((u32)bf16r(a.y) << 16);
      r[1] = (u32)bf16r(a.z) | ((u32)bf16r(a.w) << 16);
      r[2] = (u32)bf16r(b.x) | ((u32)bf16r(b.y) << 16);
      r[3] = (u32)bf16r(b.z) | ((u32)bf16r(b.w) << 16);
      *(u32x4*)(cat_u + (size_t)row * 64 + 16 + wg * 4) = r;
    } else {
      *(u32x4*)(cat_u + (size_t)row * 64 + 48 + (wg - 8) * 4) = (u32x4){0, 0, 0, 0};
    }
  } else if (id < NUV * 12 + NMV * 8) {
    int id2 = id - NUV * 12;
    int row = id2 / 8, wg = id2 % 8;
    if (wg < 4) {
      const float* src = x_merch + (size_t)row * 32 + wg * 8;
      float4 a = *(const float4*)src, b = *(const float4*)(src + 4);
      u32x4 r;
      r[0] = (u32)bf16r(a.x) | ((u32)bf16r(a.y) << 16);
      r[1] = (u32)bf16r(a.z) | ((u32)bf16r(a.w) << 16);
      r[2] = (u32)bf16r(b.x) | ((u32)bf16r(b.y) << 16);
      r[3] = (u32)bf16r(b.z) | ((u32)bf16r(b.w) << 16);
      *(u32x4*)(cat_m + (size_t)row * 64 + 32 + wg * 4) = r;
    } else {
      *(u32x4*)(cat_m + (size_t)row * 64 + 48 + (wg - 4) * 4) = (u32x4){0, 0, 0, 0};
    }
  }
}

// ---------------- merged layer-1 segment-mean (4-deep wide-lane gathers, bf16 out) ----
// merchant: gather x_user region of cat_u (8 lanes x u32x4 = 128B row), 32 edges/iter.
// user:     gather x_merch region of cat_m (8 lanes x u32x2 = 64B row), 32 edges/iter.
__global__ __launch_bounds__(256) void k_agg_l1(
    const int* __restrict__ off_um, const int* __restrict__ srow_um,
    const int* __restrict__ off_mu, const int* __restrict__ srow_mu,
    u32* __restrict__ cat_u, u32* __restrict__ cat_m) {
  int bid = blockIdx.x, tid = threadIdx.x;
  int l = tid & 63, g = l >> 3, lr = l & 7;
  if (bid < MBLK) {
    int wid = (bid * 256 + tid) >> 6;
    int s = off_um[wid], t = off_um[wid + 1];
    const u32* gx = cat_u;  // x region at +16
    float a[8] = {};
    int j = s;
    for (; j + 32 <= t; j += 32) {
      int r0 = srow_um[j + g], r1 = srow_um[j + 8 + g];
      int r2 = srow_um[j + 16 + g], r3 = srow_um[j + 24 + g];
      u32x4 v0 = *(const u32x4*)(gx + (size_t)r0 * 64 + 16 + lr * 4);
      u32x4 v1 = *(const u32x4*)(gx + (size_t)r1 * 64 + 16 + lr * 4);
      u32x4 v2 = *(const u32x4*)(gx + (size_t)r2 * 64 + 16 + lr * 4);
      u32x4 v3 = *(const u32x4*)(gx + (size_t)r3 * 64 + 16 + lr * 4);
      #pragma unroll
      for (int k = 0; k < 4; ++k) {
        a[2 * k] += (bflo(v0[k]) + bflo(v1[k])) + (bflo(v2[k]) + bflo(v3[k]));
        a[2 * k + 1] += (bfhi(v0[k]) + bfhi(v1[k])) + (bfhi(v2[k]) + bfhi(v3[k]));
      }
    }
    for (; j + 8 <= t; j += 8) {
      int r0 = srow_um[j + g];
      u32x4 v0 = *(const u32x4*)(gx + (size_t)r0 * 64 + 16 + lr * 4);
      #pragma unroll
      for (int k = 0; k < 4; ++k) { a[2 * k] += bflo(v0[k]); a[2 * k + 1] += bfhi(v0[k]); }
    }
    if (g < t - j) {
      int r0 = srow_um[j + g];
      u32x4 v0 = *(const u32x4*)(gx + (size_t)r0 * 64 + 16 + lr * 4);
      #pragma unroll
      for (int k = 0; k < 4; ++k) { a[2 * k] += bflo(v0[k]); a[2 * k + 1] += bfhi(v0[k]); }
    }
    #pragma unroll
    for (int k = 0; k < 8; ++k) {
      a[k] += __shfl_xor(a[k], 8);
      a[k] += __shfl_xor(a[k], 16);
      a[k] += __shfl_xor(a[k], 32);
    }
    if (g == 0) {
      float inv = 1.f / (float)max(t - s, 1);
      u32x4 o;
      #pragma unroll
      for (int k = 0; k < 4; ++k)
        o[k] = (u32)bf16r(a[2 * k] * inv) | ((u32)bf16r(a[2 * k + 1] * inv) << 16);
      *(u32x4*)(cat_m + (size_t)wid * 64 + lr * 4) = o;
    }
  } else {
    int wid = ((bid - MBLK) * 256 + tid) >> 6;
    int s = off_mu[wid], t = off_mu[wid + 1];
    const u32* gx = cat_m;  // x region at +32
    float a[4] = {};
    int j = s;
    for (; j + 32 <= t; j += 32) {
      int r0 = srow_mu[j + g], r1 = srow_mu[j + 8 + g];
      int r2 = srow_mu[j + 16 + g], r3 = srow_mu[j + 24 + g];
      u32x2 v0 = *(const u32x2*)(gx + (size_t)r0 * 64 + 32 + lr * 2);
      u32x2 v1 = *(const u32x2*)(gx + (size_t)r1 * 64 + 32 + lr * 2);
      u32x2 v2 = *(const u32x2*)(gx + (size_t)r2 * 64 + 32 + lr * 2);
      u32x2 v3 = *(const u32x2*)(gx + (size_t)r3 * 64 + 32 + lr * 2);
      #pragma unroll
      for (int k = 0; k < 2; ++k) {
        a[2 * k] += (bflo(v0[k]) + bflo(v1[k])) + (bflo(v2[k]) + bflo(v3[k]));
        a[2 * k + 1] += (bfhi(v0[k]) + bfhi(v1[k])) + (bfhi(v2[k]) + bfhi(v3[k]));
      }
    }
    for (; j + 8 <= t; j += 8) {
      int r0 = srow_mu[j + g];
      u32x2 v0 = *(const u32x2*)(gx + (size_t)r0 * 64 + 32 + lr * 2);
      #pragma unroll
      for (int k = 0; k < 2; ++k) { a[2 * k] += bflo(v0[k]); a[2 * k + 1] += bfhi(v0[k]); }
    }
    if (g < t - j) {
      int r0 = srow_mu[j + g];
      u32x2 v0 = *(const u32x2*)(gx + (size_t)r0 * 64 + 32 + lr * 2);
      #pragma unroll
      for (int k = 0; k < 2; ++k) { a[2 * k] += bflo(v0[k]); a[2 * k + 1] += bfhi(v0[k]); }
    }
    #pragma unroll
    for (int k = 0; k < 4; ++k) {
      a[k] += __shfl_xor(a[k], 8);
      a[k] += __shfl_xor(a[k], 16);
      a[k] += __shfl_xor(a[k], 32);
    }
    if (g == 0) {
      float inv = 1.f / (float)max(t - s, 1);
      u32x2 o;
      #pragma unroll
      for (int k = 0; k < 2; ++k)
        o[k] = (u32)bf16r(a[2 * k] * inv) | ((u32)bf16r(a[2 * k + 1] * inv) << 16);
      *(u32x2*)(cat_u + (size_t)wid * 64 + lr * 2) = o;
    }
  }
}

// ---------------- layer-1 MFMA GEMM: h = relu(cat @ Wt1^T + b1), bf16 out ----------
__global__ __launch_bounds__(256) void k_gemm1_mfma(
    const u16* __restrict__ cat_m, const u16* __restrict__ Wt1_m,
    const float* __restrict__ b1_um, u16* __restrict__ h_m,
    const u16* __restrict__ cat_u, const u16* __restrict__ Wt1_u,
    const float* __restrict__ b1_mu, u16* __restrict__ h_u) {
  __shared__ u16 Zs[64 * 128];  // 16KB
  int tid = threadIdx.x, bid = blockIdx.x;
  const u16 *cat, *Wt; const float* bias; u16* ho; int nd, r0;
  if (bid < G1TM) { cat = cat_m; Wt = Wt1_m; bias = b1_um; ho = h_m; nd = NMV; r0 = bid * 64; }
  else { cat = cat_u; Wt = Wt1_u; bias = b1_mu; ho = h_u; nd = NUV; r0 = (bid - G1TM) * 64; }
  #pragma unroll
  for (int it = 0; it < 4; ++it) {
    int q = tid + it * 256;
    int rl = q >> 4;
    int cc = (q & 15) ^ (rl & 7);
    int r = r0 + rl; r = r < nd ? r : nd - 1;
    const u16* src = cat + (size_t)r * 128 + cc * 8;
    u16* dst = Zs + (tid >> 6) * 512 + it * 2048;
    GLOAD_LDS16(src, dst);
  }
  __syncthreads();
  int l = tid & 63, wv = tid >> 6;
  int lg = l >> 4, lr = l & 15;
  f32x4 acc[4][2];
  #pragma unroll
  for (int mt = 0; mt < 4; ++mt)
    #pragma unroll
    for (int c = 0; c < 2; ++c) acc[mt][c] = (f32x4){0.f, 0.f, 0.f, 0.f};
  #pragma unroll
  for (int cti = 0; cti < 2; ++cti) {
    int o = (wv * 2 + cti) * 16 + lr;
    const u16* wp = Wt + (size_t)o * 128 + lg * 8;
    s16x8 b[4];
    #pragma unroll
    for (int ks = 0; ks < 4; ++ks) b[ks] = *(const s16x8*)(wp + ks * 32);
    #pragma unroll
    for (int mt = 0; mt < 4; ++mt) {
      int rl = mt * 16 + lr;
      int rb = rl * 256, sw = (rl & 7) << 4;
      #pragma unroll
      for (int ks = 0; ks < 4; ++ks) {
        s16x8 a = *(const s16x8*)((const char*)Zs + ((rb + ks * 64 + lg * 16) ^ sw));
        acc[mt][cti] = __builtin_amdgcn_mfma_f32_16x16x32_bf16(a, b[ks], acc[mt][cti], 0, 0, 0);
      }
    }
  }
  float bv[2];
  #pragma unroll
  for (int cti = 0; cti < 2; ++cti) bv[cti] = bias[(wv * 2 + cti) * 16 + lr];
  #pragma unroll
  for (int mt = 0; mt < 4; ++mt)
    #pragma unroll
    for (int cti = 0; cti < 2; ++cti) {
      int o = (wv * 2 + cti) * 16 + lr;
      #pragma unroll
      for (int rg = 0; rg < 4; ++rg) {
        int r = r0 + mt * 16 + lg * 4 + rg;
        if (r < nd) {
          float v = acc[mt][cti][rg] + bv[cti];
          v = v > 0.f ? v : 0.f;  // layer-1 relu
          ho[(size_t)r * 128 + o] = bf16r(v);
        }
      }
    }
}

// ---------------- merged layer-2 segment-mean (4-deep wide-lane bf16 gather) --------
__global__ __launch_bounds__(256) void k_agg_l2(
    const int* __restrict__ off_um, const int* __restrict__ srow_um,
    const u16* __restrict__ h_u, u16* __restrict__ aggb_m,
    const int* __restrict__ off_mu, const int* __restrict__ srow_mu,
    const u16* __restrict__ h_m, u16* __restrict__ aggb_u) {
  int bid = blockIdx.x, tid = threadIdx.x;
  const int* off; const int* srow; const u32* x; u32* ag; int wid;
  if (bid < MBLK) {
    off = off_um; srow = srow_um; x = (const u32*)h_u; ag = (u32*)aggb_m;
    wid = (bid * 256 + tid) >> 6;
  } else {
    off = off_mu; srow = srow_mu; x = (const u32*)h_m; ag = (u32*)aggb_u;
    wid = ((bid - MBLK) * 256 + tid) >> 6;
  }
  int l = tid & 63, g = l >> 4, lr = l & 15;
  int s = off[wid], t = off[wid + 1];
  float a[8] = {};
  int j = s;
  for (; j + 16 <= t; j += 16) {
    int r0 = srow[j + g], r1 = srow[j + 4 + g];
    int r2 = srow[j + 8 + g], r3 = srow[j + 12 + g];
    u32x4 v0 = *(const u32x4*)(x + (size_t)r0 * 64 + lr * 4);
    u32x4 v1 = *(const u32x4*)(x + (size_t)r1 * 64 + lr * 4);
    u32x4 v2 = *(const u32x4*)(x + (size_t)r2 * 64 + lr * 4);
    u32x4 v3 = *(const u32x4*)(x + (size_t)r3 * 64 + lr * 4);
    #pragma unroll
    for (int k = 0; k < 4; ++k) {
      a[2 * k] += (bflo(v0[k]) + bflo(v1[k])) + (bflo(v2[k]) + bflo(v3[k]));
      a[2 * k + 1] += (bfhi(v0[k]) + bfhi(v1[k])) + (bfhi(v2[k]) + bfhi(v3[k]));
    }
  }
  for (; j + 4 <= t; j += 4) {
    int r0 = srow[j + g];
    u32x4 v0 = *(const u32x4*)(x + (size_t)r0 * 64 + lr * 4);
    #pragma unroll
    for (int k = 0; k < 4; ++k) { a[2 * k] += bflo(v0[k]); a[2 * k + 1] += bfhi(v0[k]); }
  }
  if (g < t - j) {
    int r0 = srow[j + g];
    u32x4 v0 = *(const u32x4*)(x + (size_t)r0 * 64 + lr * 4);
    #pragma unroll
    for (int k = 0; k < 4; ++k) { a[2 * k] += bflo(v0[k]); a[2 * k + 1] += bfhi(v0[k]); }
  }
  #pragma unroll
  for (int k = 0; k < 8; ++k) {
    a[k] += __shfl_xor(a[k], 16);
    a[k] += __shfl_xor(a[k], 32);
  }
  if (g == 0) {
    float inv = 1.f / (float)max(t - s, 1);
    u32x4 o;
    #pragma unroll
    for (int k = 0; k < 4; ++k)
      o[k] = (u32)bf16r(a[2 * k] * inv) | ((u32)bf16r(a[2 * k + 1] * inv) << 16);
    *(u32x4*)(ag + (size_t)wid * 64 + lr * 4) = o;
  }
}

// ---------------- merged layer-2 GEMM (bf16 MFMA): outb = bf16(aggb@Wtl + hb@Wtr + bias) ----
__global__ __launch_bounds__(256) void k_gemm2_mfma(
    const u16* __restrict__ aggb_m, const u16* __restrict__ h_m,
    const u16* __restrict__ WtA_m, const u16* __restrict__ WtB_m,
    const float* __restrict__ bias_m, u16* __restrict__ pm_b,
    const u16* __restrict__ aggb_u, const u16* __restrict__ h_u,
    const u16* __restrict__ WtA_u, const u16* __restrict__ WtB_u,
    const float* __restrict__ bias_u, u16* __restrict__ pu_b) {
  __shared__ u16 Zs[64 * 256];  // 32KB
  int tid = threadIdx.x;
  int bid = blockIdx.x;
  const u16 *aggb, *hb, *Wtl, *Wtr; const float* bias; u16* zb; int nd, r0;
  if (bid < G2MB) {
    aggb = aggb_m; hb = h_m; Wtl = WtA_m; Wtr = WtB_m; bias = bias_m; zb = pm_b;
    nd = NMV; r0 = bid * 64;
  } else {
    aggb = aggb_u; hb = h_u; Wtl = WtA_u; Wtr = WtB_u; bias = bias_u; zb = pu_b;
    nd = NUV; r0 = (bid - G2MB) * 64;
  }
  {
    int half = (tid >> 4) & 1;
    const u16* tab = half ? hb : aggb;
    #pragma unroll
    for (int it = 0; it < 8; ++it) {
      int q = tid + it * 256;
      int rl = q >> 5;
      int cc = (q & 15) ^ (rl & 7);
      int r = r0 + rl; r = r < nd ? r : nd - 1;
      const u16* src = tab + (size_t)r * 128 + cc * 8;
      u16* dst = Zs + (tid >> 6) * 512 + it * 2048;
      GLOAD_LDS16(src, dst);
    }
  }
  __syncthreads();
  int l = tid & 63, wv = tid >> 6;
  int lg = l >> 4, lr = l & 15;
  f32x4 acc[4][2];
  #pragma unroll
  for (int mt = 0; mt < 4; ++mt)
    #pragma unroll
    for (int c = 0; c < 2; ++c) acc[mt][c] = (f32x4){0.f, 0.f, 0.f, 0.f};
  #pragma unroll
  for (int cti = 0; cti < 2; ++cti) {
    int o = (wv * 2 + cti) * 16 + lr;
    const u16* wpl = Wtl + (size_t)o * 128 + lg * 8;
    const u16* wpr = Wtr + (size_t)o * 128 + lg * 8;
    s16x8 b[8];
    #pragma unroll
    for (int ks = 0; ks < 4; ++ks) b[ks] = *(const s16x8*)(wpl + ks * 32);
    #pragma unroll
    for (int ks = 0; ks < 4; ++ks) b[ks + 4] = *(const s16x8*)(wpr + ks * 32);
    #pragma unroll
    for (int mt = 0; mt < 4; ++mt) {
      int rl = mt * 16 + lr;
      int rb = rl * 512, sw = (rl & 7) << 4;
      #pragma unroll
      for (int ks = 0; ks < 8; ++ks) {
        s16x8 a = *(const s16x8*)((const char*)Zs + ((rb + ks * 64 + lg * 16) ^ sw));
        acc[mt][cti] = __builtin_amdgcn_mfma_f32_16x16x32_bf16(a, b[ks], acc[mt][cti], 0, 0, 0);
      }
    }
  }
  float bv[2];
  #pragma unroll
  for (int cti = 0; cti < 2; ++cti) bv[cti] = bias[(wv * 2 + cti) * 16 + lr];
  #pragma unroll
  for (int mt = 0; mt < 4; ++mt)
    #pragma unroll
    for (int cti = 0; cti < 2; ++cti) {
      int o = (wv * 2 + cti) * 16 + lr;
      #pragma unroll
      for (int rg = 0; rg < 4; ++rg) {
        int r = r0 + mt * 16 + lg * 4 + rg;
        if (r < nd) zb[(size_t)r * 128 + o] = bf16r(acc[mt][cti][rg] + bv[cti]);
      }
    }
}

// ---------------- edge op: out[e] = Wc2 . relu(pu[row_t[e]] + pm[col_t[e]]) + bc2 ----------------
__global__ __launch_bounds__(256) void k_edge(
    const u32* __restrict__ pu, const u32* __restrict__ pm,
    const int* __restrict__ row_t, const int* __restrict__ col_t,
    const float* __restrict__ Wc2, const float* __restrict__ bc2,
    float* __restrict__ out) {
  __shared__ float res[256];
  int tid = threadIdx.x, l = tid & 63, wv = tid >> 6;
  int lr = l & 15, g = l >> 4;
  float w2v[8];
  #pragma unroll
  for (int q = 0; q < 8; ++q) w2v[q] = Wc2[lr * 8 + q];
  int base = blockIdx.x * 256 + wv * 64;
  #pragma unroll 2
  for (int it = 0; it < 16; ++it) {
    int e = base + it * 4 + g;
    int ec = e < ETV ? e : ETV - 1;
    int r = row_t[ec], c = col_t[ec];
    u32x4 a = *(const u32x4*)(pu + (size_t)r * 64 + lr * 4);
    u32x4 b = *(const u32x4*)(pm + (size_t)c * 64 + lr * 4);
    float p = 0.f;
    #pragma unroll
    for (int q = 0; q < 4; ++q) {
      float h0 = bflo(a[q]) + bflo(b[q]);
      float h1 = bfhi(a[q]) + bfhi(b[q]);
      h0 = h0 > 0.f ? h0 : 0.f;
      h1 = h1 > 0.f ? h1 : 0.f;
      p += h0 * w2v[2 * q] + h1 * w2v[2 * q + 1];
    }
    p += __shfl_xor(p, 1); p += __shfl_xor(p, 2);
    p += __shfl_xor(p, 4); p += __shfl_xor(p, 8);
    if (lr == 0) res[wv * 64 + it * 4 + g] = p;
  }
  __syncthreads();
  int eo = blockIdx.x * 256 + tid;
  if (eo < ETV) out[eo] = res[tid] + bc2[0];
}

extern "C" void kernel_launch(void* const* d_in, const int* in_sizes, int n_in,
                              void* d_out, int out_size, void* d_ws, size_t ws_size,
                              hipStream_t stream) {
  const float* x_user  = (const float*)d_in[0];
  const float* x_merch = (const float*)d_in[1];
  const int* row_um = (const int*)d_in[2]; const int* col_um = (const int*)d_in[3];
  const int* row_mu = (const int*)d_in[4]; const int* col_mu = (const int*)d_in[5];
  const int* row_t  = (const int*)d_in[6]; const int* col_t  = (const int*)d_in[7];
  const float* W1l_um = (const float*)d_in[8];  const float* W1r_um = (const float*)d_in[9];  const float* b1_um = (const float*)d_in[10];
  const float* W1l_mu = (const float*)d_in[11]; const float* W1r_mu = (const float*)d_in[12]; const float* b1_mu = (const float*)d_in[13];
  const float* W2l_um = (const float*)d_in[14]; const float* W2r_um = (const float*)d_in[15]; const float* b2_um = (const float*)d_in[16];
  const float* W2l_mu = (const float*)d_in[17]; const float* W2r_mu = (const float*)d_in[18]; const float* b2_mu = (const float*)d_in[19];
  const float* Wc1 = (const float*)d_in[20]; const float* bc1 = (const float*)d_in[21];
  const float* Wc2 = (const float*)d_in[22]; const float* bc2 = (const float*)d_in[23];
  float* out = (float*)d_out;

  char* ws = (char*)d_ws;
  size_t p = 0;
  auto alloc = [&](size_t bytes) -> char* {
    char* r = ws + p;
    p = (p + bytes + 255) & ~(size_t)255;
    return r;
  };
  u32* cnt_um = (u32*)alloc((size_t)NCH * WNM * 4);     // per-chunk byte counters
  u32* cnt_mu = (u32*)alloc((size_t)NCH * WNU * 4);
  u32* pre_um = (u32*)alloc((size_t)NCH * WNM * 4);     // per-chunk byte prefixes
  u32* pre_mu = (u32*)alloc((size_t)NCH * WNU * 4);
  u32* rankp_um = (u32*)alloc((size_t)(NEV / 4) * 4);   // packed chunk-local ranks
  u32* rankp_mu = (u32*)alloc((size_t)(NEV / 4) * 4);
  int* off_um = (int*)alloc((size_t)(NMV + 4) * 4);
  int* off_mu = (int*)alloc((size_t)(NUV + 4) * 4);
  int* T    = (int*)alloc((size_t)(NMV + NUV) * 4);
  int* bsum = (int*)alloc((size_t)(NCA + NCB) * 4);
  int* srow_um = (int*)alloc((size_t)NEV * 4);
  int* srow_mu = (int*)alloc((size_t)NEV * 4);
  u16* cat_m = (u16*)alloc((size_t)NMV * 128 * 2);       // [agg64|xm32|pad32] bf16
  u16* cat_u = (u16*)alloc((size_t)NUV * 128 * 2);       // [agg32|xu64|pad32] bf16
  u16* h_m   = (u16*)alloc((size_t)NMV * 128 * 2);       // bf16 hidden
  u16* h_u   = (u16*)alloc((size_t)NUV * 128 * 2);
  u16* aggb_m = (u16*)alloc((size_t)NMV * 128 * 2);      // layer2 agg (bf16)
  u16* aggb_u = (u16*)alloc((size_t)NUV * 128 * 2);
  u16* pm_b  = (u16*)alloc((size_t)NMV * 128 * 2);       // folded classifier projections (bf16)
  u16* pu_b  = (u16*)alloc((size_t)NUV * 128 * 2);
  u16* WtA_u = (u16*)alloc((size_t)128 * 128 * 2);
  u16* WtB_u = (u16*)alloc((size_t)128 * 128 * 2);
  u16* WtA_m = (u16*)alloc((size_t)128 * 128 * 2);
  u16* WtB_m = (u16*)alloc((size_t)128 * 128 * 2);
  u16* Wt1_m = (u16*)alloc((size_t)128 * 128 * 2);
  u16* Wt1_u = (u16*)alloc((size_t)128 * 128 * 2);
  float* bias_u = (float*)alloc(128 * 4);
  float* bias_m = (float*)alloc(128 * 4);
  if (p > ws_size) return;  // workspace too small: fail loudly via absmax

  k_prep_w<<<386, 256, 0, stream>>>(W1l_um, W1r_um, W1l_mu, W1r_mu,
                                    W2l_um, W2r_um, W2l_mu, W2r_mu, b2_um, b2_mu, Wc1, bc1,
                                    WtA_u, WtB_u, WtA_m, WtB_m, Wt1_m, Wt1_u, bias_u, bias_m);
  k_prep_x<<<(NUV * 12 + NMV * 8 + 255) / 256, 256, 0, stream>>>(x_user, x_merch,
                                                                 (u32*)cat_u, (u32*)cat_m);
  // CSR build: LDS histogram (0 global atomics), byte prefix planes, off scan, scatter
  k_hist_lds<<<2 * NCH, 512, 0, stream>>>(col_um, rankp_um, cnt_um,
                                          col_mu, rankp_mu, cnt_mu);
  k_scan_s1<<<NCA + NCB, 1024, 0, stream>>>(cnt_um, pre_um, cnt_mu, pre_mu, T, bsum);
  k_scan_s2<<<1, 128, 0, stream>>>(bsum, off_um, off_mu);
  k_scan_s3<<<NCA + NCB, 1024, 0, stream>>>(off_um, off_mu, T, bsum);
  k_scatter3<<<HGRID, 256, 0, stream>>>(col_um, row_um, rankp_um, pre_um, off_um, srow_um,
                                        col_mu, row_mu, rankp_mu, pre_mu, off_mu, srow_mu);
  // layer 1: deep-ILP bf16 gathers into cat agg-columns, then MFMA GEMM -> h
  k_agg_l1<<<MBLK + NUV / 4, 256, 0, stream>>>(off_um, srow_um, off_mu, srow_mu,
                                               (u32*)cat_u, (u32*)cat_m);
  k_gemm1_mfma<<<G1TM + (NUV + 63) / 64, 256, 0, stream>>>(cat_m, Wt1_m, b1_um, h_m,
                                                           cat_u, Wt1_u, b1_mu, h_u);
  // layer 2: deep-ILP bf16 gathers -> MFMA GEMM with folded classifier weights
  k_agg_l2<<<MBLK + NUV / 4, 256, 0, stream>>>(off_um, srow_um, h_u, aggb_m,
                                               off_mu, srow_mu, h_m, aggb_u);
  k_gemm2_mfma<<<G2MB + (NUV + 63) / 64, 256, 0, stream>>>(
      aggb_m, h_m, WtA_m, WtB_m, bias_m, pm_b,
      aggb_u, h_u, WtA_u, WtB_u, bias_u, pu_b);
  // edge classifier: gather + relu + dot
  k_edge<<<(ETV + 255) / 256, 256, 0, stream>>>((const u32*)pu_b, (const u32*)pm_b,
                                                row_t, col_t, Wc2, bc2, out);
}